// Round 6
// baseline (141175.244 us; speedup 1.0000x reference)
//
#include <hip/hip_runtime.h>
#include <hip/hip_bf16.h>

// Interior-point QP solver (reference: jax _solve_qp), computed in f64 on-device.
// H = tril(L)tril(L)^T + eps I + G^T D G; blocked chol BS=64 (relative pivot
// floor) with explicit diag-block inverses; W = L^-1 [A^T | rhs1]; S = W^T W;
// chol(S); dy, dx.  Output x as FLOAT32 (d_out is f32 — verified via out_npz size).
// Diagnostics in out[0] (decade-separated): ws | it0-solve | final-rx | comp | feas.

constexpr int ND = 1024;     // n
constexpr int MI = 512;      // # inequality
constexpr int PE = 256;      // # equality
constexpr int NRHS = PE + 1; // 257 (A^T columns + rhs1)
constexpr int LDWm = 264;    // padded leading dim of W
constexpr double EPSQ = 1e-4;
constexpr double SIG = 0.1;
constexpr int NITER = 25;

__device__ __forceinline__ double wred(double v) {
#pragma unroll
  for (int off = 32; off; off >>= 1) v += __shfl_down(v, off, 64);
  return v;
}

// ---------------- setup ----------------
__global__ void k_prep(const float* __restrict__ Gf, const float* __restrict__ Af,
                       const float* __restrict__ qf, const float* __restrict__ bf,
                       float* __restrict__ GTf, float* __restrict__ ATf,
                       double* __restrict__ qd, double* __restrict__ bd,
                       double* __restrict__ xv, double* __restrict__ sv,
                       double* __restrict__ zv, double* __restrict__ yv) {
  for (size_t idx = (size_t)blockIdx.x * blockDim.x + threadIdx.x;
       idx < (size_t)MI * ND; idx += (size_t)gridDim.x * blockDim.x) {
    int k = (int)(idx >> 10), i = (int)(idx & 1023);
    GTf[(size_t)i * MI + k] = Gf[idx];
    if (idx < (size_t)PE * ND) ATf[(size_t)i * PE + k] = Af[idx];
    if (idx < ND) { qd[idx] = (double)qf[idx]; xv[idx] = 0.0; }
    if (idx < MI) { sv[idx] = 1.0; zv[idx] = 1.0; }
    if (idx < PE) { bd[idx] = (double)bf[idx]; yv[idx] = 0.0; }
  }
}

__global__ __launch_bounds__(256) void k_h(const float* __restrict__ Gf,
                                           const float* __restrict__ x0f,
                                           const float* __restrict__ s0f,
                                           double* __restrict__ hd) {
  int wid = blockIdx.x * 4 + (int)(threadIdx.x >> 6), lane = threadIdx.x & 63;
  if (wid >= MI) return;
  double acc = 0;
  for (int c = lane; c < ND; c += 64) acc += (double)Gf[(size_t)wid * ND + c] * (double)x0f[c];
  acc = wred(acc);
  if (lane == 0) hd[wid] = acc + (double)s0f[wid];
}

// u = tril(L)^T * x
__global__ __launch_bounds__(256) void k_ltx(const float* __restrict__ Lf,
                                             const double* __restrict__ xin,
                                             double* __restrict__ out) {
  __shared__ double Ls[64][65];
  __shared__ double xs[64];
  __shared__ double part[4][64];
  int t = threadIdx.x;
  int k0 = blockIdx.x * 64;
  int c = t & 63, g = t >> 6;
  double acc = 0;
  for (int i0 = k0; i0 < ND; i0 += 64) {
    for (int l = t; l < 4096; l += 256) {
      int r = l >> 6, cc = l & 63;
      Ls[r][cc] = (i0 + r >= k0 + cc) ? (double)Lf[(size_t)(i0 + r) * ND + k0 + cc] : 0.0;
    }
    if (t < 64) xs[t] = xin[i0 + t];
    __syncthreads();
    for (int r = g; r < 64; r += 4) acc += Ls[r][c] * xs[r];
    __syncthreads();
  }
  part[g][c] = acc;
  __syncthreads();
  if (t < 64) out[k0 + t] = part[0][t] + part[1][t] + part[2][t] + part[3][t];
}

// r_x = Qx + q + G^T z + A^T y,  Qx = tril(L) u1 + eps x
__global__ __launch_bounds__(256) void k_rx(const float* __restrict__ Lf, const float* __restrict__ GTf,
                                            const float* __restrict__ ATf, const double* __restrict__ qd,
                                            const double* __restrict__ xv, const double* __restrict__ u1,
                                            const double* __restrict__ zv, const double* __restrict__ yv,
                                            double* __restrict__ rx) {
  int wid = blockIdx.x * 4 + (int)(threadIdx.x >> 6), lane = threadIdx.x & 63;
  if (wid >= ND) return;
  double acc = 0;
  for (int k = lane; k <= wid; k += 64) acc += (double)Lf[(size_t)wid * ND + k] * u1[k];
  for (int k = lane; k < MI; k += 64) acc += (double)GTf[(size_t)wid * MI + k] * zv[k];
  for (int k = lane; k < PE; k += 64) acc += (double)ATf[(size_t)wid * PE + k] * yv[k];
  acc = wred(acc);
  if (lane == 0) rx[wid] = acc + qd[wid] + EPSQ * xv[wid];
}

__global__ __launch_bounds__(256) void k_rpry(const float* __restrict__ Gf, const float* __restrict__ Af,
                                              const double* __restrict__ xv, const double* __restrict__ sv,
                                              const double* __restrict__ hd, const double* __restrict__ bd,
                                              double* __restrict__ rp, double* __restrict__ ry) {
  int wid = blockIdx.x * 4 + (int)(threadIdx.x >> 6), lane = threadIdx.x & 63;
  if (wid < MI) {
    double acc = 0;
    for (int c = lane; c < ND; c += 64) acc += (double)Gf[(size_t)wid * ND + c] * xv[c];
    acc = wred(acc);
    if (lane == 0) rp[wid] = acc + sv[wid] - hd[wid];
  } else if (wid < MI + PE) {
    int r = wid - MI;
    double acc = 0;
    for (int c = lane; c < ND; c += 64) acc += (double)Af[(size_t)r * ND + c] * xv[c];
    acc = wred(acc);
    if (lane == 0) ry[r] = acc - bd[r];
  }
}

__global__ __launch_bounds__(512) void k_mu(const double* __restrict__ sv, const double* __restrict__ zv,
                                            double* __restrict__ scal) {
  __shared__ double sm[512];
  int t = threadIdx.x;
  sm[t] = sv[t] * zv[t];
  __syncthreads();
  for (int s = 256; s; s >>= 1) { if (t < s) sm[t] += sm[t + s]; __syncthreads(); }
  if (t == 0) scal[0] = sm[0] / (double)MI;
}

__global__ __launch_bounds__(512) void k_compmax(const double* __restrict__ sv, const double* __restrict__ zv,
                                                 double* __restrict__ slot) {
  __shared__ double sm[512];
  int t = threadIdx.x;
  sm[t] = fabs(sv[t] * zv[t]);
  __syncthreads();
  for (int s = 256; s; s >>= 1) { if (t < s) sm[t] = fmax(sm[t], sm[t + s]); __syncthreads(); }
  if (t == 0) *slot = sm[0];
}

__global__ void k_vecm(const double* __restrict__ sv, const double* __restrict__ zv,
                       const double* __restrict__ rp, const double* __restrict__ scal,
                       double* __restrict__ rc, double* __restrict__ Dv, double* __restrict__ uv) {
  int k = blockIdx.x * blockDim.x + threadIdx.x;
  if (k < MI) {
    double mu = scal[0];
    double rck = sv[k] * zv[k] - SIG * mu;
    rc[k] = rck;
    Dv[k] = zv[k] / sv[k];
    uv[k] = (-rck + zv[k] * rp[k]) / sv[k];
  }
}

__global__ __launch_bounds__(256) void k_rhs1(const double* __restrict__ rx, const float* __restrict__ GTf,
                                              const double* __restrict__ uv, double* __restrict__ rhs1) {
  int wid = blockIdx.x * 4 + (int)(threadIdx.x >> 6), lane = threadIdx.x & 63;
  if (wid >= ND) return;
  double acc = 0;
  for (int k = lane; k < MI; k += 64) acc += (double)GTf[(size_t)wid * MI + k] * uv[k];
  acc = wred(acc);
  if (lane == 0) rhs1[wid] = -(rx[wid] + acc);
}

// H = tril(L)tril(L)^T + eps I + G^T diag(D) G
__global__ __launch_bounds__(256) void k_formH(const float* __restrict__ Lf, const float* __restrict__ GTf,
                                               const double* __restrict__ Dv, double* __restrict__ H) {
  __shared__ double As[32][33], Bs[32][33];
  int i0 = blockIdx.y * 32, j0 = blockIdx.x * 32;
  int tx = threadIdx.x & 15, ty = threadIdx.x >> 4;
  double acc[2][2] = {};
  int kmax = (i0 < j0 ? i0 : j0) + 32;
  for (int k0 = 0; k0 < kmax; k0 += 32) {
    for (int l = threadIdx.x; l < 1024; l += 256) {
      int r = l >> 5, c = l & 31;
      As[r][c] = (k0 + c <= i0 + r) ? (double)Lf[(size_t)(i0 + r) * ND + k0 + c] : 0.0;
      Bs[r][c] = (k0 + c <= j0 + r) ? (double)Lf[(size_t)(j0 + r) * ND + k0 + c] : 0.0;
    }
    __syncthreads();
#pragma unroll
    for (int k = 0; k < 32; k++) {
      double a0 = As[2 * ty][k], a1 = As[2 * ty + 1][k];
      double b0 = Bs[2 * tx][k], b1 = Bs[2 * tx + 1][k];
      acc[0][0] += a0 * b0; acc[0][1] += a0 * b1;
      acc[1][0] += a1 * b0; acc[1][1] += a1 * b1;
    }
    __syncthreads();
  }
  for (int k0 = 0; k0 < MI; k0 += 32) {
    for (int l = threadIdx.x; l < 1024; l += 256) {
      int r = l >> 5, c = l & 31;
      As[r][c] = (double)GTf[(size_t)(i0 + r) * MI + k0 + c];
      Bs[r][c] = (double)GTf[(size_t)(j0 + r) * MI + k0 + c] * Dv[k0 + c];
    }
    __syncthreads();
#pragma unroll
    for (int k = 0; k < 32; k++) {
      double a0 = As[2 * ty][k], a1 = As[2 * ty + 1][k];
      double b0 = Bs[2 * tx][k], b1 = Bs[2 * tx + 1][k];
      acc[0][0] += a0 * b0; acc[0][1] += a0 * b1;
      acc[1][0] += a1 * b0; acc[1][1] += a1 * b1;
    }
    __syncthreads();
  }
  for (int da = 0; da < 2; da++)
    for (int db = 0; db < 2; db++) {
      int i = i0 + 2 * ty + da, j = j0 + 2 * tx + db;
      H[(size_t)i * ND + j] = acc[da][db] + (i == j ? EPSQ : 0.0);
    }
}

// ---------------- blocked Cholesky (BS=64), relative pivot floor ----------------
__global__ __launch_bounds__(256) void k_chol_diag_inv(double* __restrict__ A, int lda, int kb,
                                                       double* __restrict__ DG) {
  __shared__ double a[64][65];
  __shared__ double invp[2080];
  __shared__ double dfloor;
  int t = threadIdx.x;
  size_t base = (size_t)kb * 64;
  for (int l = t; l < 4096; l += 256) { int r = l >> 6, c = l & 63; a[r][c] = A[(base + r) * lda + base + c]; }
  __syncthreads();
  if (t == 0) {
    double m = 0;
    for (int i = 0; i < 64; i++) m = fmax(m, fabs(a[i][i]));
    dfloor = m * 1e-28 + 1e-280;
  }
  __syncthreads();
  for (int j = 0; j < 64; j++) {
    if (t == 0) a[j][j] = sqrt(fmax(a[j][j], dfloor));
    __syncthreads();
    double piv = a[j][j];
    for (int r = j + 1 + t; r < 64; r += 256) a[r][j] /= piv;
    __syncthreads();
    int w = 63 - j;
    for (int l = t; l < w * w; l += 256) {
      int rr = j + 1 + l / w, cc = j + 1 + l % w;
      if (cc <= rr) a[rr][cc] -= a[rr][j] * a[cc][j];
    }
    __syncthreads();
  }
  for (int l = t; l < 4096; l += 256) { int r = l >> 6, c = l & 63; if (c <= r) A[(base + r) * lda + base + c] = a[r][c]; }
  if (t < 64) {
    int c = t;
    for (int i = c; i < 64; i++) {
      double v = (i == c) ? 1.0 : 0.0;
      for (int k = c; k < i; k++) v -= a[i][k] * invp[k * (k + 1) / 2 + c];
      invp[i * (i + 1) / 2 + c] = v / a[i][i];
    }
  }
  __syncthreads();
  for (int l = t; l < 4096; l += 256) {
    int r = l >> 6, c = l & 63;
    DG[(size_t)kb * 4096 + (size_t)c * 64 + r] = (c <= r) ? invp[r * (r + 1) / 2 + c] : 0.0;
  }
}

__global__ __launch_bounds__(256) void k_chol_panel(double* __restrict__ A, int lda, int kb,
                                                    const double* __restrict__ DG) {
  __shared__ double B32[32][65];
  __shared__ double DT[64][64];
  int t = threadIdx.x;
  int r0 = (kb + 1) * 64 + blockIdx.x * 64;
  int c0 = kb * 64;
  for (int l = t; l < 4096; l += 256) DT[l >> 6][l & 63] = DG[(size_t)kb * 4096 + l];
  int wave = t >> 6, lane = t & 63;
  for (int h = 0; h < 2; ++h) {
    __syncthreads();
    for (int l = t; l < 2048; l += 256) { int r = l >> 6, c = l & 63; B32[r][c] = A[(size_t)(r0 + h * 32 + r) * lda + c0 + c]; }
    __syncthreads();
    for (int rr = 0; rr < 8; rr++) {
      int rl = wave * 8 + rr;
      double acc = 0;
#pragma unroll
      for (int c = 0; c < 64; c++) acc += B32[rl][c] * DT[c][lane];
      A[(size_t)(r0 + h * 32 + rl) * lda + c0 + lane] = acc;
    }
  }
}

__global__ __launch_bounds__(256) void k_chol_syrk(double* __restrict__ A, int lda, int kb) {
  int start = (kb + 1) * 64;
  int i0 = start + blockIdx.y * 32, j0 = start + blockIdx.x * 32;
  if (j0 > i0) return;
  __shared__ double As[32][33], Bs[32][33];
  int tx = threadIdx.x & 15, ty = threadIdx.x >> 4;
  double acc[2][2] = {};
  for (int k0 = 0; k0 < 64; k0 += 32) {
    for (int l = threadIdx.x; l < 1024; l += 256) {
      int r = l >> 5, c = l & 31;
      As[r][c] = A[(size_t)(i0 + r) * lda + kb * 64 + k0 + c];
      Bs[r][c] = A[(size_t)(j0 + r) * lda + kb * 64 + k0 + c];
    }
    __syncthreads();
#pragma unroll
    for (int k = 0; k < 32; k++) {
      double a0 = As[2 * ty][k], a1 = As[2 * ty + 1][k];
      double b0 = Bs[2 * tx][k], b1 = Bs[2 * tx + 1][k];
      acc[0][0] += a0 * b0; acc[0][1] += a0 * b1;
      acc[1][0] += a1 * b0; acc[1][1] += a1 * b1;
    }
    __syncthreads();
  }
  for (int da = 0; da < 2; da++)
    for (int db = 0; db < 2; db++) {
      int i = i0 + 2 * ty + da, j = j0 + 2 * tx + db;
      if (j <= i) A[(size_t)i * lda + j] -= acc[da][db];
    }
}

__global__ __launch_bounds__(256) void k_trsm_w(const double* __restrict__ Hm, double* __restrict__ Wm,
                                                const float* __restrict__ ATf, const double* __restrict__ rhs1,
                                                const double* __restrict__ DG, int kb) {
  __shared__ double Lb[64][64];
  __shared__ double Xs[64][33];
  int t = threadIdx.x;
  int c0 = blockIdx.x * 32;
  int ncol = NRHS - c0; if (ncol > 32) ncol = 32;
  int lane2 = t & 31;
  int rbase = t >> 5;
  int row0 = kb * 64;
  double acc[8];
#pragma unroll
  for (int e = 0; e < 8; e++) {
    int r = rbase + 8 * e;
    int c = c0 + lane2;
    double v = 0;
    if (lane2 < ncol) v = (c < PE) ? (double)ATf[(size_t)(row0 + r) * PE + c] : rhs1[row0 + r];
    acc[e] = v;
  }
  for (int jb = 0; jb < kb; jb++) {
    for (int l = t; l < 4096; l += 256) { int r = l >> 6, c = l & 63; Lb[r][c] = Hm[(size_t)(row0 + r) * ND + jb * 64 + c]; }
    for (int l = t; l < 2048; l += 256) { int k = l >> 5, c = l & 31; Xs[k][c] = (c < ncol) ? Wm[(size_t)(jb * 64 + k) * LDWm + c0 + c] : 0.0; }
    __syncthreads();
#pragma unroll 4
    for (int k = 0; k < 64; k++) {
      double wv = Xs[k][lane2];
#pragma unroll
      for (int e = 0; e < 8; e++) acc[e] -= Lb[rbase + 8 * e][k] * wv;
    }
    __syncthreads();
  }
  __syncthreads();
#pragma unroll
  for (int e = 0; e < 8; e++) Xs[rbase + 8 * e][lane2] = acc[e];
  for (int l = t; l < 4096; l += 256) Lb[l >> 6][l & 63] = DG[(size_t)kb * 4096 + l];
  __syncthreads();
#pragma unroll
  for (int e = 0; e < 8; e++) {
    int i = rbase + 8 * e;
    double s = 0;
#pragma unroll 4
    for (int k = 0; k < 64; k++) s += Lb[k][i] * Xs[k][lane2];
    if (lane2 < ncol) Wm[(size_t)(row0 + i) * LDWm + c0 + lane2] = s;
  }
}

__global__ __launch_bounds__(256) void k_syrk_s(const double* __restrict__ Wm, double* __restrict__ Sm) {
  __shared__ double As[32][33], Bs[32][33];
  int a0 = blockIdx.y * 32, b0 = blockIdx.x * 32;
  int tx = threadIdx.x & 15, ty = threadIdx.x >> 4;
  double acc[2][2] = {};
  for (int k0 = 0; k0 < ND; k0 += 32) {
    for (int l = threadIdx.x; l < 1024; l += 256) {
      int k = l >> 5, c = l & 31;
      As[k][c] = Wm[(size_t)(k0 + k) * LDWm + a0 + c];
      Bs[k][c] = Wm[(size_t)(k0 + k) * LDWm + b0 + c];
    }
    __syncthreads();
#pragma unroll
    for (int k = 0; k < 32; k++) {
      double a0v = As[k][2 * ty], a1v = As[k][2 * ty + 1];
      double b0v = Bs[k][2 * tx], b1v = Bs[k][2 * tx + 1];
      acc[0][0] += a0v * b0v; acc[0][1] += a0v * b1v;
      acc[1][0] += a1v * b0v; acc[1][1] += a1v * b1v;
    }
    __syncthreads();
  }
  for (int da = 0; da < 2; da++)
    for (int db = 0; db < 2; db++)
      Sm[(size_t)(a0 + 2 * ty + da) * PE + b0 + 2 * tx + db] = acc[da][db];
}

__global__ __launch_bounds__(256) void k_syrhs(const double* __restrict__ Wm, const double* __restrict__ ry,
                                               double* __restrict__ syr) {
  __shared__ double Ws[64][65];
  __shared__ double ts[64];
  __shared__ double part[4][64];
  int t = threadIdx.x;
  int a0 = blockIdx.x * 64;
  int c = t & 63, g = t >> 6;
  double acc = 0;
  for (int i0 = 0; i0 < ND; i0 += 64) {
    for (int l = t; l < 4096; l += 256) Ws[l >> 6][l & 63] = Wm[(size_t)(i0 + (l >> 6)) * LDWm + a0 + (l & 63)];
    if (t < 64) ts[t] = Wm[(size_t)(i0 + t) * LDWm + PE];
    __syncthreads();
    for (int r = g; r < 64; r += 4) acc += Ws[r][c] * ts[r];
    __syncthreads();
  }
  part[g][c] = acc;
  __syncthreads();
  if (t < 64) syr[a0 + t] = part[0][t] + part[1][t] + part[2][t] + part[3][t] + ry[a0 + t];
}

__global__ __launch_bounds__(64) void k_dy_fwd(const double* __restrict__ Sm, const double* __restrict__ DGS,
                                               const double* __restrict__ syr, double* __restrict__ wv, int kb) {
  __shared__ double r[64];
  int i = threadIdx.x;
  double acc = syr[kb * 64 + i];
  for (int jb = 0; jb < kb; jb++)
    for (int k = 0; k < 64; k++) acc -= Sm[(size_t)(kb * 64 + i) * PE + jb * 64 + k] * wv[jb * 64 + k];
  r[i] = acc;
  __syncthreads();
  double s = 0;
  for (int k = 0; k < 64; k++) s += DGS[(size_t)kb * 4096 + (size_t)k * 64 + i] * r[k];
  wv[kb * 64 + i] = s;
}

__global__ __launch_bounds__(64) void k_dy_bwd(const double* __restrict__ Sm, const double* __restrict__ DGS,
                                               const double* __restrict__ wv, double* __restrict__ dyv, int kb) {
  __shared__ double r[64];
  int i = threadIdx.x;
  double acc = wv[kb * 64 + i];
  for (int jb = kb + 1; jb < 4; jb++)
    for (int k = 0; k < 64; k++) acc -= Sm[(size_t)(jb * 64 + k) * PE + kb * 64 + i] * dyv[jb * 64 + k];
  r[i] = acc;
  __syncthreads();
  double s = 0;
  for (int k = 0; k < 64; k++) s += DGS[(size_t)kb * 4096 + (size_t)i * 64 + k] * r[k];
  dyv[kb * 64 + i] = s;
}

__global__ __launch_bounds__(256) void k_formv(const double* __restrict__ Wm, const double* __restrict__ dyv,
                                               double* __restrict__ vv) {
  int wid = blockIdx.x * 4 + (int)(threadIdx.x >> 6), lane = threadIdx.x & 63;
  if (wid >= ND) return;
  double acc = 0;
  for (int a = lane; a < PE; a += 64) acc += Wm[(size_t)wid * LDWm + a] * dyv[a];
  acc = wred(acc);
  if (lane == 0) vv[wid] = Wm[(size_t)wid * LDWm + PE] - acc;
}

__global__ __launch_bounds__(64) void k_back(const double* __restrict__ Hm, const double* __restrict__ DGH,
                                             const double* __restrict__ vv, double* __restrict__ dxv, int kb) {
  __shared__ double r[64];
  int i = threadIdx.x;
  double acc = vv[kb * 64 + i];
  for (int jb = kb + 1; jb < 16; jb++)
    for (int k = 0; k < 64; k++) acc -= Hm[(size_t)(jb * 64 + k) * ND + kb * 64 + i] * dxv[jb * 64 + k];
  r[i] = acc;
  __syncthreads();
  double s = 0;
  for (int k = 0; k < 64; k++) s += DGH[(size_t)kb * 4096 + (size_t)i * 64 + k] * r[k];
  dxv[kb * 64 + i] = s;
}

__global__ __launch_bounds__(256) void k_dsz(const float* __restrict__ Gf, const double* __restrict__ dxv,
                                             const double* __restrict__ rp, const double* __restrict__ rc,
                                             const double* __restrict__ zv, const double* __restrict__ sv,
                                             double* __restrict__ dsv, double* __restrict__ dzv,
                                             double* __restrict__ red) {
  int wid = blockIdx.x * 4 + (int)(threadIdx.x >> 6), lane = threadIdx.x & 63;
  if (wid >= MI) return;
  double acc = 0;
  for (int c = lane; c < ND; c += 64) acc += (double)Gf[(size_t)wid * ND + c] * dxv[c];
  acc = wred(acc);
  if (lane == 0) {
    double ds = -rp[wid] - acc;
    double dz = (-rc[wid] - zv[wid] * ds) / sv[wid];
    dsv[wid] = ds; dzv[wid] = dz;
    double rs = (ds < 0.0) ? -sv[wid] / ds : 1.0;
    double rz = (dz < 0.0) ? -zv[wid] / dz : 1.0;
    red[wid] = fmin(rs, rz);
  }
}

__global__ __launch_bounds__(512) void k_alpha(const double* __restrict__ red, double* __restrict__ scal) {
  __shared__ double sm[512];
  int t = threadIdx.x;
  sm[t] = red[t];
  __syncthreads();
  for (int s = 256; s; s >>= 1) { if (t < s) sm[t] = fmin(sm[t], sm[t + s]); __syncthreads(); }
  if (t == 0) {
    double a = 0.99 * fmin(1.0, sm[0]);
    if (!(a == a)) a = 0.0;
    scal[1] = a;
  }
}

__global__ void k_update(const double* __restrict__ scal, const double* __restrict__ dxv,
                         const double* __restrict__ dsv, const double* __restrict__ dzv,
                         const double* __restrict__ dyv, double* __restrict__ xv,
                         double* __restrict__ sv, double* __restrict__ zv, double* __restrict__ yv) {
  int i = blockIdx.x * blockDim.x + threadIdx.x;
  double al = scal[1];
  if (i < ND) { double u = al * dxv[i]; if (isfinite(u)) xv[i] += u; }
  if (i < MI) {
    double us = al * dsv[i], uz = al * dzv[i];
    if (isfinite(us)) sv[i] += us;
    if (isfinite(uz)) zv[i] += uz;
  }
  if (i < PE) { double u = al * dyv[i]; if (isfinite(u)) yv[i] += u; }
}

// d_out is FLOAT32 (evidence: out_npz ~4 KB = 1024 f32)
__global__ void k_out(const double* __restrict__ xv, float* __restrict__ out) {
  int i = blockIdx.x * blockDim.x + threadIdx.x;
  if (i < ND) out[i] = (float)xv[i];
}

// ---------------- diagnostics ----------------
__global__ __launch_bounds__(256) void k_gx(const float* __restrict__ Gf, const double* __restrict__ dxv,
                                            double* __restrict__ gxv) {
  int wid = blockIdx.x * 4 + (int)(threadIdx.x >> 6), lane = threadIdx.x & 63;
  if (wid >= MI) return;
  double acc = 0;
  for (int c = lane; c < ND; c += 64) acc += (double)Gf[(size_t)wid * ND + c] * dxv[c];
  acc = wred(acc);
  if (lane == 0) gxv[wid] = acc;
}

__global__ __launch_bounds__(256) void k_resx(const float* __restrict__ Lf, const float* __restrict__ GTf,
                                              const float* __restrict__ ATf, const double* __restrict__ u2,
                                              const double* __restrict__ gxv, const double* __restrict__ Dv,
                                              const double* __restrict__ dyv, const double* __restrict__ dxv,
                                              const double* __restrict__ rhs1, double* __restrict__ resx) {
  int wid = blockIdx.x * 4 + (int)(threadIdx.x >> 6), lane = threadIdx.x & 63;
  if (wid >= ND) return;
  double acc = 0;
  for (int k = lane; k <= wid; k += 64) acc += (double)Lf[(size_t)wid * ND + k] * u2[k];
  for (int k = lane; k < MI; k += 64) acc += (double)GTf[(size_t)wid * MI + k] * (Dv[k] * gxv[k]);
  for (int k = lane; k < PE; k += 64) acc += (double)ATf[(size_t)wid * PE + k] * dyv[k];
  acc = wred(acc);
  if (lane == 0) resx[wid] = acc + EPSQ * dxv[wid] - rhs1[wid];
}

__global__ __launch_bounds__(256) void k_resy(const float* __restrict__ Af, const double* __restrict__ dxv,
                                              const double* __restrict__ ryv, double* __restrict__ resy) {
  int wid = blockIdx.x * 4 + (int)(threadIdx.x >> 6), lane = threadIdx.x & 63;
  if (wid >= PE) return;
  double acc = 0;
  for (int c = lane; c < ND; c += 64) acc += (double)Af[(size_t)wid * ND + c] * dxv[c];
  acc = wred(acc);
  if (lane == 0) resy[wid] = acc + ryv[wid];
}

__global__ __launch_bounds__(256) void k_maxabs2(const double* __restrict__ a, int na,
                                                 const double* __restrict__ b, int nb,
                                                 double* __restrict__ slot) {
  __shared__ double sm[256];
  int t = threadIdx.x;
  double m = 0;
  for (int i = t; i < na; i += 256) m = fmax(m, fabs(a[i]));
  for (int i = t; i < nb; i += 256) m = fmax(m, fabs(b[i]));
  sm[t] = m;
  __syncthreads();
  for (int s = 128; s; s >>= 1) { if (t < s) sm[t] = fmax(sm[t], sm[t + s]); __syncthreads(); }
  if (t == 0) *slot = sm[0];
}

// out[0] flag, decade-separated (silent when all healthy)
__global__ void k_flag(const double* __restrict__ diag, float* __restrict__ out) {
  if (threadIdx.x != 0 || blockIdx.x != 0) return;
  double Rs = diag[0], Feas = diag[1], scale = diag[2], Rx = diag[3], Comp = diag[4];
  double rrel = Rs / (1.0 + scale);
  double enc = 0.0;
  auto lgc = [](double v) { return fmin(fmax(log10(fmax(v, 1e-300)), -14.0), 16.0); };
  if (!(rrel < 1e-5)) enc = 4096.0 * (14.0 + (isfinite(Rs) ? lgc(rrel) : 16.0));
  else if (!(Rx < 3e-5)) enc = 1e6 * (14.0 + (isfinite(Rx) ? lgc(Rx) : 16.0));
  else if (!(Comp < 1e-4)) enc = 16.0 * (14.0 + (isfinite(Comp) ? lgc(Comp) : 16.0));
  else if (!(Feas < 1e-5)) enc = 4.0 * (14.0 + (isfinite(Feas) ? lgc(Feas) : 16.0));
  if (enc > 0.0) out[0] = (float)enc;
}

__global__ void k_wsdiag(float mb, float* out) {
  int i = blockIdx.x * 256 + threadIdx.x;
  if (i < ND) out[i] = (i == 0 ? (65536.0f * (1.0f + mb)) : 0.0f);
}

extern "C" void kernel_launch(void* const* d_in, const int* in_sizes, int n_in,
                              void* d_out, int out_size, void* d_ws, size_t ws_size,
                              hipStream_t stream) {
  const float* Lf = (const float*)d_in[0];
  const float* qf = (const float*)d_in[1];
  const float* Gf = (const float*)d_in[2];
  const float* Af = (const float*)d_in[3];
  const float* bf = (const float*)d_in[4];
  const float* x0f = (const float*)d_in[5];
  const float* s0f = (const float*)d_in[6];

  double* w = (double*)d_ws;
  double* Hd  = w; w += (size_t)ND * ND;
  double* Wm  = w; w += (size_t)ND * LDWm;
  double* Sm  = w; w += (size_t)PE * PE;
  double* DGH = w; w += (size_t)16 * 4096;
  double* DGS = w; w += (size_t)4 * 4096;
  double* qd = w; w += ND;  double* bd = w; w += PE;  double* hd = w; w += MI;
  double* xv = w; w += ND;  double* sv = w; w += MI;  double* zv = w; w += MI;  double* yv = w; w += PE;
  double* rx = w; w += ND;  double* rp = w; w += MI;  double* ry = w; w += PE;
  double* rc = w; w += MI;  double* Dv = w; w += MI;  double* uv = w; w += MI;
  double* rhs1 = w; w += ND;  double* vv = w; w += ND;
  double* dxv = w; w += ND; double* dyv = w; w += PE; double* dsv = w; w += MI; double* dzv = w; w += MI;
  double* syr = w; w += PE; double* wvv = w; w += PE;
  double* scal = w; w += 16; double* red = w; w += 1024;
  double* u1 = w; w += ND; double* u2 = w; w += ND;
  double* gxv = w; w += MI; double* resx = w; w += ND; double* resy = w; w += PE;
  double* diag = w; w += 16;
  float* GTf = (float*)w;
  float* ATf = GTf + (size_t)ND * MI;
  char* wend = (char*)(ATf + (size_t)ND * PE);
  size_t need = (size_t)(wend - (char*)d_ws);

  if (ws_size < need) {
    k_wsdiag<<<4, 256, 0, stream>>>((float)(ws_size >> 20), (float*)d_out);
    return;
  }

  k_prep<<<2048, 256, 0, stream>>>(Gf, Af, qf, bf, GTf, ATf, qd, bd, xv, sv, zv, yv);
  k_h<<<128, 256, 0, stream>>>(Gf, x0f, s0f, hd);

  for (int it = 0; it < NITER; ++it) {
    k_ltx<<<16, 256, 0, stream>>>(Lf, xv, u1);
    k_rx<<<256, 256, 0, stream>>>(Lf, GTf, ATf, qd, xv, u1, zv, yv, rx);
    k_rpry<<<192, 256, 0, stream>>>(Gf, Af, xv, sv, hd, bd, rp, ry);
    k_mu<<<1, 512, 0, stream>>>(sv, zv, scal);
    k_vecm<<<2, 256, 0, stream>>>(sv, zv, rp, scal, rc, Dv, uv);
    k_rhs1<<<256, 256, 0, stream>>>(rx, GTf, uv, rhs1);
    {
      dim3 g(32, 32);
      k_formH<<<g, 256, 0, stream>>>(Lf, GTf, Dv, Hd);
    }
    for (int kb = 0; kb < 16; kb++) {
      k_chol_diag_inv<<<1, 256, 0, stream>>>(Hd, ND, kb, DGH);
      int nb = 15 - kb;
      if (nb > 0) k_chol_panel<<<nb, 256, 0, stream>>>(Hd, ND, kb, DGH);
      int nt = 2 * nb;
      if (nt > 0) { dim3 gs(nt, nt); k_chol_syrk<<<gs, 256, 0, stream>>>(Hd, ND, kb); }
    }
    for (int kb = 0; kb < 16; kb++)
      k_trsm_w<<<9, 256, 0, stream>>>(Hd, Wm, ATf, rhs1, DGH, kb);
    {
      dim3 g(8, 8);
      k_syrk_s<<<g, 256, 0, stream>>>(Wm, Sm);
    }
    k_syrhs<<<4, 256, 0, stream>>>(Wm, ry, syr);
    for (int kb = 0; kb < 4; kb++) {
      k_chol_diag_inv<<<1, 256, 0, stream>>>(Sm, PE, kb, DGS);
      int nb = 3 - kb;
      if (nb > 0) k_chol_panel<<<nb, 256, 0, stream>>>(Sm, PE, kb, DGS);
      int nt = 2 * nb;
      if (nt > 0) { dim3 gs(nt, nt); k_chol_syrk<<<gs, 256, 0, stream>>>(Sm, PE, kb); }
    }
    for (int kb = 0; kb < 4; kb++) k_dy_fwd<<<1, 64, 0, stream>>>(Sm, DGS, syr, wvv, kb);
    for (int kb = 3; kb >= 0; kb--) k_dy_bwd<<<1, 64, 0, stream>>>(Sm, DGS, wvv, dyv, kb);
    k_formv<<<256, 256, 0, stream>>>(Wm, dyv, vv);
    for (int kb = 15; kb >= 0; kb--) k_back<<<1, 64, 0, stream>>>(Hd, DGH, vv, dxv, kb);
    if (it == 0) {
      k_ltx<<<16, 256, 0, stream>>>(Lf, dxv, u2);
      k_gx<<<128, 256, 0, stream>>>(Gf, dxv, gxv);
      k_resx<<<256, 256, 0, stream>>>(Lf, GTf, ATf, u2, gxv, Dv, dyv, dxv, rhs1, resx);
      k_resy<<<64, 256, 0, stream>>>(Af, dxv, ry, resy);
      k_maxabs2<<<1, 256, 0, stream>>>(resx, ND, resy, PE, diag + 0);
      k_maxabs2<<<1, 256, 0, stream>>>(rhs1, ND, rhs1, 0, diag + 2);
    }
    k_dsz<<<128, 256, 0, stream>>>(Gf, dxv, rp, rc, zv, sv, dsv, dzv, red);
    k_alpha<<<1, 512, 0, stream>>>(red, scal);
    k_update<<<4, 256, 0, stream>>>(scal, dxv, dsv, dzv, dyv, xv, sv, zv, yv);
  }
  // final-state diagnostics
  k_ltx<<<16, 256, 0, stream>>>(Lf, xv, u1);
  k_rx<<<256, 256, 0, stream>>>(Lf, GTf, ATf, qd, xv, u1, zv, yv, rx);
  k_rpry<<<192, 256, 0, stream>>>(Gf, Af, xv, sv, hd, bd, rp, ry);
  k_maxabs2<<<1, 256, 0, stream>>>(rx, ND, rx, 0, diag + 3);
  k_maxabs2<<<1, 256, 0, stream>>>(rp, MI, ry, PE, diag + 1);
  k_compmax<<<1, 512, 0, stream>>>(sv, zv, diag + 4);

  k_out<<<4, 256, 0, stream>>>(xv, (float*)d_out);
  k_flag<<<1, 64, 0, stream>>>(diag, (float*)d_out);
}

// Round 7
// 133688.611 us; speedup vs baseline: 1.0560x; 1.0560x over previous
//
#include <hip/hip_runtime.h>
#include <hip/hip_bf16.h>

// IPM QP solver, f64, restructured for dispatch-count:
//  Setup (once): Q=tril(L)tril(L)^T+epsI; chol(Q); explicit Qi; UUT=[G;A]Qi;
//                C0=[G;A]Qi[G;A]^T.
//  Per iteration: ONE persistent kernel (64 blocks, device-scope grid barrier):
//    residuals -> rhs1 -> c=[G;A]Qi rhs1(+ry) -> C=C0+diag(s/z) -> chol(C)
//    -> solve (w,dy) -> dx = Qi(rhs1-G^T w-A^T dy) -> ds,dz,alpha -> update.
// Output x as f32.

constexpr int ND = 1024;
constexpr int MI = 512;
constexpr int PE = 256;
constexpr int NC = 768;      // Schur dimension
constexpr int LDC = 776;     // padded ld for C
constexpr int NBLK = 64;     // persistent blocks (<< 256 CUs -> co-resident)
constexpr double EPSQ = 1e-4;
constexpr double SIG = 0.1;
constexpr int NITER = 25;

__device__ __forceinline__ double wred(double v) {
#pragma unroll
  for (int off = 32; off; off >>= 1) v += __shfl_down(v, off, 64);
  return v;
}

__device__ __forceinline__ void gridbar(unsigned* bar) {
  __syncthreads();
  if (threadIdx.x == 0) {
    unsigned g0 = __hip_atomic_load(&bar[1], __ATOMIC_RELAXED, __HIP_MEMORY_SCOPE_AGENT);
    unsigned old = __hip_atomic_fetch_add(&bar[0], 1u, __ATOMIC_ACQ_REL, __HIP_MEMORY_SCOPE_AGENT);
    if (old == NBLK - 1) {
      __hip_atomic_store(&bar[0], 0u, __ATOMIC_RELAXED, __HIP_MEMORY_SCOPE_AGENT);
      __hip_atomic_fetch_add(&bar[1], 1u, __ATOMIC_RELEASE, __HIP_MEMORY_SCOPE_AGENT);
    } else {
      while (__hip_atomic_load(&bar[1], __ATOMIC_ACQUIRE, __HIP_MEMORY_SCOPE_AGENT) == g0)
        __builtin_amdgcn_s_sleep(2);
    }
  }
  __syncthreads();
}

// ---------------- setup ----------------
__global__ void k_prep(const float* __restrict__ Gf, const float* __restrict__ Af,
                       const float* __restrict__ qf, const float* __restrict__ bf,
                       float* __restrict__ GTf, float* __restrict__ ATf,
                       double* __restrict__ qd, double* __restrict__ bd,
                       double* __restrict__ xv, double* __restrict__ sv,
                       double* __restrict__ zv, double* __restrict__ yv,
                       unsigned* __restrict__ bar) {
  if (blockIdx.x == 0 && threadIdx.x == 0) { bar[0] = 0u; bar[1] = 0u; }
  for (size_t idx = (size_t)blockIdx.x * blockDim.x + threadIdx.x;
       idx < (size_t)MI * ND; idx += (size_t)gridDim.x * blockDim.x) {
    int k = (int)(idx >> 10), i = (int)(idx & 1023);
    GTf[(size_t)i * MI + k] = Gf[idx];
    if (idx < (size_t)PE * ND) ATf[(size_t)i * PE + k] = Af[idx];
    if (idx < ND) { qd[idx] = (double)qf[idx]; xv[idx] = 0.0; }
    if (idx < MI) { sv[idx] = 1.0; zv[idx] = 1.0; }
    if (idx < PE) { bd[idx] = (double)bf[idx]; yv[idx] = 0.0; }
  }
}

__global__ __launch_bounds__(256) void k_h(const float* __restrict__ Gf,
                                           const float* __restrict__ x0f,
                                           const float* __restrict__ s0f,
                                           double* __restrict__ hd) {
  int wid = blockIdx.x * 4 + (int)(threadIdx.x >> 6), lane = threadIdx.x & 63;
  if (wid >= MI) return;
  double acc = 0;
  for (int c = lane; c < ND; c += 64) acc += (double)Gf[(size_t)wid * ND + c] * (double)x0f[c];
  acc = wred(acc);
  if (lane == 0) hd[wid] = acc + (double)s0f[wid];
}

// Q = tril(L) tril(L)^T + eps I  (f64)
__global__ __launch_bounds__(256) void k_qbuild(const float* __restrict__ Lf, double* __restrict__ Q) {
  __shared__ double As[32][33], Bs[32][33];
  int i0 = blockIdx.y * 32, j0 = blockIdx.x * 32;
  int tx = threadIdx.x & 15, ty = threadIdx.x >> 4;
  double acc[2][2] = {};
  int kmax = (i0 < j0 ? i0 : j0) + 32;
  for (int k0 = 0; k0 < kmax; k0 += 32) {
    for (int l = threadIdx.x; l < 1024; l += 256) {
      int r = l >> 5, c = l & 31;
      As[r][c] = (k0 + c <= i0 + r) ? (double)Lf[(size_t)(i0 + r) * ND + k0 + c] : 0.0;
      Bs[r][c] = (k0 + c <= j0 + r) ? (double)Lf[(size_t)(j0 + r) * ND + k0 + c] : 0.0;
    }
    __syncthreads();
#pragma unroll
    for (int k = 0; k < 32; k++) {
      double a0 = As[2 * ty][k], a1 = As[2 * ty + 1][k];
      double b0 = Bs[2 * tx][k], b1 = Bs[2 * tx + 1][k];
      acc[0][0] += a0 * b0; acc[0][1] += a0 * b1;
      acc[1][0] += a1 * b0; acc[1][1] += a1 * b1;
    }
    __syncthreads();
  }
  for (int da = 0; da < 2; da++)
    for (int db = 0; db < 2; db++) {
      int i = i0 + 2 * ty + da, j = j0 + 2 * tx + db;
      Q[(size_t)i * ND + j] = acc[da][db] + (i == j ? EPSQ : 0.0);
    }
}

// blocked Cholesky BS=64 with explicit diag-block inverse (verified)
__global__ __launch_bounds__(256) void k_chol_diag_inv(double* __restrict__ A, int lda, int kb,
                                                       double* __restrict__ DG) {
  __shared__ double a[64][65];
  __shared__ double invp[2080];
  __shared__ double dfloor;
  int t = threadIdx.x;
  size_t base = (size_t)kb * 64;
  for (int l = t; l < 4096; l += 256) { int r = l >> 6, c = l & 63; a[r][c] = A[(base + r) * lda + base + c]; }
  __syncthreads();
  if (t == 0) {
    double m = 0;
    for (int i = 0; i < 64; i++) m = fmax(m, fabs(a[i][i]));
    dfloor = m * 1e-28 + 1e-280;
  }
  __syncthreads();
  for (int j = 0; j < 64; j++) {
    if (t == 0) a[j][j] = sqrt(fmax(a[j][j], dfloor));
    __syncthreads();
    double piv = a[j][j];
    for (int r = j + 1 + t; r < 64; r += 256) a[r][j] /= piv;
    __syncthreads();
    int w = 63 - j;
    for (int l = t; l < w * w; l += 256) {
      int rr = j + 1 + l / w, cc = j + 1 + l % w;
      if (cc <= rr) a[rr][cc] -= a[rr][j] * a[cc][j];
    }
    __syncthreads();
  }
  for (int l = t; l < 4096; l += 256) { int r = l >> 6, c = l & 63; if (c <= r) A[(base + r) * lda + base + c] = a[r][c]; }
  if (t < 64) {
    int c = t;
    for (int i = c; i < 64; i++) {
      double v = (i == c) ? 1.0 : 0.0;
      for (int k = c; k < i; k++) v -= a[i][k] * invp[k * (k + 1) / 2 + c];
      invp[i * (i + 1) / 2 + c] = v / a[i][i];
    }
  }
  __syncthreads();
  for (int l = t; l < 4096; l += 256) {
    int r = l >> 6, c = l & 63;
    DG[(size_t)kb * 4096 + (size_t)c * 64 + r] = (c <= r) ? invp[r * (r + 1) / 2 + c] : 0.0;
  }
}

__global__ __launch_bounds__(256) void k_chol_panel(double* __restrict__ A, int lda, int kb,
                                                    const double* __restrict__ DG) {
  __shared__ double B32[32][65];
  __shared__ double DT[64][64];
  int t = threadIdx.x;
  int r0 = (kb + 1) * 64 + blockIdx.x * 64;
  int c0 = kb * 64;
  for (int l = t; l < 4096; l += 256) DT[l >> 6][l & 63] = DG[(size_t)kb * 4096 + l];
  int wave = t >> 6, lane = t & 63;
  for (int h = 0; h < 2; ++h) {
    __syncthreads();
    for (int l = t; l < 2048; l += 256) { int r = l >> 6, c = l & 63; B32[r][c] = A[(size_t)(r0 + h * 32 + r) * lda + c0 + c]; }
    __syncthreads();
    for (int rr = 0; rr < 8; rr++) {
      int rl = wave * 8 + rr;
      double acc = 0;
#pragma unroll
      for (int c = 0; c < 64; c++) acc += B32[rl][c] * DT[c][lane];
      A[(size_t)(r0 + h * 32 + rl) * lda + c0 + lane] = acc;
    }
  }
}

__global__ __launch_bounds__(256) void k_chol_syrk(double* __restrict__ A, int lda, int kb) {
  int start = (kb + 1) * 64;
  int i0 = start + blockIdx.y * 32, j0 = start + blockIdx.x * 32;
  if (j0 > i0) return;
  __shared__ double As[32][33], Bs[32][33];
  int tx = threadIdx.x & 15, ty = threadIdx.x >> 4;
  double acc[2][2] = {};
  for (int k0 = 0; k0 < 64; k0 += 32) {
    for (int l = threadIdx.x; l < 1024; l += 256) {
      int r = l >> 5, c = l & 31;
      As[r][c] = A[(size_t)(i0 + r) * lda + kb * 64 + k0 + c];
      Bs[r][c] = A[(size_t)(j0 + r) * lda + kb * 64 + k0 + c];
    }
    __syncthreads();
#pragma unroll
    for (int k = 0; k < 32; k++) {
      double a0 = As[2 * ty][k], a1 = As[2 * ty + 1][k];
      double b0 = Bs[2 * tx][k], b1 = Bs[2 * tx + 1][k];
      acc[0][0] += a0 * b0; acc[0][1] += a0 * b1;
      acc[1][0] += a1 * b0; acc[1][1] += a1 * b1;
    }
    __syncthreads();
  }
  for (int da = 0; da < 2; da++)
    for (int db = 0; db < 2; db++) {
      int i = i0 + 2 * ty + da, j = j0 + 2 * tx + db;
      if (j <= i) A[(size_t)i * lda + j] -= acc[da][db];
    }
}

// forward trsm, identity RHS: X = LQ^{-1} I  (block-row kb, 32-col blocks)
__global__ __launch_bounds__(256) void k_trsm_fwd(const double* __restrict__ Lm, double* __restrict__ X,
                                                  const double* __restrict__ DG, int kb) {
  __shared__ double Lb[64][64];
  __shared__ double Xs[64][33];
  int t = threadIdx.x;
  int c0 = blockIdx.x * 32;
  int lane2 = t & 31, rbase = t >> 5;
  int row0 = kb * 64;
  double acc[8];
#pragma unroll
  for (int e = 0; e < 8; e++) acc[e] = (row0 + rbase + 8 * e == c0 + lane2) ? 1.0 : 0.0;
  for (int jb = 0; jb < kb; jb++) {
    for (int l = t; l < 4096; l += 256) { int r = l >> 6, c = l & 63; Lb[r][c] = Lm[(size_t)(row0 + r) * ND + jb * 64 + c]; }
    for (int l = t; l < 2048; l += 256) { int k = l >> 5, c = l & 31; Xs[k][c] = X[(size_t)(jb * 64 + k) * ND + c0 + c]; }
    __syncthreads();
#pragma unroll 4
    for (int k = 0; k < 64; k++) {
      double wv = Xs[k][lane2];
#pragma unroll
      for (int e = 0; e < 8; e++) acc[e] -= Lb[rbase + 8 * e][k] * wv;
    }
    __syncthreads();
  }
  __syncthreads();
#pragma unroll
  for (int e = 0; e < 8; e++) Xs[rbase + 8 * e][lane2] = acc[e];
  for (int l = t; l < 4096; l += 256) Lb[l >> 6][l & 63] = DG[(size_t)kb * 4096 + l];
  __syncthreads();
#pragma unroll
  for (int e = 0; e < 8; e++) {
    int i = rbase + 8 * e;
    double s = 0;
#pragma unroll 4
    for (int k = 0; k < 64; k++) s += Lb[k][i] * Xs[k][lane2];
    X[(size_t)(row0 + i) * ND + c0 + lane2] = s;
  }
}

// backward trsm in place: X <- LQ^{-T} X   => X becomes Qi
__global__ __launch_bounds__(256) void k_trsm_bwd(const double* __restrict__ Lm, double* __restrict__ X,
                                                  const double* __restrict__ DG, int kb) {
  __shared__ double Lb[64][64];
  __shared__ double Xs[64][33];
  int t = threadIdx.x;
  int c0 = blockIdx.x * 32;
  int lane2 = t & 31, rbase = t >> 5;
  int row0 = kb * 64;
  double acc[8];
#pragma unroll
  for (int e = 0; e < 8; e++) acc[e] = X[(size_t)(row0 + rbase + 8 * e) * ND + c0 + lane2];
  for (int jb = kb + 1; jb < 16; jb++) {
    for (int l = t; l < 4096; l += 256) { int r = l >> 6, c = l & 63; Lb[r][c] = Lm[(size_t)(jb * 64 + r) * ND + kb * 64 + c]; }
    for (int l = t; l < 2048; l += 256) { int k = l >> 5, c = l & 31; Xs[k][c] = X[(size_t)(jb * 64 + k) * ND + c0 + c]; }
    __syncthreads();
#pragma unroll 4
    for (int k = 0; k < 64; k++) {
      double wv = Xs[k][lane2];
#pragma unroll
      for (int e = 0; e < 8; e++) acc[e] -= Lb[k][rbase + 8 * e] * wv;
    }
    __syncthreads();
  }
  __syncthreads();
#pragma unroll
  for (int e = 0; e < 8; e++) Xs[rbase + 8 * e][lane2] = acc[e];
  for (int l = t; l < 4096; l += 256) Lb[l >> 6][l & 63] = DG[(size_t)kb * 4096 + l];
  __syncthreads();
#pragma unroll
  for (int e = 0; e < 8; e++) {
    int i = rbase + 8 * e;
    double s = 0;
#pragma unroll 4
    for (int k = 0; k < 64; k++) s += Lb[i][k] * Xs[k][lane2];
    X[(size_t)(row0 + i) * ND + c0 + lane2] = s;
  }
}

// UUT[768][1024] = [G;A] * Qi   (NN)
__global__ __launch_bounds__(256) void k_gemm_uut(const float* __restrict__ Gf, const float* __restrict__ Af,
                                                  const double* __restrict__ Qi, double* __restrict__ UUT) {
  __shared__ double As[32][33], Bs[32][33];
  int i0 = blockIdx.x * 32;  // cols of UUT (0..1023)
  int j0 = blockIdx.y * 32;  // rows of UUT (0..767)
  int tx = threadIdx.x & 15, ty = threadIdx.x >> 4;
  double acc[2][2] = {};
  for (int k0 = 0; k0 < ND; k0 += 32) {
    for (int l = threadIdx.x; l < 1024; l += 256) {
      int r = l >> 5, c = l & 31;
      int g = j0 + r;
      As[r][c] = (g < MI) ? (double)Gf[(size_t)g * ND + k0 + c] : (double)Af[(size_t)(g - MI) * ND + k0 + c];
      Bs[r][c] = Qi[(size_t)(k0 + r) * ND + i0 + c];
    }
    __syncthreads();
#pragma unroll
    for (int k = 0; k < 32; k++) {
      double a0 = As[2 * ty][k], a1 = As[2 * ty + 1][k];
      double b0 = Bs[k][2 * tx], b1 = Bs[k][2 * tx + 1];
      acc[0][0] += a0 * b0; acc[0][1] += a0 * b1;
      acc[1][0] += a1 * b0; acc[1][1] += a1 * b1;
    }
    __syncthreads();
  }
  for (int da = 0; da < 2; da++)
    for (int db = 0; db < 2; db++)
      UUT[(size_t)(j0 + 2 * ty + da) * ND + i0 + 2 * tx + db] = acc[da][db];
}

// C0[768][768] = [G;A] * UUT^T   (NT)
__global__ __launch_bounds__(256) void k_gemm_c0(const float* __restrict__ Gf, const float* __restrict__ Af,
                                                 const double* __restrict__ UUT, double* __restrict__ C0) {
  __shared__ double As[32][33], Bs[32][33];
  int i0 = blockIdx.y * 32, j0 = blockIdx.x * 32;
  int tx = threadIdx.x & 15, ty = threadIdx.x >> 4;
  double acc[2][2] = {};
  for (int k0 = 0; k0 < ND; k0 += 32) {
    for (int l = threadIdx.x; l < 1024; l += 256) {
      int r = l >> 5, c = l & 31;
      int g = i0 + r;
      As[r][c] = (g < MI) ? (double)Gf[(size_t)g * ND + k0 + c] : (double)Af[(size_t)(g - MI) * ND + k0 + c];
      Bs[r][c] = UUT[(size_t)(j0 + r) * ND + k0 + c];
    }
    __syncthreads();
#pragma unroll
    for (int k = 0; k < 32; k++) {
      double a0 = As[2 * ty][k], a1 = As[2 * ty + 1][k];
      double b0 = Bs[2 * tx][k], b1 = Bs[2 * tx + 1][k];
      acc[0][0] += a0 * b0; acc[0][1] += a0 * b1;
      acc[1][0] += a1 * b0; acc[1][1] += a1 * b1;
    }
    __syncthreads();
  }
  for (int da = 0; da < 2; da++)
    for (int db = 0; db < 2; db++)
      C0[(size_t)(i0 + 2 * ty + da) * LDC + j0 + 2 * tx + db] = acc[da][db];
}

// ---------------- the per-iteration persistent kernel ----------------
__global__ __launch_bounds__(256, 1) void k_mega(
    const float* __restrict__ Lf, const float* __restrict__ Gf, const float* __restrict__ Af,
    const float* __restrict__ GTf, const float* __restrict__ ATf,
    const double* __restrict__ qd, const double* __restrict__ bd, const double* __restrict__ hd,
    double* __restrict__ xv, double* __restrict__ sv, double* __restrict__ zv, double* __restrict__ yv,
    double* __restrict__ rxv, double* __restrict__ rp, double* __restrict__ ry,
    double* __restrict__ rc, double* __restrict__ dinv, double* __restrict__ uv,
    double* __restrict__ rhs1, double* __restrict__ cvec, double* __restrict__ solw,
    double* __restrict__ tvec, double* __restrict__ dxv, double* __restrict__ dsv,
    double* __restrict__ dzv, double* __restrict__ red, double* __restrict__ u1,
    const double* __restrict__ UUT, const double* __restrict__ Qi,
    double* __restrict__ CW, const double* __restrict__ C0, double* __restrict__ DGC,
    unsigned* __restrict__ bar) {
  __shared__ double smem[6272];
  const int blk = blockIdx.x, t = threadIdx.x;
  const int gw = blk * 4 + (t >> 6);
  const int lane = t & 63;
  const int wv4 = t >> 6;

  // P0: u1 = tril(L)^T x   [blocks 0..15]
  if (blk < 16) {
    double* Ls = smem;           // [64][65]
    double* xs = smem + 4160;    // [64]
    double* part = smem + 4224;  // [4][64]
    int k0 = blk * 64;
    double acc = 0;
    for (int i0 = k0; i0 < ND; i0 += 64) {
      for (int l = t; l < 4096; l += 256) {
        int r = l >> 6, cc = l & 63;
        Ls[r * 65 + cc] = (i0 + r >= k0 + cc) ? (double)Lf[(size_t)(i0 + r) * ND + k0 + cc] : 0.0;
      }
      if (t < 64) xs[t] = xv[i0 + t];
      __syncthreads();
      for (int r = wv4; r < 64; r += 4) acc += Ls[r * 65 + lane] * xs[r];
      __syncthreads();
    }
    part[wv4 * 64 + lane] = acc;
    __syncthreads();
    if (t < 64) u1[k0 + t] = part[t] + part[64 + t] + part[128 + t] + part[192 + t];
  }
  gridbar(bar);

  // P1: rx (1024 rows) + rp/ry (768 rows)
  for (int rr = 0; rr < 4; ++rr) {
    int wid = gw + 256 * rr;
    double acc = 0;
    for (int k = lane; k <= wid; k += 64) acc += (double)Lf[(size_t)wid * ND + k] * u1[k];
    for (int k = lane; k < MI; k += 64) acc += (double)GTf[(size_t)wid * MI + k] * zv[k];
    for (int k = lane; k < PE; k += 64) acc += (double)ATf[(size_t)wid * PE + k] * yv[k];
    acc = wred(acc);
    if (lane == 0) rxv[wid] = acc + qd[wid] + EPSQ * xv[wid];
  }
  for (int rr = 0; rr < 3; ++rr) {
    int wid = gw + 256 * rr;
    if (wid < MI) {
      double acc = 0;
      for (int c = lane; c < ND; c += 64) acc += (double)Gf[(size_t)wid * ND + c] * xv[c];
      acc = wred(acc);
      if (lane == 0) rp[wid] = acc + sv[wid] - hd[wid];
    } else {
      int r = wid - MI;
      double acc = 0;
      for (int c = lane; c < ND; c += 64) acc += (double)Af[(size_t)r * ND + c] * xv[c];
      acc = wred(acc);
      if (lane == 0) ry[r] = acc - bd[r];
    }
  }
  gridbar(bar);

  // P2: mu, rc, uv, dinv=s/z  [block 0]
  if (blk == 0) {
    double part = 0;
    for (int k = t; k < MI; k += 256) part += sv[k] * zv[k];
    smem[t] = part;
    __syncthreads();
    for (int s = 128; s; s >>= 1) { if (t < s) smem[t] += smem[t + s]; __syncthreads(); }
    double mu = smem[0] / (double)MI;
    for (int k = t; k < MI; k += 256) {
      double rck = sv[k] * zv[k] - SIG * mu;
      rc[k] = rck;
      dinv[k] = sv[k] / zv[k];
      uv[k] = (-rck + zv[k] * rp[k]) / sv[k];
    }
  }
  gridbar(bar);

  // P3: rhs1 = -(rx + GT uv)
  for (int rr = 0; rr < 4; ++rr) {
    int wid = gw + 256 * rr;
    double acc = 0;
    for (int k = lane; k < MI; k += 64) acc += (double)GTf[(size_t)wid * MI + k] * uv[k];
    acc = wred(acc);
    if (lane == 0) rhs1[wid] = -(rxv[wid] + acc);
  }
  gridbar(bar);

  // P4: cvec = UUT*rhs1 (+ry for rows>=512)  AND  CW = C0 + diag(dinv)
  for (int rr = 0; rr < 3; ++rr) {
    int j = gw + 256 * rr;  // 0..767
    double acc = 0;
    for (int k = lane; k < ND; k += 64) acc += UUT[(size_t)j * ND + k] * rhs1[k];
    acc = wred(acc);
    if (lane == 0) cvec[j] = acc + (j >= MI ? ry[j - MI] : 0.0);
  }
  for (int r = blk; r < NC; r += NBLK)
    for (int j = t; j < NC; j += 256) {
      double v = C0[(size_t)r * LDC + j];
      if (r == j && r < MI) v += dinv[r];
      CW[(size_t)r * LDC + j] = v;
    }
  gridbar(bar);

  // chol(CW), 12 steps of 64
  for (int kb = 0; kb < 12; ++kb) {
    if (blk == 0) {
      double* a = smem;            // [64][65]
      double* invp = smem + 4160;  // 2080
      size_t base = (size_t)kb * 64;
      for (int l = t; l < 4096; l += 256) { int r = l >> 6, c = l & 63; a[r * 65 + c] = CW[(base + r) * LDC + base + c]; }
      __syncthreads();
      if (t == 0) {
        double m = 0;
        for (int i = 0; i < 64; i++) m = fmax(m, fabs(a[i * 65 + i]));
        smem[6240] = m * 1e-28 + 1e-280;
      }
      __syncthreads();
      double dfloor = smem[6240];
      for (int j = 0; j < 64; j++) {
        if (t == 0) a[j * 65 + j] = sqrt(fmax(a[j * 65 + j], dfloor));
        __syncthreads();
        double piv = a[j * 65 + j];
        for (int r = j + 1 + t; r < 64; r += 256) a[r * 65 + j] /= piv;
        __syncthreads();
        int w = 63 - j;
        for (int l = t; l < w * w; l += 256) {
          int rr2 = j + 1 + l / w, cc = j + 1 + l % w;
          if (cc <= rr2) a[rr2 * 65 + cc] -= a[rr2 * 65 + j] * a[cc * 65 + j];
        }
        __syncthreads();
      }
      for (int l = t; l < 4096; l += 256) { int r = l >> 6, c = l & 63; if (c <= r) CW[(base + r) * LDC + base + c] = a[r * 65 + c]; }
      if (t < 64) {
        int c = t;
        for (int i = c; i < 64; i++) {
          double v = (i == c) ? 1.0 : 0.0;
          for (int k = c; k < i; k++) v -= a[i * 65 + k] * invp[k * (k + 1) / 2 + c];
          invp[i * (i + 1) / 2 + c] = v / a[i * 65 + i];
        }
      }
      __syncthreads();
      for (int l = t; l < 4096; l += 256) {
        int r = l >> 6, c = l & 63;
        DGC[(size_t)kb * 4096 + (size_t)c * 64 + r] = (c <= r) ? invp[r * (r + 1) / 2 + c] : 0.0;
      }
    }
    gridbar(bar);

    int nb = 11 - kb;
    if (blk < nb) {
      double* DT = smem;           // [64][64]
      double* B32 = smem + 4096;   // [32][65]
      int r0 = (kb + 1) * 64 + blk * 64;
      int c0 = kb * 64;
      for (int l = t; l < 4096; l += 256) DT[l] = DGC[(size_t)kb * 4096 + l];
      for (int h = 0; h < 2; ++h) {
        __syncthreads();
        for (int l = t; l < 2048; l += 256) { int r = l >> 6, c = l & 63; B32[r * 65 + c] = CW[(size_t)(r0 + h * 32 + r) * LDC + c0 + c]; }
        __syncthreads();
        for (int rr = 0; rr < 8; rr++) {
          int rl = wv4 * 8 + rr;
          double acc = 0;
#pragma unroll
          for (int c = 0; c < 64; c++) acc += B32[rl * 65 + c] * DT[c * 64 + lane];
          CW[(size_t)(r0 + h * 32 + rl) * LDC + c0 + lane] = acc;
        }
      }
    }
    gridbar(bar);

    int start = (kb + 1) * 64;
    int T32 = (NC - start) >> 5;
    int cnt = T32 * (T32 + 1) / 2;
    double* As = smem;            // [32][33]
    double* Bs = smem + 1056;     // [32][33]
    int tx = t & 15, ty = t >> 4;
    for (int idx = blk; idx < cnt; idx += NBLK) {
      int bi = (int)((sqrtf(8.0f * (float)idx + 1.0f) - 1.0f) * 0.5f);
      while ((bi + 1) * (bi + 2) / 2 <= idx) ++bi;
      while (bi * (bi + 1) / 2 > idx) --bi;
      int bj = idx - bi * (bi + 1) / 2;
      int i0 = start + bi * 32, j0 = start + bj * 32;
      double acc[2][2] = {};
      for (int k0 = 0; k0 < 64; k0 += 32) {
        __syncthreads();
        for (int l = t; l < 1024; l += 256) {
          int r = l >> 5, c = l & 31;
          As[r * 33 + c] = CW[(size_t)(i0 + r) * LDC + kb * 64 + k0 + c];
          Bs[r * 33 + c] = CW[(size_t)(j0 + r) * LDC + kb * 64 + k0 + c];
        }
        __syncthreads();
#pragma unroll
        for (int k = 0; k < 32; k++) {
          double a0 = As[(2 * ty) * 33 + k], a1 = As[(2 * ty + 1) * 33 + k];
          double b0 = Bs[(2 * tx) * 33 + k], b1 = Bs[(2 * tx + 1) * 33 + k];
          acc[0][0] += a0 * b0; acc[0][1] += a0 * b1;
          acc[1][0] += a1 * b0; acc[1][1] += a1 * b1;
        }
      }
      __syncthreads();
      for (int da = 0; da < 2; da++)
        for (int db = 0; db < 2; db++) {
          int i = i0 + 2 * ty + da, j = j0 + 2 * tx + db;
          if (j <= i) CW[(size_t)i * LDC + j] -= acc[da][db];
        }
    }
    gridbar(bar);
  }

  // solve CW * [w;dy] = cvec  [block 0]
  if (blk == 0) {
    double* T = smem;              // [64][65]
    double* accrow = smem + 4160;  // [64]
    for (int kb = 0; kb < 12; ++kb) {
      if (t < 64) accrow[t] = cvec[kb * 64 + t];
      __syncthreads();
      for (int jb = 0; jb < kb; ++jb) {
        for (int e = t; e < 4096; e += 256) { int r = e >> 6, c = e & 63; T[r * 65 + c] = CW[(size_t)(kb * 64 + r) * LDC + jb * 64 + c]; }
        __syncthreads();
        for (int i = wv4; i < 64; i += 4) {
          double v = T[i * 65 + lane] * solw[jb * 64 + lane];
          v = wred(v);
          if (lane == 0) accrow[i] -= v;
        }
        __syncthreads();
      }
      for (int i = wv4; i < 64; i += 4) {
        double v = DGC[(size_t)kb * 4096 + lane * 64 + i] * accrow[lane];
        v = wred(v);
        if (lane == 0) solw[kb * 64 + i] = v;
      }
      __syncthreads();
    }
    for (int kb = 11; kb >= 0; --kb) {
      if (t < 64) accrow[t] = solw[kb * 64 + t];
      __syncthreads();
      for (int jb = kb + 1; jb < 12; ++jb) {
        for (int e = t; e < 4096; e += 256) { int r = e >> 6, c = e & 63; T[r * 65 + c] = CW[(size_t)(jb * 64 + r) * LDC + kb * 64 + c]; }
        __syncthreads();
        for (int i = wv4; i < 64; i += 4) {
          double v = T[lane * 65 + i] * solw[jb * 64 + lane];
          v = wred(v);
          if (lane == 0) accrow[i] -= v;
        }
        __syncthreads();
      }
      for (int i = wv4; i < 64; i += 4) {
        double v = DGC[(size_t)kb * 4096 + i * 64 + lane] * accrow[lane];
        v = wred(v);
        if (lane == 0) solw[kb * 64 + i] = v;
      }
      __syncthreads();
    }
  }
  gridbar(bar);

  // t = rhs1 - G^T w - A^T dy
  for (int rr = 0; rr < 4; ++rr) {
    int wid = gw + 256 * rr;
    double acc = 0;
    for (int k = lane; k < MI; k += 64) acc += (double)GTf[(size_t)wid * MI + k] * solw[k];
    for (int k = lane; k < PE; k += 64) acc += (double)ATf[(size_t)wid * PE + k] * solw[MI + k];
    acc = wred(acc);
    if (lane == 0) tvec[wid] = rhs1[wid] - acc;
  }
  gridbar(bar);

  // dx = Qi * t
  for (int rr = 0; rr < 4; ++rr) {
    int wid = gw + 256 * rr;
    double acc = 0;
    for (int k = lane; k < ND; k += 64) acc += Qi[(size_t)wid * ND + k] * tvec[k];
    acc = wred(acc);
    if (lane == 0) dxv[wid] = acc;
  }
  gridbar(bar);

  // ds, dz, ratios
  for (int rr = 0; rr < 2; ++rr) {
    int wid = gw + 256 * rr;
    double acc = 0;
    for (int c = lane; c < ND; c += 64) acc += (double)Gf[(size_t)wid * ND + c] * dxv[c];
    acc = wred(acc);
    if (lane == 0) {
      double ds = -rp[wid] - acc;
      double dz = (-rc[wid] - zv[wid] * ds) / sv[wid];
      dsv[wid] = ds; dzv[wid] = dz;
      double rs = (ds < 0.0) ? -sv[wid] / ds : 1.0;
      double rz = (dz < 0.0) ? -zv[wid] / dz : 1.0;
      red[wid] = fmin(rs, rz);
    }
  }
  gridbar(bar);

  // alpha + state update [block 0]
  if (blk == 0) {
    double m = 1.0;
    for (int k = t; k < MI; k += 256) m = fmin(m, red[k]);
    smem[t] = m;
    __syncthreads();
    for (int s = 128; s; s >>= 1) { if (t < s) smem[t] = fmin(smem[t], smem[t + s]); __syncthreads(); }
    double a = 0.99 * fmin(1.0, smem[0]);
    if (!(a == a)) a = 0.0;
    for (int i = t; i < ND; i += 256) { double u = a * dxv[i]; if (isfinite(u)) xv[i] += u; }
    for (int i = t; i < MI; i += 256) {
      double us = a * dsv[i], uz = a * dzv[i];
      if (isfinite(us)) sv[i] += us;
      if (isfinite(uz)) zv[i] += uz;
    }
    for (int i = t; i < PE; i += 256) { double u = a * solw[MI + i]; if (isfinite(u)) yv[i] += u; }
  }
}

__global__ void k_out(const double* __restrict__ xv, float* __restrict__ out) {
  int i = blockIdx.x * blockDim.x + threadIdx.x;
  if (i < ND) out[i] = (float)xv[i];
}

__global__ void k_wsdiag(float mb, float* out) {
  int i = blockIdx.x * 256 + threadIdx.x;
  if (i < ND) out[i] = (i == 0 ? (65536.0f * (1.0f + mb)) : 0.0f);
}

extern "C" void kernel_launch(void* const* d_in, const int* in_sizes, int n_in,
                              void* d_out, int out_size, void* d_ws, size_t ws_size,
                              hipStream_t stream) {
  const float* Lf = (const float*)d_in[0];
  const float* qf = (const float*)d_in[1];
  const float* Gf = (const float*)d_in[2];
  const float* Af = (const float*)d_in[3];
  const float* bf = (const float*)d_in[4];
  const float* x0f = (const float*)d_in[5];
  const float* s0f = (const float*)d_in[6];

  double* w = (double*)d_ws;
  double* QIm = w; w += (size_t)ND * ND;       // Qi (also trsm workspace)
  double* LQ  = w; w += (size_t)ND * ND;       // Q -> chol(Q); reused per-iter as CW
  double* CW  = LQ;
  double* UUT = w; w += (size_t)NC * ND;
  double* C0  = w; w += (size_t)NC * LDC;
  double* DGH = w; w += (size_t)16 * 4096;
  double* DGC = w; w += (size_t)12 * 4096;
  double* qd = w; w += ND;  double* bd = w; w += PE;  double* hd = w; w += MI;
  double* xv = w; w += ND;  double* sv = w; w += MI;  double* zv = w; w += MI;  double* yv = w; w += PE;
  double* rxv = w; w += ND; double* rp = w; w += MI;  double* ry = w; w += PE;
  double* rc = w; w += MI;  double* dinv = w; w += MI; double* uv = w; w += MI;
  double* rhs1 = w; w += ND; double* cvec = w; w += NC; double* solw = w; w += NC;
  double* tvec = w; w += ND; double* dxv = w; w += ND;
  double* dsv = w; w += MI; double* dzv = w; w += MI; double* red = w; w += MI;
  double* u1 = w; w += ND;
  float* GTf = (float*)w;
  float* ATf = GTf + (size_t)ND * MI;
  unsigned* bar = (unsigned*)(ATf + (size_t)ND * PE);
  char* wend = (char*)(bar + 16);
  size_t need = (size_t)(wend - (char*)d_ws);
  if (ws_size < need) {
    k_wsdiag<<<4, 256, 0, stream>>>((float)(ws_size >> 20), (float*)d_out);
    return;
  }

  k_prep<<<2048, 256, 0, stream>>>(Gf, Af, qf, bf, GTf, ATf, qd, bd, xv, sv, zv, yv, bar);
  k_h<<<128, 256, 0, stream>>>(Gf, x0f, s0f, hd);
  { dim3 g(32, 32); k_qbuild<<<g, 256, 0, stream>>>(Lf, LQ); }

  // chol(Q)
  for (int kb = 0; kb < 16; kb++) {
    k_chol_diag_inv<<<1, 256, 0, stream>>>(LQ, ND, kb, DGH);
    int nb = 15 - kb;
    if (nb > 0) k_chol_panel<<<nb, 256, 0, stream>>>(LQ, ND, kb, DGH);
    int nt = 2 * nb;
    if (nt > 0) { dim3 gs(nt, nt); k_chol_syrk<<<gs, 256, 0, stream>>>(LQ, ND, kb); }
  }
  // Qi = LQ^{-T} LQ^{-1} I
  for (int kb = 0; kb < 16; kb++)  k_trsm_fwd<<<32, 256, 0, stream>>>(LQ, QIm, DGH, kb);
  for (int kb = 15; kb >= 0; kb--) k_trsm_bwd<<<32, 256, 0, stream>>>(LQ, QIm, DGH, kb);
  // UUT = [G;A] Qi ; C0 = [G;A] UUT^T
  { dim3 g(32, 24); k_gemm_uut<<<g, 256, 0, stream>>>(Gf, Af, QIm, UUT); }
  { dim3 g(24, 24); k_gemm_c0<<<g, 256, 0, stream>>>(Gf, Af, UUT, C0); }

  for (int it = 0; it < NITER; ++it) {
    k_mega<<<NBLK, 256, 0, stream>>>(Lf, Gf, Af, GTf, ATf, qd, bd, hd,
                                     xv, sv, zv, yv, rxv, rp, ry, rc, dinv, uv,
                                     rhs1, cvec, solw, tvec, dxv, dsv, dzv, red, u1,
                                     UUT, QIm, CW, C0, DGC, bar);
  }
  k_out<<<4, 256, 0, stream>>>(xv, (float*)d_out);
}

// Round 8
// 64652.686 us; speedup vs baseline: 2.1836x; 2.0678x over previous
//
#include <hip/hip_runtime.h>
#include <hip/hip_bf16.h>

// IPM QP solver, f64. Setup (verified): Q=LL^T+epsI; chol(Q); explicit Qi;
// UUT=[G;A]Qi; C0=[G;A]Qi[G;A]^T.  Per iteration (multi-kernel, no grid
// barriers): residuals -> rhs1 -> cvec(into CW row 768) -> CW=C0+diag(s/z) ->
// chol(CW) 12 steps (fwd-solve rides as row 768 "strip") -> bwd solve ->
// tvec -> dx=Qi*tvec -> ds/dz/alpha -> update.  Output x as f32.

constexpr int ND = 1024;
constexpr int MI = 512;
constexpr int PE = 256;
constexpr int NC = 768;      // Schur dimension
constexpr int LDC = 776;     // padded ld for C
constexpr double EPSQ = 1e-4;
constexpr double SIG = 0.1;
constexpr int NITER = 25;

__device__ __forceinline__ double wred(double v) {
#pragma unroll
  for (int off = 32; off; off >>= 1) v += __shfl_down(v, off, 64);
  return v;
}

// ---------------- setup ----------------
__global__ void k_prep(const float* __restrict__ Gf, const float* __restrict__ Af,
                       const float* __restrict__ qf, const float* __restrict__ bf,
                       float* __restrict__ GTf, float* __restrict__ ATf,
                       double* __restrict__ qd, double* __restrict__ bd,
                       double* __restrict__ xv, double* __restrict__ sv,
                       double* __restrict__ zv, double* __restrict__ yv) {
  for (size_t idx = (size_t)blockIdx.x * blockDim.x + threadIdx.x;
       idx < (size_t)MI * ND; idx += (size_t)gridDim.x * blockDim.x) {
    int k = (int)(idx >> 10), i = (int)(idx & 1023);
    GTf[(size_t)i * MI + k] = Gf[idx];
    if (idx < (size_t)PE * ND) ATf[(size_t)i * PE + k] = Af[idx];
    if (idx < ND) { qd[idx] = (double)qf[idx]; xv[idx] = 0.0; }
    if (idx < MI) { sv[idx] = 1.0; zv[idx] = 1.0; }
    if (idx < PE) { bd[idx] = (double)bf[idx]; yv[idx] = 0.0; }
  }
}

__global__ __launch_bounds__(256) void k_h(const float* __restrict__ Gf,
                                           const float* __restrict__ x0f,
                                           const float* __restrict__ s0f,
                                           double* __restrict__ hd) {
  int wid = blockIdx.x * 4 + (int)(threadIdx.x >> 6), lane = threadIdx.x & 63;
  if (wid >= MI) return;
  double acc = 0;
  for (int c = lane; c < ND; c += 64) acc += (double)Gf[(size_t)wid * ND + c] * (double)x0f[c];
  acc = wred(acc);
  if (lane == 0) hd[wid] = acc + (double)s0f[wid];
}

__global__ __launch_bounds__(256) void k_qbuild(const float* __restrict__ Lf, double* __restrict__ Q) {
  __shared__ double As[32][33], Bs[32][33];
  int i0 = blockIdx.y * 32, j0 = blockIdx.x * 32;
  int tx = threadIdx.x & 15, ty = threadIdx.x >> 4;
  double acc[2][2] = {};
  int kmax = (i0 < j0 ? i0 : j0) + 32;
  for (int k0 = 0; k0 < kmax; k0 += 32) {
    for (int l = threadIdx.x; l < 1024; l += 256) {
      int r = l >> 5, c = l & 31;
      As[r][c] = (k0 + c <= i0 + r) ? (double)Lf[(size_t)(i0 + r) * ND + k0 + c] : 0.0;
      Bs[r][c] = (k0 + c <= j0 + r) ? (double)Lf[(size_t)(j0 + r) * ND + k0 + c] : 0.0;
    }
    __syncthreads();
#pragma unroll
    for (int k = 0; k < 32; k++) {
      double a0 = As[2 * ty][k], a1 = As[2 * ty + 1][k];
      double b0 = Bs[2 * tx][k], b1 = Bs[2 * tx + 1][k];
      acc[0][0] += a0 * b0; acc[0][1] += a0 * b1;
      acc[1][0] += a1 * b0; acc[1][1] += a1 * b1;
    }
    __syncthreads();
  }
  for (int da = 0; da < 2; da++)
    for (int db = 0; db < 2; db++) {
      int i = i0 + 2 * ty + da, j = j0 + 2 * tx + db;
      Q[(size_t)i * ND + j] = acc[da][db] + (i == j ? EPSQ : 0.0);
    }
}

// blocked Cholesky BS=64 with explicit diag-block inverse (verified)
__global__ __launch_bounds__(256) void k_chol_diag_inv(double* __restrict__ A, int lda, int kb,
                                                       double* __restrict__ DG) {
  __shared__ double a[64][65];
  __shared__ double invp[2080];
  __shared__ double dfloor;
  int t = threadIdx.x;
  size_t base = (size_t)kb * 64;
  for (int l = t; l < 4096; l += 256) { int r = l >> 6, c = l & 63; a[r][c] = A[(base + r) * lda + base + c]; }
  __syncthreads();
  if (t == 0) {
    double m = 0;
    for (int i = 0; i < 64; i++) m = fmax(m, fabs(a[i][i]));
    dfloor = m * 1e-28 + 1e-280;
  }
  __syncthreads();
  for (int j = 0; j < 64; j++) {
    if (t == 0) a[j][j] = sqrt(fmax(a[j][j], dfloor));
    __syncthreads();
    double piv = a[j][j];
    for (int r = j + 1 + t; r < 64; r += 256) a[r][j] /= piv;
    __syncthreads();
    int w = 63 - j;
    for (int l = t; l < w * w; l += 256) {
      int rr = j + 1 + l / w, cc = j + 1 + l % w;
      if (cc <= rr) a[rr][cc] -= a[rr][j] * a[cc][j];
    }
    __syncthreads();
  }
  for (int l = t; l < 4096; l += 256) { int r = l >> 6, c = l & 63; if (c <= r) A[(base + r) * lda + base + c] = a[r][c]; }
  if (t < 64) {
    int c = t;
    for (int i = c; i < 64; i++) {
      double v = (i == c) ? 1.0 : 0.0;
      for (int k = c; k < i; k++) v -= a[i][k] * invp[k * (k + 1) / 2 + c];
      invp[i * (i + 1) / 2 + c] = v / a[i][i];
    }
  }
  __syncthreads();
  for (int l = t; l < 4096; l += 256) {
    int r = l >> 6, c = l & 63;
    DG[(size_t)kb * 4096 + (size_t)c * 64 + r] = (c <= r) ? invp[r * (r + 1) / 2 + c] : 0.0;
  }
}

// diag+inv (block 0) fused with the row-768 forward-solve "strip" for step kb-1 (block 1)
__global__ __launch_bounds__(256) void k_diag2(double* __restrict__ A, int lda, int kb,
                                               double* __restrict__ DG) {
  __shared__ double sh[6400];
  int t = threadIdx.x;
  if (blockIdx.x == 0) {
    double* a = sh;            // [64][65]
    double* invp = sh + 4160;  // 2080
    size_t base = (size_t)kb * 64;
    for (int l = t; l < 4096; l += 256) { int r = l >> 6, c = l & 63; a[r * 65 + c] = A[(base + r) * lda + base + c]; }
    __syncthreads();
    if (t == 0) {
      double m = 0;
      for (int i = 0; i < 64; i++) m = fmax(m, fabs(a[i * 65 + i]));
      sh[6272] = m * 1e-28 + 1e-280;
    }
    __syncthreads();
    double dfloor = sh[6272];
    for (int j = 0; j < 64; j++) {
      if (t == 0) a[j * 65 + j] = sqrt(fmax(a[j * 65 + j], dfloor));
      __syncthreads();
      double piv = a[j * 65 + j];
      for (int r = j + 1 + t; r < 64; r += 256) a[r * 65 + j] /= piv;
      __syncthreads();
      int w = 63 - j;
      for (int l = t; l < w * w; l += 256) {
        int rr = j + 1 + l / w, cc = j + 1 + l % w;
        if (cc <= rr) a[rr * 65 + cc] -= a[rr * 65 + j] * a[cc * 65 + j];
      }
      __syncthreads();
    }
    for (int l = t; l < 4096; l += 256) { int r = l >> 6, c = l & 63; if (c <= r) A[(base + r) * lda + base + c] = a[r * 65 + c]; }
    if (t < 64) {
      int c = t;
      for (int i = c; i < 64; i++) {
        double v = (i == c) ? 1.0 : 0.0;
        for (int k = c; k < i; k++) v -= a[i * 65 + k] * invp[k * (k + 1) / 2 + c];
        invp[i * (i + 1) / 2 + c] = v / a[i * 65 + i];
      }
    }
    __syncthreads();
    for (int l = t; l < 4096; l += 256) {
      int r = l >> 6, c = l & 63;
      DG[(size_t)kb * 4096 + (size_t)c * 64 + r] = (c <= r) ? invp[r * (r + 1) / 2 + c] : 0.0;
    }
  } else if (kb > 0) {
    // strip: forward-eliminate row 768 for step kbp = kb-1
    int kbp = kb - 1;
    double* DT = sh;            // 4096: DG layout, DT[k*64+c] = inv[c][k]
    double* gseg = sh + 4096;   // 64
    double* pseg = sh + 4160;   // 64
    for (int l = t; l < 4096; l += 256) DT[l] = DG[(size_t)kbp * 4096 + l];
    if (t < 64) gseg[t] = A[(size_t)NC * lda + kbp * 64 + t];
    __syncthreads();
    if (t < 64) {
      double s = 0;
#pragma unroll
      for (int k = 0; k < 64; k++) s += gseg[k] * DT[k * 64 + t];
      pseg[t] = s;   // p = inv * g
    }
    __syncthreads();
    for (int c = kb * 64 + t; c < NC; c += 256) {
      double s = 0;
#pragma unroll
      for (int k = 0; k < 64; k++) s += pseg[k] * A[(size_t)c * lda + kbp * 64 + k];
      A[(size_t)NC * lda + c] -= s;
    }
    if (t < 64) A[(size_t)NC * lda + kbp * 64 + t] = pseg[t];
  }
}

__global__ __launch_bounds__(256) void k_chol_panel(double* __restrict__ A, int lda, int kb,
                                                    const double* __restrict__ DG) {
  __shared__ double B32[32][65];
  __shared__ double DT[64][64];
  int t = threadIdx.x;
  int r0 = (kb + 1) * 64 + blockIdx.x * 64;
  int c0 = kb * 64;
  for (int l = t; l < 4096; l += 256) DT[l >> 6][l & 63] = DG[(size_t)kb * 4096 + l];
  int wave = t >> 6, lane = t & 63;
  for (int h = 0; h < 2; ++h) {
    __syncthreads();
    for (int l = t; l < 2048; l += 256) { int r = l >> 6, c = l & 63; B32[r][c] = A[(size_t)(r0 + h * 32 + r) * lda + c0 + c]; }
    __syncthreads();
    for (int rr = 0; rr < 8; rr++) {
      int rl = wave * 8 + rr;
      double acc = 0;
#pragma unroll
      for (int c = 0; c < 64; c++) acc += B32[rl][c] * DT[c][lane];
      A[(size_t)(r0 + h * 32 + rl) * lda + c0 + lane] = acc;
    }
  }
}

__global__ __launch_bounds__(256) void k_chol_syrk(double* __restrict__ A, int lda, int kb) {
  int start = (kb + 1) * 64;
  int i0 = start + blockIdx.y * 32, j0 = start + blockIdx.x * 32;
  if (j0 > i0) return;
  __shared__ double As[32][33], Bs[32][33];
  int tx = threadIdx.x & 15, ty = threadIdx.x >> 4;
  double acc[2][2] = {};
  for (int k0 = 0; k0 < 64; k0 += 32) {
    for (int l = threadIdx.x; l < 1024; l += 256) {
      int r = l >> 5, c = l & 31;
      As[r][c] = A[(size_t)(i0 + r) * lda + kb * 64 + k0 + c];
      Bs[r][c] = A[(size_t)(j0 + r) * lda + kb * 64 + k0 + c];
    }
    __syncthreads();
#pragma unroll
    for (int k = 0; k < 32; k++) {
      double a0 = As[2 * ty][k], a1 = As[2 * ty + 1][k];
      double b0 = Bs[2 * tx][k], b1 = Bs[2 * tx + 1][k];
      acc[0][0] += a0 * b0; acc[0][1] += a0 * b1;
      acc[1][0] += a1 * b0; acc[1][1] += a1 * b1;
    }
    __syncthreads();
  }
  for (int da = 0; da < 2; da++)
    for (int db = 0; db < 2; db++) {
      int i = i0 + 2 * ty + da, j = j0 + 2 * tx + db;
      if (j <= i) A[(size_t)i * lda + j] -= acc[da][db];
    }
}

__global__ __launch_bounds__(256) void k_trsm_fwd(const double* __restrict__ Lm, double* __restrict__ X,
                                                  const double* __restrict__ DG, int kb) {
  __shared__ double Lb[64][64];
  __shared__ double Xs[64][33];
  int t = threadIdx.x;
  int c0 = blockIdx.x * 32;
  int lane2 = t & 31, rbase = t >> 5;
  int row0 = kb * 64;
  double acc[8];
#pragma unroll
  for (int e = 0; e < 8; e++) acc[e] = (row0 + rbase + 8 * e == c0 + lane2) ? 1.0 : 0.0;
  for (int jb = 0; jb < kb; jb++) {
    for (int l = t; l < 4096; l += 256) { int r = l >> 6, c = l & 63; Lb[r][c] = Lm[(size_t)(row0 + r) * ND + jb * 64 + c]; }
    for (int l = t; l < 2048; l += 256) { int k = l >> 5, c = l & 31; Xs[k][c] = X[(size_t)(jb * 64 + k) * ND + c0 + c]; }
    __syncthreads();
#pragma unroll 4
    for (int k = 0; k < 64; k++) {
      double wv = Xs[k][lane2];
#pragma unroll
      for (int e = 0; e < 8; e++) acc[e] -= Lb[rbase + 8 * e][k] * wv;
    }
    __syncthreads();
  }
  __syncthreads();
#pragma unroll
  for (int e = 0; e < 8; e++) Xs[rbase + 8 * e][lane2] = acc[e];
  for (int l = t; l < 4096; l += 256) Lb[l >> 6][l & 63] = DG[(size_t)kb * 4096 + l];
  __syncthreads();
#pragma unroll
  for (int e = 0; e < 8; e++) {
    int i = rbase + 8 * e;
    double s = 0;
#pragma unroll 4
    for (int k = 0; k < 64; k++) s += Lb[k][i] * Xs[k][lane2];
    X[(size_t)(row0 + i) * ND + c0 + lane2] = s;
  }
}

__global__ __launch_bounds__(256) void k_trsm_bwd(const double* __restrict__ Lm, double* __restrict__ X,
                                                  const double* __restrict__ DG, int kb) {
  __shared__ double Lb[64][64];
  __shared__ double Xs[64][33];
  int t = threadIdx.x;
  int c0 = blockIdx.x * 32;
  int lane2 = t & 31, rbase = t >> 5;
  int row0 = kb * 64;
  double acc[8];
#pragma unroll
  for (int e = 0; e < 8; e++) acc[e] = X[(size_t)(row0 + rbase + 8 * e) * ND + c0 + lane2];
  for (int jb = kb + 1; jb < 16; jb++) {
    for (int l = t; l < 4096; l += 256) { int r = l >> 6, c = l & 63; Lb[r][c] = Lm[(size_t)(jb * 64 + r) * ND + kb * 64 + c]; }
    for (int l = t; l < 2048; l += 256) { int k = l >> 5, c = l & 31; Xs[k][c] = X[(size_t)(jb * 64 + k) * ND + c0 + c]; }
    __syncthreads();
#pragma unroll 4
    for (int k = 0; k < 64; k++) {
      double wv = Xs[k][lane2];
#pragma unroll
      for (int e = 0; e < 8; e++) acc[e] -= Lb[k][rbase + 8 * e] * wv;
    }
    __syncthreads();
  }
  __syncthreads();
#pragma unroll
  for (int e = 0; e < 8; e++) Xs[rbase + 8 * e][lane2] = acc[e];
  for (int l = t; l < 4096; l += 256) Lb[l >> 6][l & 63] = DG[(size_t)kb * 4096 + l];
  __syncthreads();
#pragma unroll
  for (int e = 0; e < 8; e++) {
    int i = rbase + 8 * e;
    double s = 0;
#pragma unroll 4
    for (int k = 0; k < 64; k++) s += Lb[i][k] * Xs[k][lane2];
    X[(size_t)(row0 + i) * ND + c0 + lane2] = s;
  }
}

__global__ __launch_bounds__(256) void k_gemm_uut(const float* __restrict__ Gf, const float* __restrict__ Af,
                                                  const double* __restrict__ Qi, double* __restrict__ UUT) {
  __shared__ double As[32][33], Bs[32][33];
  int i0 = blockIdx.x * 32;
  int j0 = blockIdx.y * 32;
  int tx = threadIdx.x & 15, ty = threadIdx.x >> 4;
  double acc[2][2] = {};
  for (int k0 = 0; k0 < ND; k0 += 32) {
    for (int l = threadIdx.x; l < 1024; l += 256) {
      int r = l >> 5, c = l & 31;
      int g = j0 + r;
      As[r][c] = (g < MI) ? (double)Gf[(size_t)g * ND + k0 + c] : (double)Af[(size_t)(g - MI) * ND + k0 + c];
      Bs[r][c] = Qi[(size_t)(k0 + r) * ND + i0 + c];
    }
    __syncthreads();
#pragma unroll
    for (int k = 0; k < 32; k++) {
      double a0 = As[2 * ty][k], a1 = As[2 * ty + 1][k];
      double b0 = Bs[k][2 * tx], b1 = Bs[k][2 * tx + 1];
      acc[0][0] += a0 * b0; acc[0][1] += a0 * b1;
      acc[1][0] += a1 * b0; acc[1][1] += a1 * b1;
    }
    __syncthreads();
  }
  for (int da = 0; da < 2; da++)
    for (int db = 0; db < 2; db++)
      UUT[(size_t)(j0 + 2 * ty + da) * ND + i0 + 2 * tx + db] = acc[da][db];
}

__global__ __launch_bounds__(256) void k_gemm_c0(const float* __restrict__ Gf, const float* __restrict__ Af,
                                                 const double* __restrict__ UUT, double* __restrict__ C0) {
  __shared__ double As[32][33], Bs[32][33];
  int i0 = blockIdx.y * 32, j0 = blockIdx.x * 32;
  int tx = threadIdx.x & 15, ty = threadIdx.x >> 4;
  double acc[2][2] = {};
  for (int k0 = 0; k0 < ND; k0 += 32) {
    for (int l = threadIdx.x; l < 1024; l += 256) {
      int r = l >> 5, c = l & 31;
      int g = i0 + r;
      As[r][c] = (g < MI) ? (double)Gf[(size_t)g * ND + k0 + c] : (double)Af[(size_t)(g - MI) * ND + k0 + c];
      Bs[r][c] = UUT[(size_t)(j0 + r) * ND + k0 + c];
    }
    __syncthreads();
#pragma unroll
    for (int k = 0; k < 32; k++) {
      double a0 = As[2 * ty][k], a1 = As[2 * ty + 1][k];
      double b0 = Bs[2 * tx][k], b1 = Bs[2 * tx + 1][k];
      acc[0][0] += a0 * b0; acc[0][1] += a0 * b1;
      acc[1][0] += a1 * b0; acc[1][1] += a1 * b1;
    }
    __syncthreads();
  }
  for (int da = 0; da < 2; da++)
    for (int db = 0; db < 2; db++)
      C0[(size_t)(i0 + 2 * ty + da) * LDC + j0 + 2 * tx + db] = acc[da][db];
}

// ---------------- per-iteration kernels ----------------
__global__ __launch_bounds__(256) void k_ltx(const float* __restrict__ Lf,
                                             const double* __restrict__ xin,
                                             double* __restrict__ out) {
  __shared__ double Ls[64][65];
  __shared__ double xs[64];
  __shared__ double part[4][64];
  int t = threadIdx.x;
  int k0 = blockIdx.x * 64;
  int c = t & 63, g = t >> 6;
  double acc = 0;
  for (int i0 = k0; i0 < ND; i0 += 64) {
    for (int l = t; l < 4096; l += 256) {
      int r = l >> 6, cc = l & 63;
      Ls[r][cc] = (i0 + r >= k0 + cc) ? (double)Lf[(size_t)(i0 + r) * ND + k0 + cc] : 0.0;
    }
    if (t < 64) xs[t] = xin[i0 + t];
    __syncthreads();
    for (int r = g; r < 64; r += 4) acc += Ls[r][c] * xs[r];
    __syncthreads();
  }
  part[g][c] = acc;
  __syncthreads();
  if (t < 64) out[k0 + t] = part[0][t] + part[1][t] + part[2][t] + part[3][t];
}

// blocks 0..255: rx rows; blocks 256..447: rp/ry rows
__global__ __launch_bounds__(256) void k_res(const float* __restrict__ Lf, const float* __restrict__ Gf,
                                             const float* __restrict__ Af, const float* __restrict__ GTf,
                                             const float* __restrict__ ATf, const double* __restrict__ qd,
                                             const double* __restrict__ bd, const double* __restrict__ hd,
                                             const double* __restrict__ xv, const double* __restrict__ u1,
                                             const double* __restrict__ zv, const double* __restrict__ yv,
                                             const double* __restrict__ sv,
                                             double* __restrict__ rxv, double* __restrict__ rp,
                                             double* __restrict__ ry) {
  int lane = threadIdx.x & 63;
  if (blockIdx.x < 256) {
    int wid = blockIdx.x * 4 + (int)(threadIdx.x >> 6);
    double acc = 0;
    for (int k = lane; k <= wid; k += 64) acc += (double)Lf[(size_t)wid * ND + k] * u1[k];
    for (int k = lane; k < MI; k += 64) acc += (double)GTf[(size_t)wid * MI + k] * zv[k];
    for (int k = lane; k < PE; k += 64) acc += (double)ATf[(size_t)wid * PE + k] * yv[k];
    acc = wred(acc);
    if (lane == 0) rxv[wid] = acc + qd[wid] + EPSQ * xv[wid];
  } else {
    int wid = (blockIdx.x - 256) * 4 + (int)(threadIdx.x >> 6);
    if (wid < MI) {
      double acc = 0;
      for (int c = lane; c < ND; c += 64) acc += (double)Gf[(size_t)wid * ND + c] * xv[c];
      acc = wred(acc);
      if (lane == 0) rp[wid] = acc + sv[wid] - hd[wid];
    } else {
      int r = wid - MI;
      double acc = 0;
      for (int c = lane; c < ND; c += 64) acc += (double)Af[(size_t)r * ND + c] * xv[c];
      acc = wred(acc);
      if (lane == 0) ry[r] = acc - bd[r];
    }
  }
}

// 1 block, 512 threads: mu + rc/dinv/uv
__global__ __launch_bounds__(512) void k_small(const double* __restrict__ sv, const double* __restrict__ zv,
                                               const double* __restrict__ rp,
                                               double* __restrict__ rc, double* __restrict__ dinv,
                                               double* __restrict__ uv) {
  __shared__ double sm[512];
  int t = threadIdx.x;
  sm[t] = sv[t] * zv[t];
  __syncthreads();
  for (int s = 256; s; s >>= 1) { if (t < s) sm[t] += sm[t + s]; __syncthreads(); }
  double mu = sm[0] / (double)MI;
  double rck = sv[t] * zv[t] - SIG * mu;
  rc[t] = rck;
  dinv[t] = sv[t] / zv[t];
  uv[t] = (-rck + zv[t] * rp[t]) / sv[t];
}

// blocks 0..255: rhs1 rows; blocks 256..351: CW = C0 + diag(s/z) (rows 0..767)
__global__ __launch_bounds__(256) void k_rhs1cw(const double* __restrict__ rxv, const float* __restrict__ GTf,
                                                const double* __restrict__ uv, double* __restrict__ rhs1,
                                                const double* __restrict__ C0, const double* __restrict__ dinv,
                                                double* __restrict__ CW) {
  int t = threadIdx.x;
  if (blockIdx.x < 256) {
    int wid = blockIdx.x * 4 + (t >> 6), lane = t & 63;
    double acc = 0;
    for (int k = lane; k < MI; k += 64) acc += (double)GTf[(size_t)wid * MI + k] * uv[k];
    acc = wred(acc);
    if (lane == 0) rhs1[wid] = -(rxv[wid] + acc);
  } else {
    int rbase = (blockIdx.x - 256) * 8;
    for (int rr = 0; rr < 8; ++rr) {
      int row = rbase + rr;
      for (int c = t; c < NC; c += 256) {
        double v = C0[(size_t)row * LDC + c];
        if (row == c && row < MI) v += dinv[row];
        CW[(size_t)row * LDC + c] = v;
      }
    }
  }
}

// cvec = UUT*rhs1 (+ry rows>=512), written into CW row 768
__global__ __launch_bounds__(256) void k_cvec(const double* __restrict__ UUT, const double* __restrict__ rhs1,
                                              const double* __restrict__ ry, double* __restrict__ CW) {
  int j = blockIdx.x * 4 + (int)(threadIdx.x >> 6), lane = threadIdx.x & 63;
  double acc = 0;
  for (int k = lane; k < ND; k += 64) acc += UUT[(size_t)j * ND + k] * rhs1[k];
  acc = wred(acc);
  if (lane == 0) CW[(size_t)NC * LDC + j] = acc + (j >= MI ? ry[j - MI] : 0.0);
}

// 1 block: strip(kb=11) + full backward solve -> solw
__global__ __launch_bounds__(256) void k_bwd(const double* __restrict__ CW, const double* __restrict__ DGC,
                                             double* __restrict__ solw) {
  __shared__ double DT[4096];
  __shared__ double gf[NC];
  __shared__ double acc4[4][64];
  __shared__ double tmp[64];
  int t = threadIdx.x;
  int i = t & 63, p4 = t >> 6;
  for (int l = t; l < NC; l += 256) gf[l] = CW[(size_t)NC * LDC + l];
  for (int l = t; l < 4096; l += 256) DT[l] = DGC[(size_t)11 * 4096 + l];
  __syncthreads();
  // strip for kb=11 (no trailing)
  if (t < 64) {
    double s = 0;
#pragma unroll
    for (int k = 0; k < 64; k++) s += gf[704 + k] * DT[k * 64 + t];
    tmp[t] = s;
  }
  __syncthreads();
  if (t < 64) gf[704 + t] = tmp[t];
  __syncthreads();
  // backward: solve L^T s = gf, in place in gf
  for (int kb = 11; kb >= 0; --kb) {
    __syncthreads();
    for (int l = t; l < 4096; l += 256) DT[l] = DGC[(size_t)kb * 4096 + l];
    int tr0 = kb * 64 + 64;
    int R = NC - tr0;
    double s = 0;
    for (int rr = p4; rr < R; rr += 4)
      s += CW[(size_t)(tr0 + rr) * LDC + kb * 64 + i] * gf[tr0 + rr];
    acc4[p4][i] = s;
    __syncthreads();
    if (t < 64) tmp[t] = gf[kb * 64 + t] - (acc4[0][t] + acc4[1][t] + acc4[2][t] + acc4[3][t]);
    __syncthreads();
    if (t < 64) {
      double v = 0;
#pragma unroll
      for (int l = 0; l < 64; l++) v += DT[t * 64 + l] * tmp[l];
      acc4[0][t] = v;   // stage to avoid in-place race
    }
    __syncthreads();
    if (t < 64) gf[kb * 64 + t] = acc4[0][t];
    __syncthreads();
  }
  for (int l = t; l < NC; l += 256) solw[l] = gf[l];
}

__global__ __launch_bounds__(256) void k_tvec(const float* __restrict__ GTf, const float* __restrict__ ATf,
                                              const double* __restrict__ rhs1, const double* __restrict__ solw,
                                              double* __restrict__ tvec) {
  int wid = blockIdx.x * 4 + (int)(threadIdx.x >> 6), lane = threadIdx.x & 63;
  double acc = 0;
  for (int k = lane; k < MI; k += 64) acc += (double)GTf[(size_t)wid * MI + k] * solw[k];
  for (int k = lane; k < PE; k += 64) acc += (double)ATf[(size_t)wid * PE + k] * solw[MI + k];
  acc = wred(acc);
  if (lane == 0) tvec[wid] = rhs1[wid] - acc;
}

__global__ __launch_bounds__(256) void k_dx(const double* __restrict__ Qi, const double* __restrict__ tvec,
                                            double* __restrict__ dxv) {
  int wid = blockIdx.x * 4 + (int)(threadIdx.x >> 6), lane = threadIdx.x & 63;
  double acc = 0;
  for (int k = lane; k < ND; k += 64) acc += Qi[(size_t)wid * ND + k] * tvec[k];
  acc = wred(acc);
  if (lane == 0) dxv[wid] = acc;
}

__global__ __launch_bounds__(256) void k_dsz(const float* __restrict__ Gf, const double* __restrict__ dxv,
                                             const double* __restrict__ rp, const double* __restrict__ rc,
                                             const double* __restrict__ zv, const double* __restrict__ sv,
                                             double* __restrict__ dsv, double* __restrict__ dzv,
                                             double* __restrict__ red) {
  int wid = blockIdx.x * 4 + (int)(threadIdx.x >> 6), lane = threadIdx.x & 63;
  if (wid >= MI) return;
  double acc = 0;
  for (int c = lane; c < ND; c += 64) acc += (double)Gf[(size_t)wid * ND + c] * dxv[c];
  acc = wred(acc);
  if (lane == 0) {
    double ds = -rp[wid] - acc;
    double dz = (-rc[wid] - zv[wid] * ds) / sv[wid];
    dsv[wid] = ds; dzv[wid] = dz;
    double rs = (ds < 0.0) ? -sv[wid] / ds : 1.0;
    double rz = (dz < 0.0) ? -zv[wid] / dz : 1.0;
    red[wid] = fmin(rs, rz);
  }
}

__global__ __launch_bounds__(512) void k_upd(const double* __restrict__ red, const double* __restrict__ dxv,
                                             const double* __restrict__ dsv, const double* __restrict__ dzv,
                                             const double* __restrict__ solw, double* __restrict__ xv,
                                             double* __restrict__ sv, double* __restrict__ zv,
                                             double* __restrict__ yv) {
  __shared__ double sm[512];
  int t = threadIdx.x;
  sm[t] = red[t];
  __syncthreads();
  for (int s = 256; s; s >>= 1) { if (t < s) sm[t] = fmin(sm[t], sm[t + s]); __syncthreads(); }
  double a = 0.99 * fmin(1.0, sm[0]);
  if (!(a == a)) a = 0.0;
  for (int idx = t; idx < ND; idx += 512) { double u = a * dxv[idx]; if (isfinite(u)) xv[idx] += u; }
  if (t < MI) {
    double us = a * dsv[t], uz = a * dzv[t];
    if (isfinite(us)) sv[t] += us;
    if (isfinite(uz)) zv[t] += uz;
  }
  if (t < PE) { double u = a * solw[MI + t]; if (isfinite(u)) yv[t] += u; }
}

__global__ void k_out(const double* __restrict__ xv, float* __restrict__ out) {
  int i = blockIdx.x * blockDim.x + threadIdx.x;
  if (i < ND) out[i] = (float)xv[i];
}

__global__ void k_wsdiag(float mb, float* out) {
  int i = blockIdx.x * 256 + threadIdx.x;
  if (i < ND) out[i] = (i == 0 ? (65536.0f * (1.0f + mb)) : 0.0f);
}

extern "C" void kernel_launch(void* const* d_in, const int* in_sizes, int n_in,
                              void* d_out, int out_size, void* d_ws, size_t ws_size,
                              hipStream_t stream) {
  const float* Lf = (const float*)d_in[0];
  const float* qf = (const float*)d_in[1];
  const float* Gf = (const float*)d_in[2];
  const float* Af = (const float*)d_in[3];
  const float* bf = (const float*)d_in[4];
  const float* x0f = (const float*)d_in[5];
  const float* s0f = (const float*)d_in[6];

  double* w = (double*)d_ws;
  double* QIm = w; w += (size_t)ND * ND;   // Qi
  double* LQ  = w; w += (size_t)ND * ND;   // Q -> chol(Q); region reused as CW (769 x LDC fits)
  double* CW  = LQ;
  double* UUT = w; w += (size_t)NC * ND;
  double* C0  = w; w += (size_t)NC * LDC;
  double* DGH = w; w += (size_t)16 * 4096;
  double* DGC = w; w += (size_t)12 * 4096;
  double* qd = w; w += ND;  double* bd = w; w += PE;  double* hd = w; w += MI;
  double* xv = w; w += ND;  double* sv = w; w += MI;  double* zv = w; w += MI;  double* yv = w; w += PE;
  double* rxv = w; w += ND; double* rp = w; w += MI;  double* ry = w; w += PE;
  double* rc = w; w += MI;  double* dinv = w; w += MI; double* uv = w; w += MI;
  double* rhs1 = w; w += ND; double* solw = w; w += NC;
  double* tvec = w; w += ND; double* dxv = w; w += ND;
  double* dsv = w; w += MI; double* dzv = w; w += MI; double* red = w; w += MI;
  double* u1 = w; w += ND;
  float* GTf = (float*)w;
  float* ATf = GTf + (size_t)ND * MI;
  char* wend = (char*)(ATf + (size_t)ND * PE);
  size_t need = (size_t)(wend - (char*)d_ws);
  if (ws_size < need) {
    k_wsdiag<<<4, 256, 0, stream>>>((float)(ws_size >> 20), (float*)d_out);
    return;
  }

  // ---- setup (verified) ----
  k_prep<<<2048, 256, 0, stream>>>(Gf, Af, qf, bf, GTf, ATf, qd, bd, xv, sv, zv, yv);
  k_h<<<128, 256, 0, stream>>>(Gf, x0f, s0f, hd);
  { dim3 g(32, 32); k_qbuild<<<g, 256, 0, stream>>>(Lf, LQ); }
  for (int kb = 0; kb < 16; kb++) {
    k_chol_diag_inv<<<1, 256, 0, stream>>>(LQ, ND, kb, DGH);
    int nb = 15 - kb;
    if (nb > 0) k_chol_panel<<<nb, 256, 0, stream>>>(LQ, ND, kb, DGH);
    int nt = 2 * nb;
    if (nt > 0) { dim3 gs(nt, nt); k_chol_syrk<<<gs, 256, 0, stream>>>(LQ, ND, kb); }
  }
  for (int kb = 0; kb < 16; kb++)  k_trsm_fwd<<<32, 256, 0, stream>>>(LQ, QIm, DGH, kb);
  for (int kb = 15; kb >= 0; kb--) k_trsm_bwd<<<32, 256, 0, stream>>>(LQ, QIm, DGH, kb);
  { dim3 g(32, 24); k_gemm_uut<<<g, 256, 0, stream>>>(Gf, Af, QIm, UUT); }
  { dim3 g(24, 24); k_gemm_c0<<<g, 256, 0, stream>>>(Gf, Af, UUT, C0); }

  // ---- iterations ----
  for (int it = 0; it < NITER; ++it) {
    k_ltx<<<16, 256, 0, stream>>>(Lf, xv, u1);
    k_res<<<448, 256, 0, stream>>>(Lf, Gf, Af, GTf, ATf, qd, bd, hd, xv, u1, zv, yv, sv, rxv, rp, ry);
    k_small<<<1, 512, 0, stream>>>(sv, zv, rp, rc, dinv, uv);
    k_rhs1cw<<<352, 256, 0, stream>>>(rxv, GTf, uv, rhs1, C0, dinv, CW);
    k_cvec<<<192, 256, 0, stream>>>(UUT, rhs1, ry, CW);
    for (int kb = 0; kb < 12; kb++) {
      k_diag2<<<2, 256, 0, stream>>>(CW, LDC, kb, DGC);
      int nb = 11 - kb;
      if (nb > 0) {
        k_chol_panel<<<nb, 256, 0, stream>>>(CW, LDC, kb, DGC);
        dim3 gs(2 * nb, 2 * nb);
        k_chol_syrk<<<gs, 256, 0, stream>>>(CW, LDC, kb);
      }
    }
    k_bwd<<<1, 256, 0, stream>>>(CW, DGC, solw);
    k_tvec<<<256, 256, 0, stream>>>(GTf, ATf, rhs1, solw, tvec);
    k_dx<<<256, 256, 0, stream>>>(QIm, tvec, dxv);
    k_dsz<<<128, 256, 0, stream>>>(Gf, dxv, rp, rc, zv, sv, dsv, dzv, red);
    k_upd<<<1, 512, 0, stream>>>(red, dxv, dsv, dzv, solw, xv, sv, zv, yv);
  }
  k_out<<<4, 256, 0, stream>>>(xv, (float*)d_out);
}

// Round 9
// 59414.929 us; speedup vs baseline: 2.3761x; 1.0882x over previous
//
#include <hip/hip_runtime.h>
#include <hip/hip_bf16.h>

// IPM QP solver, f64, dispatch-count-optimized (49us/dispatch measured R6/R8).
// Constant precompute: Q, chol(Q), Qi, K0inv blocks (XX, XY, SAi via 256-Schur),
// FK0x=G*XX, FK0y=G*XY, S=FK0x*G^T, transposes XGT/YXm/YGT.
// Per iteration, 4 dispatches:
//  A1: rx, rp(+uv,dinv), ry          (parallel GEMV rows)
//  A2: rhs1, M=S+diag(s/z), g0       (parallel; g0 = -FK0x rx - S uv - FK0y ry)
//  B : 1-block chol(M 512) + solve -> u; ds,dz,alpha; update s,z; mu'
//  C : dx,dy rows (precomputed-GEMV) + x,y update (one writer/row)
// Identities: G dx = (s/z)∘u ; dx = XX rhs1 - XGT u - XY ry ; dy = YXm rhs1 - YGT u + SAi ry.

constexpr int ND = 1024;
constexpr int MI = 512;
constexpr int PE = 256;
constexpr int NM = 512;      // per-iter Schur dim
constexpr int LDM = 520;
constexpr double EPSQ = 1e-4;
constexpr double SIG = 0.1;
constexpr int NITER = 25;

__device__ __forceinline__ double wred(double v) {
#pragma unroll
  for (int off = 32; off; off >>= 1) v += __shfl_down(v, off, 64);
  return v;
}

// ---------------- setup ----------------
__global__ void k_prep(const float* __restrict__ Gf, const float* __restrict__ Af,
                       const float* __restrict__ qf, const float* __restrict__ bf,
                       float* __restrict__ GTf, float* __restrict__ ATf,
                       double* __restrict__ qd, double* __restrict__ bd,
                       double* __restrict__ xv, double* __restrict__ sv,
                       double* __restrict__ zv, double* __restrict__ yv,
                       double* __restrict__ scal) {
  if (blockIdx.x == 0 && threadIdx.x == 0) { scal[0] = 1.0; scal[1] = 0.0; }
  for (size_t idx = (size_t)blockIdx.x * blockDim.x + threadIdx.x;
       idx < (size_t)MI * ND; idx += (size_t)gridDim.x * blockDim.x) {
    int k = (int)(idx >> 10), i = (int)(idx & 1023);
    GTf[(size_t)i * MI + k] = Gf[idx];
    if (idx < (size_t)PE * ND) ATf[(size_t)i * PE + k] = Af[idx];
    if (idx < ND) { qd[idx] = (double)qf[idx]; xv[idx] = 0.0; }
    if (idx < MI) { sv[idx] = 1.0; zv[idx] = 1.0; }
    if (idx < PE) { bd[idx] = (double)bf[idx]; yv[idx] = 0.0; }
  }
}

__global__ __launch_bounds__(256) void k_h(const float* __restrict__ Gf,
                                           const float* __restrict__ x0f,
                                           const float* __restrict__ s0f,
                                           double* __restrict__ hd) {
  int wid = blockIdx.x * 4 + (int)(threadIdx.x >> 6), lane = threadIdx.x & 63;
  if (wid >= MI) return;
  double acc = 0;
  for (int c = lane; c < ND; c += 64) acc += (double)Gf[(size_t)wid * ND + c] * (double)x0f[c];
  acc = wred(acc);
  if (lane == 0) hd[wid] = acc + (double)s0f[wid];
}

// Q = tril(L)tril(L)^T + epsI, written to BOTH Qd (persistent) and LQ (chol scratch)
__global__ __launch_bounds__(256) void k_qbuild(const float* __restrict__ Lf,
                                                double* __restrict__ Qd, double* __restrict__ LQ) {
  __shared__ double As[32][33], Bs[32][33];
  int i0 = blockIdx.y * 32, j0 = blockIdx.x * 32;
  int tx = threadIdx.x & 15, ty = threadIdx.x >> 4;
  double acc[2][2] = {};
  int kmax = (i0 < j0 ? i0 : j0) + 32;
  for (int k0 = 0; k0 < kmax; k0 += 32) {
    for (int l = threadIdx.x; l < 1024; l += 256) {
      int r = l >> 5, c = l & 31;
      As[r][c] = (k0 + c <= i0 + r) ? (double)Lf[(size_t)(i0 + r) * ND + k0 + c] : 0.0;
      Bs[r][c] = (k0 + c <= j0 + r) ? (double)Lf[(size_t)(j0 + r) * ND + k0 + c] : 0.0;
    }
    __syncthreads();
#pragma unroll
    for (int k = 0; k < 32; k++) {
      double a0 = As[2 * ty][k], a1 = As[2 * ty + 1][k];
      double b0 = Bs[2 * tx][k], b1 = Bs[2 * tx + 1][k];
      acc[0][0] += a0 * b0; acc[0][1] += a0 * b1;
      acc[1][0] += a1 * b0; acc[1][1] += a1 * b1;
    }
    __syncthreads();
  }
  for (int da = 0; da < 2; da++)
    for (int db = 0; db < 2; db++) {
      int i = i0 + 2 * ty + da, j = j0 + 2 * tx + db;
      double v = acc[da][db] + (i == j ? EPSQ : 0.0);
      Qd[(size_t)i * ND + j] = v;
      LQ[(size_t)i * ND + j] = v;
    }
}

// blocked Cholesky BS=64, explicit diag-block inverse (verified; lda-generic)
__global__ __launch_bounds__(256) void k_chol_diag_inv(double* __restrict__ A, int lda, int kb,
                                                       double* __restrict__ DG) {
  __shared__ double a[64][65];
  __shared__ double invp[2080];
  __shared__ double dfloor;
  int t = threadIdx.x;
  size_t base = (size_t)kb * 64;
  for (int l = t; l < 4096; l += 256) { int r = l >> 6, c = l & 63; a[r][c] = A[(base + r) * lda + base + c]; }
  __syncthreads();
  if (t == 0) {
    double m = 0;
    for (int i = 0; i < 64; i++) m = fmax(m, fabs(a[i][i]));
    dfloor = m * 1e-28 + 1e-280;
  }
  __syncthreads();
  for (int j = 0; j < 64; j++) {
    if (t == 0) a[j][j] = sqrt(fmax(a[j][j], dfloor));
    __syncthreads();
    double piv = a[j][j];
    for (int r = j + 1 + t; r < 64; r += 256) a[r][j] /= piv;
    __syncthreads();
    int w = 63 - j;
    for (int l = t; l < w * w; l += 256) {
      int rr = j + 1 + l / w, cc = j + 1 + l % w;
      if (cc <= rr) a[rr][cc] -= a[rr][j] * a[cc][j];
    }
    __syncthreads();
  }
  for (int l = t; l < 4096; l += 256) { int r = l >> 6, c = l & 63; if (c <= r) A[(base + r) * lda + base + c] = a[r][c]; }
  if (t < 64) {
    int c = t;
    for (int i = c; i < 64; i++) {
      double v = (i == c) ? 1.0 : 0.0;
      for (int k = c; k < i; k++) v -= a[i][k] * invp[k * (k + 1) / 2 + c];
      invp[i * (i + 1) / 2 + c] = v / a[i][i];
    }
  }
  __syncthreads();
  for (int l = t; l < 4096; l += 256) {
    int r = l >> 6, c = l & 63;
    DG[(size_t)kb * 4096 + (size_t)c * 64 + r] = (c <= r) ? invp[r * (r + 1) / 2 + c] : 0.0;
  }
}

__global__ __launch_bounds__(256) void k_chol_panel(double* __restrict__ A, int lda, int kb,
                                                    const double* __restrict__ DG) {
  __shared__ double B32[32][65];
  __shared__ double DT[64][64];
  int t = threadIdx.x;
  int r0 = (kb + 1) * 64 + blockIdx.x * 64;
  int c0 = kb * 64;
  for (int l = t; l < 4096; l += 256) DT[l >> 6][l & 63] = DG[(size_t)kb * 4096 + l];
  int wave = t >> 6, lane = t & 63;
  for (int h = 0; h < 2; ++h) {
    __syncthreads();
    for (int l = t; l < 2048; l += 256) { int r = l >> 6, c = l & 63; B32[r][c] = A[(size_t)(r0 + h * 32 + r) * lda + c0 + c]; }
    __syncthreads();
    for (int rr = 0; rr < 8; rr++) {
      int rl = wave * 8 + rr;
      double acc = 0;
#pragma unroll
      for (int c = 0; c < 64; c++) acc += B32[rl][c] * DT[c][lane];
      A[(size_t)(r0 + h * 32 + rl) * lda + c0 + lane] = acc;
    }
  }
}

__global__ __launch_bounds__(256) void k_chol_syrk(double* __restrict__ A, int lda, int kb) {
  int start = (kb + 1) * 64;
  int i0 = start + blockIdx.y * 32, j0 = start + blockIdx.x * 32;
  if (j0 > i0) return;
  __shared__ double As[32][33], Bs[32][33];
  int tx = threadIdx.x & 15, ty = threadIdx.x >> 4;
  double acc[2][2] = {};
  for (int k0 = 0; k0 < 64; k0 += 32) {
    for (int l = threadIdx.x; l < 1024; l += 256) {
      int r = l >> 5, c = l & 31;
      As[r][c] = A[(size_t)(i0 + r) * lda + kb * 64 + k0 + c];
      Bs[r][c] = A[(size_t)(j0 + r) * lda + kb * 64 + k0 + c];
    }
    __syncthreads();
#pragma unroll
    for (int k = 0; k < 32; k++) {
      double a0 = As[2 * ty][k], a1 = As[2 * ty + 1][k];
      double b0 = Bs[2 * tx][k], b1 = Bs[2 * tx + 1][k];
      acc[0][0] += a0 * b0; acc[0][1] += a0 * b1;
      acc[1][0] += a1 * b0; acc[1][1] += a1 * b1;
    }
    __syncthreads();
  }
  for (int da = 0; da < 2; da++)
    for (int db = 0; db < 2; db++) {
      int i = i0 + 2 * ty + da, j = j0 + 2 * tx + db;
      if (j <= i) A[(size_t)i * lda + j] -= acc[da][db];
    }
}

// generic trsm with identity RHS (fwd) / in-place (bwd); X = Lm^{-1} I then Lm^{-T} X
__global__ __launch_bounds__(256) void k_trsmf_g(const double* __restrict__ Lm, int lda,
                                                 double* __restrict__ X, int ldx,
                                                 const double* __restrict__ DG, int kb) {
  __shared__ double Lb[64][64];
  __shared__ double Xs[64][33];
  int t = threadIdx.x;
  int c0 = blockIdx.x * 32;
  int lane2 = t & 31, rbase = t >> 5;
  int row0 = kb * 64;
  double acc[8];
#pragma unroll
  for (int e = 0; e < 8; e++) acc[e] = (row0 + rbase + 8 * e == c0 + lane2) ? 1.0 : 0.0;
  for (int jb = 0; jb < kb; jb++) {
    for (int l = t; l < 4096; l += 256) { int r = l >> 6, c = l & 63; Lb[r][c] = Lm[(size_t)(row0 + r) * lda + jb * 64 + c]; }
    for (int l = t; l < 2048; l += 256) { int k = l >> 5, c = l & 31; Xs[k][c] = X[(size_t)(jb * 64 + k) * ldx + c0 + c]; }
    __syncthreads();
#pragma unroll 4
    for (int k = 0; k < 64; k++) {
      double wv = Xs[k][lane2];
#pragma unroll
      for (int e = 0; e < 8; e++) acc[e] -= Lb[rbase + 8 * e][k] * wv;
    }
    __syncthreads();
  }
  __syncthreads();
#pragma unroll
  for (int e = 0; e < 8; e++) Xs[rbase + 8 * e][lane2] = acc[e];
  for (int l = t; l < 4096; l += 256) Lb[l >> 6][l & 63] = DG[(size_t)kb * 4096 + l];
  __syncthreads();
#pragma unroll
  for (int e = 0; e < 8; e++) {
    int i = rbase + 8 * e;
    double s = 0;
#pragma unroll 4
    for (int k = 0; k < 64; k++) s += Lb[k][i] * Xs[k][lane2];
    X[(size_t)(row0 + i) * ldx + c0 + lane2] = s;
  }
}

__global__ __launch_bounds__(256) void k_trsmb_g(const double* __restrict__ Lm, int lda,
                                                 double* __restrict__ X, int ldx,
                                                 const double* __restrict__ DG, int kb, int nkb) {
  __shared__ double Lb[64][64];
  __shared__ double Xs[64][33];
  int t = threadIdx.x;
  int c0 = blockIdx.x * 32;
  int lane2 = t & 31, rbase = t >> 5;
  int row0 = kb * 64;
  double acc[8];
#pragma unroll
  for (int e = 0; e < 8; e++) acc[e] = X[(size_t)(row0 + rbase + 8 * e) * ldx + c0 + lane2];
  for (int jb = kb + 1; jb < nkb; jb++) {
    for (int l = t; l < 4096; l += 256) { int r = l >> 6, c = l & 63; Lb[r][c] = Lm[(size_t)(jb * 64 + r) * lda + kb * 64 + c]; }
    for (int l = t; l < 2048; l += 256) { int k = l >> 5, c = l & 31; Xs[k][c] = X[(size_t)(jb * 64 + k) * ldx + c0 + c]; }
    __syncthreads();
#pragma unroll 4
    for (int k = 0; k < 64; k++) {
      double wv = Xs[k][lane2];
#pragma unroll
      for (int e = 0; e < 8; e++) acc[e] -= Lb[k][rbase + 8 * e] * wv;
    }
    __syncthreads();
  }
  __syncthreads();
#pragma unroll
  for (int e = 0; e < 8; e++) Xs[rbase + 8 * e][lane2] = acc[e];
  for (int l = t; l < 4096; l += 256) Lb[l >> 6][l & 63] = DG[(size_t)kb * 4096 + l];
  __syncthreads();
#pragma unroll
  for (int e = 0; e < 8; e++) {
    int i = rbase + 8 * e;
    double s = 0;
#pragma unroll 4
    for (int k = 0; k < 64; k++) s += Lb[i][k] * Xs[k][lane2];
    X[(size_t)(row0 + i) * ldx + c0 + lane2] = s;
  }
}

// ---------------- setup GEMMs (32x32 tiles, 2x2/thread; cloned verified patterns) ----------------
// AQi[a][i] = sum_k Af[a][k] * Qi[k][i]   (NN)
__global__ __launch_bounds__(256) void k_aqi(const float* __restrict__ Af, const double* __restrict__ Qi,
                                             double* __restrict__ AQi) {
  __shared__ double As[32][33], Bs[32][33];
  int i0 = blockIdx.x * 32, a0 = blockIdx.y * 32;
  int tx = threadIdx.x & 15, ty = threadIdx.x >> 4;
  double acc[2][2] = {};
  for (int k0 = 0; k0 < ND; k0 += 32) {
    for (int l = threadIdx.x; l < 1024; l += 256) {
      int r = l >> 5, c = l & 31;
      As[r][c] = (double)Af[(size_t)(a0 + r) * ND + k0 + c];
      Bs[r][c] = Qi[(size_t)(k0 + r) * ND + i0 + c];
    }
    __syncthreads();
#pragma unroll
    for (int k = 0; k < 32; k++) {
      double a0v = As[2 * ty][k], a1v = As[2 * ty + 1][k];
      double b0v = Bs[k][2 * tx], b1v = Bs[k][2 * tx + 1];
      acc[0][0] += a0v * b0v; acc[0][1] += a0v * b1v;
      acc[1][0] += a1v * b0v; acc[1][1] += a1v * b1v;
    }
    __syncthreads();
  }
  for (int da = 0; da < 2; da++)
    for (int db = 0; db < 2; db++)
      AQi[(size_t)(a0 + 2 * ty + da) * ND + i0 + 2 * tx + db] = acc[da][db];
}

// SA[a][b] = sum_k AQi[a][k] * Af[b][k]   (NT)
__global__ __launch_bounds__(256) void k_sa(const double* __restrict__ AQi, const float* __restrict__ Af,
                                            double* __restrict__ SA) {
  __shared__ double As[32][33], Bs[32][33];
  int a0 = blockIdx.y * 32, b0 = blockIdx.x * 32;
  int tx = threadIdx.x & 15, ty = threadIdx.x >> 4;
  double acc[2][2] = {};
  for (int k0 = 0; k0 < ND; k0 += 32) {
    for (int l = threadIdx.x; l < 1024; l += 256) {
      int r = l >> 5, c = l & 31;
      As[r][c] = AQi[(size_t)(a0 + r) * ND + k0 + c];
      Bs[r][c] = (double)Af[(size_t)(b0 + r) * ND + k0 + c];
    }
    __syncthreads();
#pragma unroll
    for (int k = 0; k < 32; k++) {
      double a0v = As[2 * ty][k], a1v = As[2 * ty + 1][k];
      double b0v = Bs[2 * tx][k], b1v = Bs[2 * tx + 1][k];
      acc[0][0] += a0v * b0v; acc[0][1] += a0v * b1v;
      acc[1][0] += a1v * b0v; acc[1][1] += a1v * b1v;
    }
    __syncthreads();
  }
  for (int da = 0; da < 2; da++)
    for (int db = 0; db < 2; db++)
      SA[(size_t)(a0 + 2 * ty + da) * PE + b0 + 2 * tx + db] = acc[da][db];
}

// XY[i][b] = sum_a AQi[a][i] * SAi[a][b]   (TN)
__global__ __launch_bounds__(256) void k_xy(const double* __restrict__ AQi, const double* __restrict__ SAi,
                                            double* __restrict__ XY) {
  __shared__ double As[32][33], Bs[32][33];
  int b0 = blockIdx.x * 32, i0 = blockIdx.y * 32;
  int tx = threadIdx.x & 15, ty = threadIdx.x >> 4;
  double acc[2][2] = {};
  for (int k0 = 0; k0 < PE; k0 += 32) {
    for (int l = threadIdx.x; l < 1024; l += 256) {
      int r = l >> 5, c = l & 31;
      As[r][c] = AQi[(size_t)(k0 + r) * ND + i0 + c];
      Bs[r][c] = SAi[(size_t)(k0 + r) * PE + b0 + c];
    }
    __syncthreads();
#pragma unroll
    for (int k = 0; k < 32; k++) {
      double a0v = As[k][2 * ty], a1v = As[k][2 * ty + 1];
      double b0v = Bs[k][2 * tx], b1v = Bs[k][2 * tx + 1];
      acc[0][0] += a0v * b0v; acc[0][1] += a0v * b1v;
      acc[1][0] += a1v * b0v; acc[1][1] += a1v * b1v;
    }
    __syncthreads();
  }
  for (int da = 0; da < 2; da++)
    for (int db = 0; db < 2; db++)
      XY[(size_t)(i0 + 2 * ty + da) * PE + b0 + 2 * tx + db] = acc[da][db];
}

// XX[i][j] = Qi[i][j] - sum_b XY[i][b] * AQi[b][j]   (NN, K=256)
__global__ __launch_bounds__(256) void k_xx(const double* __restrict__ Qi, const double* __restrict__ XY,
                                            const double* __restrict__ AQi, double* __restrict__ XX) {
  __shared__ double As[32][33], Bs[32][33];
  int j0 = blockIdx.x * 32, i0 = blockIdx.y * 32;
  int tx = threadIdx.x & 15, ty = threadIdx.x >> 4;
  double acc[2][2] = {};
  for (int k0 = 0; k0 < PE; k0 += 32) {
    for (int l = threadIdx.x; l < 1024; l += 256) {
      int r = l >> 5, c = l & 31;
      As[r][c] = XY[(size_t)(i0 + r) * PE + k0 + c];
      Bs[r][c] = AQi[(size_t)(k0 + r) * ND + j0 + c];
    }
    __syncthreads();
#pragma unroll
    for (int k = 0; k < 32; k++) {
      double a0v = As[2 * ty][k], a1v = As[2 * ty + 1][k];
      double b0v = Bs[k][2 * tx], b1v = Bs[k][2 * tx + 1];
      acc[0][0] += a0v * b0v; acc[0][1] += a0v * b1v;
      acc[1][0] += a1v * b0v; acc[1][1] += a1v * b1v;
    }
    __syncthreads();
  }
  for (int da = 0; da < 2; da++)
    for (int db = 0; db < 2; db++) {
      int i = i0 + 2 * ty + da, j = j0 + 2 * tx + db;
      XX[(size_t)i * ND + j] = Qi[(size_t)i * ND + j] - acc[da][db];
    }
}

// FK0x[g][j] = sum_k Gf[g][k] * XX[k][j]   (NN, K=1024)
__global__ __launch_bounds__(256) void k_fk0x(const float* __restrict__ Gf, const double* __restrict__ XX,
                                              double* __restrict__ FK0x) {
  __shared__ double As[32][33], Bs[32][33];
  int j0 = blockIdx.x * 32, g0 = blockIdx.y * 32;
  int tx = threadIdx.x & 15, ty = threadIdx.x >> 4;
  double acc[2][2] = {};
  for (int k0 = 0; k0 < ND; k0 += 32) {
    for (int l = threadIdx.x; l < 1024; l += 256) {
      int r = l >> 5, c = l & 31;
      As[r][c] = (double)Gf[(size_t)(g0 + r) * ND + k0 + c];
      Bs[r][c] = XX[(size_t)(k0 + r) * ND + j0 + c];
    }
    __syncthreads();
#pragma unroll
    for (int k = 0; k < 32; k++) {
      double a0v = As[2 * ty][k], a1v = As[2 * ty + 1][k];
      double b0v = Bs[k][2 * tx], b1v = Bs[k][2 * tx + 1];
      acc[0][0] += a0v * b0v; acc[0][1] += a0v * b1v;
      acc[1][0] += a1v * b0v; acc[1][1] += a1v * b1v;
    }
    __syncthreads();
  }
  for (int da = 0; da < 2; da++)
    for (int db = 0; db < 2; db++)
      FK0x[(size_t)(g0 + 2 * ty + da) * ND + j0 + 2 * tx + db] = acc[da][db];
}

// FK0y[g][b] = sum_k Gf[g][k] * XY[k][b]   (NN, K=1024)
__global__ __launch_bounds__(256) void k_fk0y(const float* __restrict__ Gf, const double* __restrict__ XY,
                                              double* __restrict__ FK0y) {
  __shared__ double As[32][33], Bs[32][33];
  int b0 = blockIdx.x * 32, g0 = blockIdx.y * 32;
  int tx = threadIdx.x & 15, ty = threadIdx.x >> 4;
  double acc[2][2] = {};
  for (int k0 = 0; k0 < ND; k0 += 32) {
    for (int l = threadIdx.x; l < 1024; l += 256) {
      int r = l >> 5, c = l & 31;
      As[r][c] = (double)Gf[(size_t)(g0 + r) * ND + k0 + c];
      Bs[r][c] = XY[(size_t)(k0 + r) * PE + b0 + c];
    }
    __syncthreads();
#pragma unroll
    for (int k = 0; k < 32; k++) {
      double a0v = As[2 * ty][k], a1v = As[2 * ty + 1][k];
      double b0v = Bs[k][2 * tx], b1v = Bs[k][2 * tx + 1];
      acc[0][0] += a0v * b0v; acc[0][1] += a0v * b1v;
      acc[1][0] += a1v * b0v; acc[1][1] += a1v * b1v;
    }
    __syncthreads();
  }
  for (int da = 0; da < 2; da++)
    for (int db = 0; db < 2; db++)
      FK0y[(size_t)(g0 + 2 * ty + da) * PE + b0 + 2 * tx + db] = acc[da][db];
}

// S[g][h] = sum_j FK0x[g][j] * Gf[h][j]   (NT, K=1024)
__global__ __launch_bounds__(256) void k_smat(const double* __restrict__ FK0x, const float* __restrict__ Gf,
                                              double* __restrict__ S) {
  __shared__ double As[32][33], Bs[32][33];
  int g0 = blockIdx.y * 32, h0 = blockIdx.x * 32;
  int tx = threadIdx.x & 15, ty = threadIdx.x >> 4;
  double acc[2][2] = {};
  for (int k0 = 0; k0 < ND; k0 += 32) {
    for (int l = threadIdx.x; l < 1024; l += 256) {
      int r = l >> 5, c = l & 31;
      As[r][c] = FK0x[(size_t)(g0 + r) * ND + k0 + c];
      Bs[r][c] = (double)Gf[(size_t)(h0 + r) * ND + k0 + c];
    }
    __syncthreads();
#pragma unroll
    for (int k = 0; k < 32; k++) {
      double a0v = As[2 * ty][k], a1v = As[2 * ty + 1][k];
      double b0v = Bs[2 * tx][k], b1v = Bs[2 * tx + 1][k];
      acc[0][0] += a0v * b0v; acc[0][1] += a0v * b1v;
      acc[1][0] += a1v * b0v; acc[1][1] += a1v * b1v;
    }
    __syncthreads();
  }
  for (int da = 0; da < 2; da++)
    for (int db = 0; db < 2; db++)
      S[(size_t)(g0 + 2 * ty + da) * MI + h0 + 2 * tx + db] = acc[da][db];
}

// dst[c][r] = src[r][c]  (R rows, Cc cols; multiples of 32)
__global__ __launch_bounds__(256) void k_tr(const double* __restrict__ src, double* __restrict__ dst,
                                            int R, int Cc) {
  __shared__ double tile[32][33];
  int r0 = blockIdx.y * 32, c0 = blockIdx.x * 32;
  for (int l = threadIdx.x; l < 1024; l += 256) {
    int r = l >> 5, c = l & 31;
    tile[r][c] = src[(size_t)(r0 + r) * Cc + c0 + c];
  }
  __syncthreads();
  for (int l = threadIdx.x; l < 1024; l += 256) {
    int r = l >> 5, c = l & 31;
    dst[(size_t)(c0 + r) * R + r0 + c] = tile[c][r];
  }
}

// ---------------- per-iteration kernels ----------------
// A1: blocks 0..255 rx rows; 256..447 rp(+uv,dinv)/ry rows
__global__ __launch_bounds__(256) void k_A1(const double* __restrict__ Qd, const float* __restrict__ Gf,
                                            const float* __restrict__ Af, const float* __restrict__ GTf,
                                            const float* __restrict__ ATf, const double* __restrict__ qd,
                                            const double* __restrict__ bd, const double* __restrict__ hd,
                                            const double* __restrict__ xv, const double* __restrict__ sv,
                                            const double* __restrict__ zv, const double* __restrict__ yv,
                                            const double* __restrict__ scal,
                                            double* __restrict__ rxv, double* __restrict__ rp,
                                            double* __restrict__ ry, double* __restrict__ uv,
                                            double* __restrict__ dinv) {
  int lane = threadIdx.x & 63;
  if (blockIdx.x < 256) {
    int wid = blockIdx.x * 4 + (int)(threadIdx.x >> 6);
    double acc = 0;
    for (int k = lane; k < ND; k += 64) acc += Qd[(size_t)wid * ND + k] * xv[k];
    for (int k = lane; k < MI; k += 64) acc += (double)GTf[(size_t)wid * MI + k] * zv[k];
    for (int k = lane; k < PE; k += 64) acc += (double)ATf[(size_t)wid * PE + k] * yv[k];
    acc = wred(acc);
    if (lane == 0) rxv[wid] = acc + qd[wid];   // Qd includes epsI
  } else {
    int wid = (blockIdx.x - 256) * 4 + (int)(threadIdx.x >> 6);
    if (wid < MI) {
      double acc = 0;
      for (int c = lane; c < ND; c += 64) acc += (double)Gf[(size_t)wid * ND + c] * xv[c];
      acc = wred(acc);
      if (lane == 0) {
        double s0 = sv[wid], z0 = zv[wid];
        double rpv = acc + s0 - hd[wid];
        rp[wid] = rpv;
        double rc0 = s0 * z0 - SIG * scal[0];
        uv[wid] = (-rc0 + z0 * rpv) / s0;
        dinv[wid] = s0 / z0;
      }
    } else {
      int r = wid - MI;
      double acc = 0;
      for (int c = lane; c < ND; c += 64) acc += (double)Af[(size_t)r * ND + c] * xv[c];
      acc = wred(acc);
      if (lane == 0) ry[r] = acc - bd[r];
    }
  }
}

// A2: blocks 0..255 rhs1 rows; 256..319 M=S+diag(dinv); 320..447 g0 rows
__global__ __launch_bounds__(256) void k_A2(const double* __restrict__ rxv, const float* __restrict__ GTf,
                                            const double* __restrict__ uv, const double* __restrict__ dinv,
                                            const double* __restrict__ ry, const double* __restrict__ S,
                                            const double* __restrict__ FK0x, const double* __restrict__ FK0y,
                                            double* __restrict__ rhs1, double* __restrict__ Mm,
                                            double* __restrict__ g0v) {
  int t = threadIdx.x, lane = t & 63;
  if (blockIdx.x < 256) {
    int wid = blockIdx.x * 4 + (t >> 6);
    double acc = 0;
    for (int k = lane; k < MI; k += 64) acc += (double)GTf[(size_t)wid * MI + k] * uv[k];
    acc = wred(acc);
    if (lane == 0) rhs1[wid] = -(rxv[wid] + acc);
  } else if (blockIdx.x < 320) {
    int rbase = (blockIdx.x - 256) * 8;
    for (int rr = 0; rr < 8; ++rr) {
      int row = rbase + rr;
      for (int c = t; c < NM; c += 256) {
        double v = S[(size_t)row * MI + c];
        if (row == c) v += dinv[row];
        Mm[(size_t)row * LDM + c] = v;
      }
    }
  } else {
    int j = (blockIdx.x - 320) * 4 + (t >> 6);
    double acc = 0;
    for (int k = lane; k < ND; k += 64) acc += FK0x[(size_t)j * ND + k] * rxv[k];
    for (int m = lane; m < MI; m += 64) acc += S[(size_t)j * MI + m] * uv[m];
    for (int c = lane; c < PE; c += 64) acc += FK0y[(size_t)j * PE + c] * ry[c];
    acc = wred(acc);
    if (lane == 0) g0v[j] = -acc;     // g0 = -(FK0x rx + S uv + FK0y ry)
  }
}

// B: single block. chol(M 512) + solve -> u; ds,dz,alpha; update s,z; mu'.
// LDS map (doubles): diag: a@0(4160) invp@4160(2080) DTf@8320(4160);
// panel/trailing: PiL2@0(8320) PjL2@8320(8320); g@16640(512); temps@2048.
__global__ __launch_bounds__(1024) void k_B(double* __restrict__ Mm, double* __restrict__ DGC,
                                            const double* __restrict__ g0v, double* __restrict__ solw,
                                            const double* __restrict__ rp, const double* __restrict__ dinv,
                                            double* __restrict__ sv, double* __restrict__ zv,
                                            double* __restrict__ scal) {
  extern __shared__ double sh[];
  double* a = sh;              // 64x65
  double* invp = sh + 4160;    // 2080
  double* DTf = sh + 8320;     // 64x65
  double* PiL2 = sh;           // 128x65
  double* PjL2 = sh + 8320;    // 128x65
  double* g = sh + 16640;      // 512
  const int t = threadIdx.x;

  // ---------- Cholesky of Mm ----------
  for (int kb = 0; kb < 8; ++kb) {
    const int base = kb * 64;
    // diag factor + inverse
    for (int l = t; l < 4096; l += 1024) { int r = l >> 6, c = l & 63; a[r * 65 + c] = Mm[(size_t)(base + r) * LDM + base + c]; }
    __syncthreads();
    if (t == 0) { double m = 0; for (int i = 0; i < 64; i++) m = fmax(m, fabs(a[i * 65 + i])); a[4159] = m * 1e-28 + 1e-280; }
    __syncthreads();
    double dfloor = a[4159];
    for (int j = 0; j < 64; ++j) {
      if (t == 0) a[j * 65 + j] = sqrt(fmax(a[j * 65 + j], dfloor));
      __syncthreads();
      double piv = a[j * 65 + j];
      for (int r = j + 1 + t; r < 64; r += 1024) a[r * 65 + j] /= piv;
      __syncthreads();
      int w = 63 - j;
      for (int l = t; l < w * w; l += 1024) { int rr = j + 1 + l / w, cc = j + 1 + l % w; if (cc <= rr) a[rr * 65 + cc] -= a[rr * 65 + j] * a[cc * 65 + j]; }
      __syncthreads();
    }
    for (int l = t; l < 4096; l += 1024) { int r = l >> 6, c = l & 63; if (c <= r) Mm[(size_t)(base + r) * LDM + base + c] = a[r * 65 + c]; }
    if (t < 64) {
      int c = t;
      for (int i = c; i < 64; ++i) {
        double v = (i == c) ? 1.0 : 0.0;
        for (int k = c; k < i; ++k) v -= a[i * 65 + k] * invp[k * (k + 1) / 2 + c];
        invp[i * (i + 1) / 2 + c] = v / a[i * 65 + i];
      }
    }
    __syncthreads();
    for (int l = t; l < 4096; l += 1024) {
      int r = l >> 6, c = l & 63;
      double v = (c <= r) ? invp[r * (r + 1) / 2 + c] : 0.0;
      DTf[r * 65 + c] = v;                                   // DTf[r][c] = inv[r][c]
      DGC[(size_t)kb * 4096 + (size_t)c * 64 + r] = v;       // verified DG layout
    }
    __syncthreads();
    // panel: P = B * Ldiag^{-T}; P[r][col] = sum_k B[r][k] * inv[col][k]
    for (int r0 = base + 64; r0 < NM; r0 += 128) {
      int Ri = NM - r0; if (Ri > 128) Ri = 128;
      for (int l = t; l < 8192; l += 1024) { int r = l >> 6, k = l & 63; PiL2[r * 65 + k] = (r < Ri) ? Mm[(size_t)(r0 + r) * LDM + base + k] : 0.0; }
      __syncthreads();
      int ty = t >> 5, tx = t & 31;
      double acc[4][2] = {};
      for (int k = 0; k < 64; ++k) {
        double b0 = PiL2[ty * 65 + k], b1 = PiL2[(ty + 32) * 65 + k];
        double b2 = PiL2[(ty + 64) * 65 + k], b3 = PiL2[(ty + 96) * 65 + k];
        double d0 = DTf[tx * 65 + k], d1 = DTf[(tx + 32) * 65 + k];
        acc[0][0] += b0 * d0; acc[0][1] += b0 * d1;
        acc[1][0] += b1 * d0; acc[1][1] += b1 * d1;
        acc[2][0] += b2 * d0; acc[2][1] += b2 * d1;
        acc[3][0] += b3 * d0; acc[3][1] += b3 * d1;
      }
      for (int e = 0; e < 4; ++e) {
        int r = ty + 32 * e;
        if (r < Ri) {
          Mm[(size_t)(r0 + r) * LDM + base + tx] = acc[e][0];
          Mm[(size_t)(r0 + r) * LDM + base + tx + 32] = acc[e][1];
        }
      }
      __syncthreads();
    }
    // trailing: A22 -= P P^T (128-row super-strip pairs, 4x4/thread)
    int rem = NM - base - 64;
    int nss = (rem + 127) >> 7;
    for (int si = 0; si < nss; ++si) {
      int i0 = base + 64 + (si << 7);
      int Ri = NM - i0; if (Ri > 128) Ri = 128;
      for (int l = t; l < 8192; l += 1024) { int r = l >> 6, k = l & 63; PiL2[r * 65 + k] = (r < Ri) ? Mm[(size_t)(i0 + r) * LDM + base + k] : 0.0; }
      __syncthreads();
      for (int sj = 0; sj <= si; ++sj) {
        int j0 = base + 64 + (sj << 7);
        int Rj = NM - j0; if (Rj > 128) Rj = 128;
        double* Pjp = PiL2;
        if (sj != si) {
          for (int l = t; l < 8192; l += 1024) { int r = l >> 6, k = l & 63; PjL2[r * 65 + k] = (r < Rj) ? Mm[(size_t)(j0 + r) * LDM + base + k] : 0.0; }
          Pjp = PjL2;
        }
        __syncthreads();
        int ty = t >> 5, tx = t & 31;
        double acc[4][4] = {};
        for (int k = 0; k < 64; ++k) {
          double p0 = PiL2[ty * 65 + k], p1 = PiL2[(ty + 32) * 65 + k];
          double p2 = PiL2[(ty + 64) * 65 + k], p3 = PiL2[(ty + 96) * 65 + k];
          double q0 = Pjp[tx * 65 + k], q1 = Pjp[(tx + 32) * 65 + k];
          double q2 = Pjp[(tx + 64) * 65 + k], q3 = Pjp[(tx + 96) * 65 + k];
          acc[0][0] += p0 * q0; acc[0][1] += p0 * q1; acc[0][2] += p0 * q2; acc[0][3] += p0 * q3;
          acc[1][0] += p1 * q0; acc[1][1] += p1 * q1; acc[1][2] += p1 * q2; acc[1][3] += p1 * q3;
          acc[2][0] += p2 * q0; acc[2][1] += p2 * q1; acc[2][2] += p2 * q2; acc[2][3] += p2 * q3;
          acc[3][0] += p3 * q0; acc[3][1] += p3 * q1; acc[3][2] += p3 * q2; acc[3][3] += p3 * q3;
        }
        for (int e = 0; e < 4; ++e)
          for (int f = 0; f < 4; ++f) {
            int r = ty + 32 * e, c = tx + 32 * f;
            if (r < Ri && c < Rj) Mm[(size_t)(i0 + r) * LDM + j0 + c] -= acc[e][f];
          }
        __syncthreads();
      }
    }
  }

  // ---------- solve M u = g0 (fwd then bwd) ----------
  double* rt = sh + 2048;
  double* rt2 = sh + 2112;
  for (int l = t; l < NM; l += 1024) g[l] = g0v[l];
  __syncthreads();
  for (int kb = 0; kb < 8; ++kb) {
    if (t < 64) {
      double acc = g[kb * 64 + t];
      for (int jb = 0; jb < kb; ++jb)
        for (int k = 0; k < 64; ++k) acc -= Mm[(size_t)(kb * 64 + t) * LDM + jb * 64 + k] * g[jb * 64 + k];
      rt[t] = acc;
    }
    __syncthreads();
    if (t < 64) { double v = 0; for (int k = 0; k < 64; ++k) v += DGC[(size_t)kb * 4096 + k * 64 + t] * rt[k]; rt2[t] = v; }
    __syncthreads();
    if (t < 64) g[kb * 64 + t] = rt2[t];
    __syncthreads();
  }
  for (int kb = 7; kb >= 0; --kb) {
    if (t < 64) {
      double acc = g[kb * 64 + t];
      for (int jb = kb + 1; jb < 8; ++jb)
        for (int k = 0; k < 64; ++k) acc -= Mm[(size_t)(jb * 64 + k) * LDM + kb * 64 + t] * g[jb * 64 + k];
      rt[t] = acc;
    }
    __syncthreads();
    if (t < 64) { double v = 0; for (int k = 0; k < 64; ++k) v += DGC[(size_t)kb * 4096 + t * 64 + k] * rt[k]; rt2[t] = v; }
    __syncthreads();
    if (t < 64) g[kb * 64 + t] = rt2[t];
    __syncthreads();
  }
  for (int l = t; l < NM; l += 1024) solw[l] = g[l];

  // ---------- ds, dz, alpha; update s,z; mu' ----------
  double* red = sh;          // 1024
  double* dsA = sh + 1024;   // 512
  double* dzA = sh + 1536;   // 512  (rt/rt2@2048 now dead)
  double mu = scal[0];
  if (t < 512) {
    double s0 = sv[t], z0 = zv[t];
    double u0 = g[t];
    double ds = -rp[t] - dinv[t] * u0;   // G dx = dinv .* u
    double rc0 = s0 * z0 - SIG * mu;
    double dz = (-rc0 - z0 * ds) / s0;
    dsA[t] = ds; dzA[t] = dz;
    double rs = (ds < 0.0) ? -s0 / ds : 1.0;
    double rz = (dz < 0.0) ? -z0 / dz : 1.0;
    red[t] = fmin(rs, rz);
  } else {
    red[t] = 1.0;
  }
  __syncthreads();
  for (int s2 = 512; s2; s2 >>= 1) { if (t < s2) red[t] = fmin(red[t], red[t + s2]); __syncthreads(); }
  double alpha = 0.99 * fmin(1.0, red[0]);
  if (!(alpha == alpha)) alpha = 0.0;
  if (t < 512) {
    double us = alpha * dsA[t], uz = alpha * dzA[t];
    if (isfinite(us)) sv[t] += us;
    if (isfinite(uz)) zv[t] += uz;
  }
  __syncthreads();
  red[t] = (t < 512) ? sv[t] * zv[t] : 0.0;
  __syncthreads();
  for (int s2 = 512; s2; s2 >>= 1) { if (t < s2) red[t] += red[t + s2]; __syncthreads(); }
  if (t == 0) { scal[0] = red[0] / (double)MI; scal[1] = alpha; }
}

// C: dx rows + x update (blocks 0..255); dy rows + y update (256..319)
__global__ __launch_bounds__(256) void k_C(const double* __restrict__ XX, const double* __restrict__ XGT,
                                           const double* __restrict__ XY, const double* __restrict__ YXm,
                                           const double* __restrict__ YGT, const double* __restrict__ SAi,
                                           const double* __restrict__ rhs1, const double* __restrict__ solw,
                                           const double* __restrict__ ry, const double* __restrict__ scal,
                                           double* __restrict__ xv, double* __restrict__ yv) {
  int lane = threadIdx.x & 63;
  double al = scal[1];
  if (blockIdx.x < 256) {
    int wid = blockIdx.x * 4 + (int)(threadIdx.x >> 6);
    double acc = 0;
    for (int k = lane; k < ND; k += 64) acc += XX[(size_t)wid * ND + k] * rhs1[k];
    for (int m = lane; m < MI; m += 64) acc -= XGT[(size_t)wid * MI + m] * solw[m];
    for (int c = lane; c < PE; c += 64) acc -= XY[(size_t)wid * PE + c] * ry[c];
    acc = wred(acc);
    if (lane == 0) { double u = al * acc; if (isfinite(u)) xv[wid] += u; }
  } else {
    int r = (blockIdx.x - 256) * 4 + (int)(threadIdx.x >> 6);
    double acc = 0;
    for (int k = lane; k < ND; k += 64) acc += YXm[(size_t)r * ND + k] * rhs1[k];
    for (int m = lane; m < MI; m += 64) acc -= YGT[(size_t)r * MI + m] * solw[m];
    for (int c = lane; c < PE; c += 64) acc += SAi[(size_t)r * PE + c] * ry[c];
    acc = wred(acc);
    if (lane == 0) { double u = al * acc; if (isfinite(u)) yv[r] += u; }
  }
}

__global__ void k_out(const double* __restrict__ xv, float* __restrict__ out) {
  int i = blockIdx.x * blockDim.x + threadIdx.x;
  if (i < ND) out[i] = (float)xv[i];
}

__global__ void k_wsdiag(float mb, float* out) {
  int i = blockIdx.x * 256 + threadIdx.x;
  if (i < ND) out[i] = (i == 0 ? (65536.0f * (1.0f + mb)) : 0.0f);
}

extern "C" void kernel_launch(void* const* d_in, const int* in_sizes, int n_in,
                              void* d_out, int out_size, void* d_ws, size_t ws_size,
                              hipStream_t stream) {
  const float* Lf = (const float*)d_in[0];
  const float* qf = (const float*)d_in[1];
  const float* Gf = (const float*)d_in[2];
  const float* Af = (const float*)d_in[3];
  const float* bf = (const float*)d_in[4];
  const float* x0f = (const float*)d_in[5];
  const float* s0f = (const float*)d_in[6];

  double* w = (double*)d_ws;
  double* Qd  = w; w += (size_t)ND * ND;          // Q (persistent, rx)
  double* XX  = w; w += (size_t)ND * ND;          // K0inv xx-block (persistent)
  double* R1  = w; w += (size_t)ND * ND;          // Qi (setup) -> XGT/YXm/YGT (iter)
  double* R2  = w; w += (size_t)ND * ND;          // LQ (setup) -> Mm/FK0y/SAi/S (iter)
  double* XY  = w; w += (size_t)ND * PE;          // persistent
  double* FK0xReg = w; w += (size_t)MI * ND;      // AQi (setup head) -> FK0x
  double* SA  = w; w += (size_t)PE * PE;
  double* DGH = w; w += (size_t)16 * 4096;
  double* DGA = w; w += (size_t)4 * 4096;
  double* DGC = w; w += (size_t)8 * 4096;
  double* qd = w; w += ND;  double* bd = w; w += PE;  double* hd = w; w += MI;
  double* xv = w; w += ND;  double* sv = w; w += MI;  double* zv = w; w += MI;  double* yv = w; w += PE;
  double* rxv = w; w += ND; double* rp = w; w += MI;  double* ry = w; w += PE;
  double* uv = w; w += MI;  double* dinv = w; w += MI;
  double* rhs1 = w; w += ND; double* g0v = w; w += NM; double* solw = w; w += NM;
  double* scal = w; w += 16;
  float* GTf = (float*)w;
  float* ATf = GTf + (size_t)ND * MI;
  char* wend = (char*)(ATf + (size_t)ND * PE);
  size_t need = (size_t)(wend - (char*)d_ws);
  if (ws_size < need) {
    k_wsdiag<<<4, 256, 0, stream>>>((float)(ws_size >> 20), (float*)d_out);
    return;
  }

  // region aliases
  double* Qi  = R1;
  double* XGT = R1;                                   // 1024x512 (after Qi dead)
  double* YXm = R1 + (size_t)ND * MI;                 // 256x1024
  double* YGT = R1 + (size_t)ND * MI + (size_t)PE * ND; // 256x512
  double* LQ  = R2;
  double* Mm  = R2;                                   // 512xLDM (after LQ dead)
  double* FK0y = R2 + (size_t)NM * LDM;               // 512x256
  double* SAi  = FK0y + (size_t)MI * PE;              // 256x256
  double* Smat = SAi + (size_t)PE * PE;               // 512x512
  double* AQi  = FK0xReg;                             // 256x1024 (dead after XX)
  double* FK0x = FK0xReg;                             // 512x1024

  // ---- setup ----
  k_prep<<<2048, 256, 0, stream>>>(Gf, Af, qf, bf, GTf, ATf, qd, bd, xv, sv, zv, yv, scal);
  k_h<<<128, 256, 0, stream>>>(Gf, x0f, s0f, hd);
  { dim3 g(32, 32); k_qbuild<<<g, 256, 0, stream>>>(Lf, Qd, LQ); }
  for (int kb = 0; kb < 16; kb++) {
    k_chol_diag_inv<<<1, 256, 0, stream>>>(LQ, ND, kb, DGH);
    int nb = 15 - kb;
    if (nb > 0) k_chol_panel<<<nb, 256, 0, stream>>>(LQ, ND, kb, DGH);
    int nt = 2 * nb;
    if (nt > 0) { dim3 gs(nt, nt); k_chol_syrk<<<gs, 256, 0, stream>>>(LQ, ND, kb); }
  }
  for (int kb = 0; kb < 16; kb++)  k_trsmf_g<<<32, 256, 0, stream>>>(LQ, ND, Qi, ND, DGH, kb);
  for (int kb = 15; kb >= 0; kb--) k_trsmb_g<<<32, 256, 0, stream>>>(LQ, ND, Qi, ND, DGH, kb, 16);
  { dim3 g(32, 8);  k_aqi<<<g, 256, 0, stream>>>(Af, Qi, AQi); }
  { dim3 g(8, 8);   k_sa<<<g, 256, 0, stream>>>(AQi, Af, SA); }
  for (int kb = 0; kb < 4; kb++) {
    k_chol_diag_inv<<<1, 256, 0, stream>>>(SA, PE, kb, DGA);
    int nb = 3 - kb;
    if (nb > 0) k_chol_panel<<<nb, 256, 0, stream>>>(SA, PE, kb, DGA);
    int nt = 2 * nb;
    if (nt > 0) { dim3 gs(nt, nt); k_chol_syrk<<<gs, 256, 0, stream>>>(SA, PE, kb); }
  }
  for (int kb = 0; kb < 4; kb++)  k_trsmf_g<<<8, 256, 0, stream>>>(SA, PE, SAi, PE, DGA, kb);
  for (int kb = 3; kb >= 0; kb--) k_trsmb_g<<<8, 256, 0, stream>>>(SA, PE, SAi, PE, DGA, kb, 4);
  { dim3 g(8, 32);  k_xy<<<g, 256, 0, stream>>>(AQi, SAi, XY); }
  { dim3 g(32, 32); k_xx<<<g, 256, 0, stream>>>(Qi, XY, AQi, XX); }   // last read of Qi, AQi
  { dim3 g(32, 16); k_fk0x<<<g, 256, 0, stream>>>(Gf, XX, FK0x); }    // overwrites AQi region (dead)
  { dim3 g(8, 16);  k_fk0y<<<g, 256, 0, stream>>>(Gf, XY, FK0y); }
  { dim3 g(16, 16); k_smat<<<g, 256, 0, stream>>>(FK0x, Gf, Smat); }
  { dim3 g(32, 16); k_tr<<<g, 256, 0, stream>>>(FK0x, XGT, MI, ND); } // XGT = FK0x^T (overwrites Qi, dead)
  { dim3 g(8, 32);  k_tr<<<g, 256, 0, stream>>>(XY, YXm, ND, PE); }   // YXm = XY^T
  { dim3 g(8, 16);  k_tr<<<g, 256, 0, stream>>>(FK0y, YGT, MI, PE); } // YGT = FK0y^T

  // ---- iterations: 4 dispatches each ----
  const size_t ldsB = (size_t)17250 * sizeof(double);
  for (int it = 0; it < NITER; ++it) {
    k_A1<<<448, 256, 0, stream>>>(Qd, Gf, Af, GTf, ATf, qd, bd, hd, xv, sv, zv, yv, scal,
                                  rxv, rp, ry, uv, dinv);
    k_A2<<<448, 256, 0, stream>>>(rxv, GTf, uv, dinv, ry, Smat, FK0x, FK0y, rhs1, Mm, g0v);
    k_B<<<1, 1024, ldsB, stream>>>(Mm, DGC, g0v, solw, rp, dinv, sv, zv, scal);
    k_C<<<320, 256, 0, stream>>>(XX, XGT, XY, YXm, YGT, SAi, rhs1, solw, ry, scal, xv, yv);
  }
  k_out<<<4, 256, 0, stream>>>(xv, (float*)d_out);
}

// Round 10
// 43938.547 us; speedup vs baseline: 3.2130x; 1.3522x over previous
//
#include <hip/hip_runtime.h>
#include <hip/hip_bf16.h>

// IPM QP solver, f64. Constant precompute (verified R9): Q, chol(Q), Qi,
// K0inv blocks (XX, XY, SAi), FK0x=G*XX, FK0y=G*XY, S=FK0x*G^T, transposes.
// Per iteration (27 dispatches, all parallel or tiny):
//  A1: rx, rp(+uv,dinv), ry
//  A2: rhs1, M=S+diag(s/z), g0 -> Mm row 512
//  chol(M): 8 x { diag2(+fwd strip on row 512), panel, syrk }   [R8-verified]
//  bwd: strip(kb=7) + backward solve -> u                        [R8-verified]
//  upd: ds,dz,alpha; s,z,mu update (G dx = (s/z)ou identity)
//  C : dx,dy rows (precomputed GEMV) + x,y update
// Output x as f32.

constexpr int ND = 1024;
constexpr int MI = 512;
constexpr int PE = 256;
constexpr int NM = 512;      // per-iter Schur dim
constexpr int LDM = 520;
constexpr double EPSQ = 1e-4;
constexpr double SIG = 0.1;
constexpr int NITER = 25;

__device__ __forceinline__ double wred(double v) {
#pragma unroll
  for (int off = 32; off; off >>= 1) v += __shfl_down(v, off, 64);
  return v;
}

// ---------------- setup ----------------
__global__ void k_prep(const float* __restrict__ Gf, const float* __restrict__ Af,
                       const float* __restrict__ qf, const float* __restrict__ bf,
                       float* __restrict__ GTf, float* __restrict__ ATf,
                       double* __restrict__ qd, double* __restrict__ bd,
                       double* __restrict__ xv, double* __restrict__ sv,
                       double* __restrict__ zv, double* __restrict__ yv,
                       double* __restrict__ scal) {
  if (blockIdx.x == 0 && threadIdx.x == 0) { scal[0] = 1.0; scal[1] = 0.0; }
  for (size_t idx = (size_t)blockIdx.x * blockDim.x + threadIdx.x;
       idx < (size_t)MI * ND; idx += (size_t)gridDim.x * blockDim.x) {
    int k = (int)(idx >> 10), i = (int)(idx & 1023);
    GTf[(size_t)i * MI + k] = Gf[idx];
    if (idx < (size_t)PE * ND) ATf[(size_t)i * PE + k] = Af[idx];
    if (idx < ND) { qd[idx] = (double)qf[idx]; xv[idx] = 0.0; }
    if (idx < MI) { sv[idx] = 1.0; zv[idx] = 1.0; }
    if (idx < PE) { bd[idx] = (double)bf[idx]; yv[idx] = 0.0; }
  }
}

__global__ __launch_bounds__(256) void k_h(const float* __restrict__ Gf,
                                           const float* __restrict__ x0f,
                                           const float* __restrict__ s0f,
                                           double* __restrict__ hd) {
  int wid = blockIdx.x * 4 + (int)(threadIdx.x >> 6), lane = threadIdx.x & 63;
  if (wid >= MI) return;
  double acc = 0;
  for (int c = lane; c < ND; c += 64) acc += (double)Gf[(size_t)wid * ND + c] * (double)x0f[c];
  acc = wred(acc);
  if (lane == 0) hd[wid] = acc + (double)s0f[wid];
}

// Q = tril(L)tril(L)^T + epsI -> Qd and LQ
__global__ __launch_bounds__(256) void k_qbuild(const float* __restrict__ Lf,
                                                double* __restrict__ Qd, double* __restrict__ LQ) {
  __shared__ double As[32][33], Bs[32][33];
  int i0 = blockIdx.y * 32, j0 = blockIdx.x * 32;
  int tx = threadIdx.x & 15, ty = threadIdx.x >> 4;
  double acc[2][2] = {};
  int kmax = (i0 < j0 ? i0 : j0) + 32;
  for (int k0 = 0; k0 < kmax; k0 += 32) {
    for (int l = threadIdx.x; l < 1024; l += 256) {
      int r = l >> 5, c = l & 31;
      As[r][c] = (k0 + c <= i0 + r) ? (double)Lf[(size_t)(i0 + r) * ND + k0 + c] : 0.0;
      Bs[r][c] = (k0 + c <= j0 + r) ? (double)Lf[(size_t)(j0 + r) * ND + k0 + c] : 0.0;
    }
    __syncthreads();
#pragma unroll
    for (int k = 0; k < 32; k++) {
      double a0 = As[2 * ty][k], a1 = As[2 * ty + 1][k];
      double b0 = Bs[2 * tx][k], b1 = Bs[2 * tx + 1][k];
      acc[0][0] += a0 * b0; acc[0][1] += a0 * b1;
      acc[1][0] += a1 * b0; acc[1][1] += a1 * b1;
    }
    __syncthreads();
  }
  for (int da = 0; da < 2; da++)
    for (int db = 0; db < 2; db++) {
      int i = i0 + 2 * ty + da, j = j0 + 2 * tx + db;
      double v = acc[da][db] + (i == j ? EPSQ : 0.0);
      Qd[(size_t)i * ND + j] = v;
      LQ[(size_t)i * ND + j] = v;
    }
}

// blocked Cholesky BS=64, explicit diag-block inverse (verified; lda-generic)
__global__ __launch_bounds__(256) void k_chol_diag_inv(double* __restrict__ A, int lda, int kb,
                                                       double* __restrict__ DG) {
  __shared__ double a[64][65];
  __shared__ double invp[2080];
  __shared__ double dfloor;
  int t = threadIdx.x;
  size_t base = (size_t)kb * 64;
  for (int l = t; l < 4096; l += 256) { int r = l >> 6, c = l & 63; a[r][c] = A[(base + r) * lda + base + c]; }
  __syncthreads();
  if (t == 0) {
    double m = 0;
    for (int i = 0; i < 64; i++) m = fmax(m, fabs(a[i][i]));
    dfloor = m * 1e-28 + 1e-280;
  }
  __syncthreads();
  for (int j = 0; j < 64; j++) {
    if (t == 0) a[j][j] = sqrt(fmax(a[j][j], dfloor));
    __syncthreads();
    double piv = a[j][j];
    for (int r = j + 1 + t; r < 64; r += 256) a[r][j] /= piv;
    __syncthreads();
    int w = 63 - j;
    for (int l = t; l < w * w; l += 256) {
      int rr = j + 1 + l / w, cc = j + 1 + l % w;
      if (cc <= rr) a[rr][cc] -= a[rr][j] * a[cc][j];
    }
    __syncthreads();
  }
  for (int l = t; l < 4096; l += 256) { int r = l >> 6, c = l & 63; if (c <= r) A[(base + r) * lda + base + c] = a[r][c]; }
  if (t < 64) {
    int c = t;
    for (int i = c; i < 64; i++) {
      double v = (i == c) ? 1.0 : 0.0;
      for (int k = c; k < i; k++) v -= a[i][k] * invp[k * (k + 1) / 2 + c];
      invp[i * (i + 1) / 2 + c] = v / a[i][i];
    }
  }
  __syncthreads();
  for (int l = t; l < 4096; l += 256) {
    int r = l >> 6, c = l & 63;
    DG[(size_t)kb * 4096 + (size_t)c * 64 + r] = (c <= r) ? invp[r * (r + 1) / 2 + c] : 0.0;
  }
}

// diag+inv (block 0) fused with the row-NM forward-solve "strip" for step kb-1 (block 1)
// [R8-verified structure, 768->512]
__global__ __launch_bounds__(256) void k_diag2(double* __restrict__ A, int lda, int kb,
                                               double* __restrict__ DG) {
  __shared__ double sh[6400];
  int t = threadIdx.x;
  if (blockIdx.x == 0) {
    double* a = sh;            // [64][65]
    double* invp = sh + 4160;  // 2080
    size_t base = (size_t)kb * 64;
    for (int l = t; l < 4096; l += 256) { int r = l >> 6, c = l & 63; a[r * 65 + c] = A[(base + r) * lda + base + c]; }
    __syncthreads();
    if (t == 0) {
      double m = 0;
      for (int i = 0; i < 64; i++) m = fmax(m, fabs(a[i * 65 + i]));
      sh[6272] = m * 1e-28 + 1e-280;
    }
    __syncthreads();
    double dfloor = sh[6272];
    for (int j = 0; j < 64; j++) {
      if (t == 0) a[j * 65 + j] = sqrt(fmax(a[j * 65 + j], dfloor));
      __syncthreads();
      double piv = a[j * 65 + j];
      for (int r = j + 1 + t; r < 64; r += 256) a[r * 65 + j] /= piv;
      __syncthreads();
      int w = 63 - j;
      for (int l = t; l < w * w; l += 256) {
        int rr = j + 1 + l / w, cc = j + 1 + l % w;
        if (cc <= rr) a[rr * 65 + cc] -= a[rr * 65 + j] * a[cc * 65 + j];
      }
      __syncthreads();
    }
    for (int l = t; l < 4096; l += 256) { int r = l >> 6, c = l & 63; if (c <= r) A[(base + r) * lda + base + c] = a[r * 65 + c]; }
    if (t < 64) {
      int c = t;
      for (int i = c; i < 64; i++) {
        double v = (i == c) ? 1.0 : 0.0;
        for (int k = c; k < i; k++) v -= a[i * 65 + k] * invp[k * (k + 1) / 2 + c];
        invp[i * (i + 1) / 2 + c] = v / a[i * 65 + i];
      }
    }
    __syncthreads();
    for (int l = t; l < 4096; l += 256) {
      int r = l >> 6, c = l & 63;
      DG[(size_t)kb * 4096 + (size_t)c * 64 + r] = (c <= r) ? invp[r * (r + 1) / 2 + c] : 0.0;
    }
  } else if (kb > 0) {
    // strip: forward-eliminate row NM for step kbp = kb-1
    int kbp = kb - 1;
    double* DT = sh;            // 4096: DG layout, DT[k*64+c] = inv[c][k]
    double* gseg = sh + 4096;   // 64
    double* pseg = sh + 4160;   // 64
    for (int l = t; l < 4096; l += 256) DT[l] = DG[(size_t)kbp * 4096 + l];
    if (t < 64) gseg[t] = A[(size_t)NM * lda + kbp * 64 + t];
    __syncthreads();
    if (t < 64) {
      double s = 0;
#pragma unroll
      for (int k = 0; k < 64; k++) s += gseg[k] * DT[k * 64 + t];
      pseg[t] = s;   // p = Ldiag^{-1} g
    }
    __syncthreads();
    for (int c = kb * 64 + t; c < NM; c += 256) {
      double s = 0;
#pragma unroll
      for (int k = 0; k < 64; k++) s += pseg[k] * A[(size_t)c * lda + kbp * 64 + k];
      A[(size_t)NM * lda + c] -= s;
    }
    if (t < 64) A[(size_t)NM * lda + kbp * 64 + t] = pseg[t];
  }
}

__global__ __launch_bounds__(256) void k_chol_panel(double* __restrict__ A, int lda, int kb,
                                                    const double* __restrict__ DG) {
  __shared__ double B32[32][65];
  __shared__ double DT[64][64];
  int t = threadIdx.x;
  int r0 = (kb + 1) * 64 + blockIdx.x * 64;
  int c0 = kb * 64;
  for (int l = t; l < 4096; l += 256) DT[l >> 6][l & 63] = DG[(size_t)kb * 4096 + l];
  int wave = t >> 6, lane = t & 63;
  for (int h = 0; h < 2; ++h) {
    __syncthreads();
    for (int l = t; l < 2048; l += 256) { int r = l >> 6, c = l & 63; B32[r][c] = A[(size_t)(r0 + h * 32 + r) * lda + c0 + c]; }
    __syncthreads();
    for (int rr = 0; rr < 8; rr++) {
      int rl = wave * 8 + rr;
      double acc = 0;
#pragma unroll
      for (int c = 0; c < 64; c++) acc += B32[rl][c] * DT[c][lane];
      A[(size_t)(r0 + h * 32 + rl) * lda + c0 + lane] = acc;
    }
  }
}

__global__ __launch_bounds__(256) void k_chol_syrk(double* __restrict__ A, int lda, int kb) {
  int start = (kb + 1) * 64;
  int i0 = start + blockIdx.y * 32, j0 = start + blockIdx.x * 32;
  if (j0 > i0) return;
  __shared__ double As[32][33], Bs[32][33];
  int tx = threadIdx.x & 15, ty = threadIdx.x >> 4;
  double acc[2][2] = {};
  for (int k0 = 0; k0 < 64; k0 += 32) {
    for (int l = threadIdx.x; l < 1024; l += 256) {
      int r = l >> 5, c = l & 31;
      As[r][c] = A[(size_t)(i0 + r) * lda + kb * 64 + k0 + c];
      Bs[r][c] = A[(size_t)(j0 + r) * lda + kb * 64 + k0 + c];
    }
    __syncthreads();
#pragma unroll
    for (int k = 0; k < 32; k++) {
      double a0 = As[2 * ty][k], a1 = As[2 * ty + 1][k];
      double b0 = Bs[2 * tx][k], b1 = Bs[2 * tx + 1][k];
      acc[0][0] += a0 * b0; acc[0][1] += a0 * b1;
      acc[1][0] += a1 * b0; acc[1][1] += a1 * b1;
    }
    __syncthreads();
  }
  for (int da = 0; da < 2; da++)
    for (int db = 0; db < 2; db++) {
      int i = i0 + 2 * ty + da, j = j0 + 2 * tx + db;
      if (j <= i) A[(size_t)i * lda + j] -= acc[da][db];
    }
}

// generic trsm identity-RHS fwd / in-place bwd (verified)
__global__ __launch_bounds__(256) void k_trsmf_g(const double* __restrict__ Lm, int lda,
                                                 double* __restrict__ X, int ldx,
                                                 const double* __restrict__ DG, int kb) {
  __shared__ double Lb[64][64];
  __shared__ double Xs[64][33];
  int t = threadIdx.x;
  int c0 = blockIdx.x * 32;
  int lane2 = t & 31, rbase = t >> 5;
  int row0 = kb * 64;
  double acc[8];
#pragma unroll
  for (int e = 0; e < 8; e++) acc[e] = (row0 + rbase + 8 * e == c0 + lane2) ? 1.0 : 0.0;
  for (int jb = 0; jb < kb; jb++) {
    for (int l = t; l < 4096; l += 256) { int r = l >> 6, c = l & 63; Lb[r][c] = Lm[(size_t)(row0 + r) * lda + jb * 64 + c]; }
    for (int l = t; l < 2048; l += 256) { int k = l >> 5, c = l & 31; Xs[k][c] = X[(size_t)(jb * 64 + k) * ldx + c0 + c]; }
    __syncthreads();
#pragma unroll 4
    for (int k = 0; k < 64; k++) {
      double wv = Xs[k][lane2];
#pragma unroll
      for (int e = 0; e < 8; e++) acc[e] -= Lb[rbase + 8 * e][k] * wv;
    }
    __syncthreads();
  }
  __syncthreads();
#pragma unroll
  for (int e = 0; e < 8; e++) Xs[rbase + 8 * e][lane2] = acc[e];
  for (int l = t; l < 4096; l += 256) Lb[l >> 6][l & 63] = DG[(size_t)kb * 4096 + l];
  __syncthreads();
#pragma unroll
  for (int e = 0; e < 8; e++) {
    int i = rbase + 8 * e;
    double s = 0;
#pragma unroll 4
    for (int k = 0; k < 64; k++) s += Lb[k][i] * Xs[k][lane2];
    X[(size_t)(row0 + i) * ldx + c0 + lane2] = s;
  }
}

__global__ __launch_bounds__(256) void k_trsmb_g(const double* __restrict__ Lm, int lda,
                                                 double* __restrict__ X, int ldx,
                                                 const double* __restrict__ DG, int kb, int nkb) {
  __shared__ double Lb[64][64];
  __shared__ double Xs[64][33];
  int t = threadIdx.x;
  int c0 = blockIdx.x * 32;
  int lane2 = t & 31, rbase = t >> 5;
  int row0 = kb * 64;
  double acc[8];
#pragma unroll
  for (int e = 0; e < 8; e++) acc[e] = X[(size_t)(row0 + rbase + 8 * e) * ldx + c0 + lane2];
  for (int jb = kb + 1; jb < nkb; jb++) {
    for (int l = t; l < 4096; l += 256) { int r = l >> 6, c = l & 63; Lb[r][c] = Lm[(size_t)(jb * 64 + r) * lda + kb * 64 + c]; }
    for (int l = t; l < 2048; l += 256) { int k = l >> 5, c = l & 31; Xs[k][c] = X[(size_t)(jb * 64 + k) * ldx + c0 + c]; }
    __syncthreads();
#pragma unroll 4
    for (int k = 0; k < 64; k++) {
      double wv = Xs[k][lane2];
#pragma unroll
      for (int e = 0; e < 8; e++) acc[e] -= Lb[k][rbase + 8 * e] * wv;
    }
    __syncthreads();
  }
  __syncthreads();
#pragma unroll
  for (int e = 0; e < 8; e++) Xs[rbase + 8 * e][lane2] = acc[e];
  for (int l = t; l < 4096; l += 256) Lb[l >> 6][l & 63] = DG[(size_t)kb * 4096 + l];
  __syncthreads();
#pragma unroll
  for (int e = 0; e < 8; e++) {
    int i = rbase + 8 * e;
    double s = 0;
#pragma unroll 4
    for (int k = 0; k < 64; k++) s += Lb[i][k] * Xs[k][lane2];
    X[(size_t)(row0 + i) * ldx + c0 + lane2] = s;
  }
}

// ---------------- setup GEMMs (verified R9) ----------------
__global__ __launch_bounds__(256) void k_aqi(const float* __restrict__ Af, const double* __restrict__ Qi,
                                             double* __restrict__ AQi) {
  __shared__ double As[32][33], Bs[32][33];
  int i0 = blockIdx.x * 32, a0 = blockIdx.y * 32;
  int tx = threadIdx.x & 15, ty = threadIdx.x >> 4;
  double acc[2][2] = {};
  for (int k0 = 0; k0 < ND; k0 += 32) {
    for (int l = threadIdx.x; l < 1024; l += 256) {
      int r = l >> 5, c = l & 31;
      As[r][c] = (double)Af[(size_t)(a0 + r) * ND + k0 + c];
      Bs[r][c] = Qi[(size_t)(k0 + r) * ND + i0 + c];
    }
    __syncthreads();
#pragma unroll
    for (int k = 0; k < 32; k++) {
      double a0v = As[2 * ty][k], a1v = As[2 * ty + 1][k];
      double b0v = Bs[k][2 * tx], b1v = Bs[k][2 * tx + 1];
      acc[0][0] += a0v * b0v; acc[0][1] += a0v * b1v;
      acc[1][0] += a1v * b0v; acc[1][1] += a1v * b1v;
    }
    __syncthreads();
  }
  for (int da = 0; da < 2; da++)
    for (int db = 0; db < 2; db++)
      AQi[(size_t)(a0 + 2 * ty + da) * ND + i0 + 2 * tx + db] = acc[da][db];
}

__global__ __launch_bounds__(256) void k_sa(const double* __restrict__ AQi, const float* __restrict__ Af,
                                            double* __restrict__ SA) {
  __shared__ double As[32][33], Bs[32][33];
  int a0 = blockIdx.y * 32, b0 = blockIdx.x * 32;
  int tx = threadIdx.x & 15, ty = threadIdx.x >> 4;
  double acc[2][2] = {};
  for (int k0 = 0; k0 < ND; k0 += 32) {
    for (int l = threadIdx.x; l < 1024; l += 256) {
      int r = l >> 5, c = l & 31;
      As[r][c] = AQi[(size_t)(a0 + r) * ND + k0 + c];
      Bs[r][c] = (double)Af[(size_t)(b0 + r) * ND + k0 + c];
    }
    __syncthreads();
#pragma unroll
    for (int k = 0; k < 32; k++) {
      double a0v = As[2 * ty][k], a1v = As[2 * ty + 1][k];
      double b0v = Bs[2 * tx][k], b1v = Bs[2 * tx + 1][k];
      acc[0][0] += a0v * b0v; acc[0][1] += a0v * b1v;
      acc[1][0] += a1v * b0v; acc[1][1] += a1v * b1v;
    }
    __syncthreads();
  }
  for (int da = 0; da < 2; da++)
    for (int db = 0; db < 2; db++)
      SA[(size_t)(a0 + 2 * ty + da) * PE + b0 + 2 * tx + db] = acc[da][db];
}

__global__ __launch_bounds__(256) void k_xy(const double* __restrict__ AQi, const double* __restrict__ SAi,
                                            double* __restrict__ XY) {
  __shared__ double As[32][33], Bs[32][33];
  int b0 = blockIdx.x * 32, i0 = blockIdx.y * 32;
  int tx = threadIdx.x & 15, ty = threadIdx.x >> 4;
  double acc[2][2] = {};
  for (int k0 = 0; k0 < PE; k0 += 32) {
    for (int l = threadIdx.x; l < 1024; l += 256) {
      int r = l >> 5, c = l & 31;
      As[r][c] = AQi[(size_t)(k0 + r) * ND + i0 + c];
      Bs[r][c] = SAi[(size_t)(k0 + r) * PE + b0 + c];
    }
    __syncthreads();
#pragma unroll
    for (int k = 0; k < 32; k++) {
      double a0v = As[k][2 * ty], a1v = As[k][2 * ty + 1];
      double b0v = Bs[k][2 * tx], b1v = Bs[k][2 * tx + 1];
      acc[0][0] += a0v * b0v; acc[0][1] += a0v * b1v;
      acc[1][0] += a1v * b0v; acc[1][1] += a1v * b1v;
    }
    __syncthreads();
  }
  for (int da = 0; da < 2; da++)
    for (int db = 0; db < 2; db++)
      XY[(size_t)(i0 + 2 * ty + da) * PE + b0 + 2 * tx + db] = acc[da][db];
}

__global__ __launch_bounds__(256) void k_xx(const double* __restrict__ Qi, const double* __restrict__ XY,
                                            const double* __restrict__ AQi, double* __restrict__ XX) {
  __shared__ double As[32][33], Bs[32][33];
  int j0 = blockIdx.x * 32, i0 = blockIdx.y * 32;
  int tx = threadIdx.x & 15, ty = threadIdx.x >> 4;
  double acc[2][2] = {};
  for (int k0 = 0; k0 < PE; k0 += 32) {
    for (int l = threadIdx.x; l < 1024; l += 256) {
      int r = l >> 5, c = l & 31;
      As[r][c] = XY[(size_t)(i0 + r) * PE + k0 + c];
      Bs[r][c] = AQi[(size_t)(k0 + r) * ND + j0 + c];
    }
    __syncthreads();
#pragma unroll
    for (int k = 0; k < 32; k++) {
      double a0v = As[2 * ty][k], a1v = As[2 * ty + 1][k];
      double b0v = Bs[k][2 * tx], b1v = Bs[k][2 * tx + 1];
      acc[0][0] += a0v * b0v; acc[0][1] += a0v * b1v;
      acc[1][0] += a1v * b0v; acc[1][1] += a1v * b1v;
    }
    __syncthreads();
  }
  for (int da = 0; da < 2; da++)
    for (int db = 0; db < 2; db++) {
      int i = i0 + 2 * ty + da, j = j0 + 2 * tx + db;
      XX[(size_t)i * ND + j] = Qi[(size_t)i * ND + j] - acc[da][db];
    }
}

__global__ __launch_bounds__(256) void k_fk0x(const float* __restrict__ Gf, const double* __restrict__ XX,
                                              double* __restrict__ FK0x) {
  __shared__ double As[32][33], Bs[32][33];
  int j0 = blockIdx.x * 32, g0 = blockIdx.y * 32;
  int tx = threadIdx.x & 15, ty = threadIdx.x >> 4;
  double acc[2][2] = {};
  for (int k0 = 0; k0 < ND; k0 += 32) {
    for (int l = threadIdx.x; l < 1024; l += 256) {
      int r = l >> 5, c = l & 31;
      As[r][c] = (double)Gf[(size_t)(g0 + r) * ND + k0 + c];
      Bs[r][c] = XX[(size_t)(k0 + r) * ND + j0 + c];
    }
    __syncthreads();
#pragma unroll
    for (int k = 0; k < 32; k++) {
      double a0v = As[2 * ty][k], a1v = As[2 * ty + 1][k];
      double b0v = Bs[k][2 * tx], b1v = Bs[k][2 * tx + 1];
      acc[0][0] += a0v * b0v; acc[0][1] += a0v * b1v;
      acc[1][0] += a1v * b0v; acc[1][1] += a1v * b1v;
    }
    __syncthreads();
  }
  for (int da = 0; da < 2; da++)
    for (int db = 0; db < 2; db++)
      FK0x[(size_t)(g0 + 2 * ty + da) * ND + j0 + 2 * tx + db] = acc[da][db];
}

__global__ __launch_bounds__(256) void k_fk0y(const float* __restrict__ Gf, const double* __restrict__ XY,
                                              double* __restrict__ FK0y) {
  __shared__ double As[32][33], Bs[32][33];
  int b0 = blockIdx.x * 32, g0 = blockIdx.y * 32;
  int tx = threadIdx.x & 15, ty = threadIdx.x >> 4;
  double acc[2][2] = {};
  for (int k0 = 0; k0 < ND; k0 += 32) {
    for (int l = threadIdx.x; l < 1024; l += 256) {
      int r = l >> 5, c = l & 31;
      As[r][c] = (double)Gf[(size_t)(g0 + r) * ND + k0 + c];
      Bs[r][c] = XY[(size_t)(k0 + r) * PE + b0 + c];
    }
    __syncthreads();
#pragma unroll
    for (int k = 0; k < 32; k++) {
      double a0v = As[2 * ty][k], a1v = As[2 * ty + 1][k];
      double b0v = Bs[k][2 * tx], b1v = Bs[k][2 * tx + 1];
      acc[0][0] += a0v * b0v; acc[0][1] += a0v * b1v;
      acc[1][0] += a1v * b0v; acc[1][1] += a1v * b1v;
    }
    __syncthreads();
  }
  for (int da = 0; da < 2; da++)
    for (int db = 0; db < 2; db++)
      FK0y[(size_t)(g0 + 2 * ty + da) * PE + b0 + 2 * tx + db] = acc[da][db];
}

__global__ __launch_bounds__(256) void k_smat(const double* __restrict__ FK0x, const float* __restrict__ Gf,
                                              double* __restrict__ S) {
  __shared__ double As[32][33], Bs[32][33];
  int g0 = blockIdx.y * 32, h0 = blockIdx.x * 32;
  int tx = threadIdx.x & 15, ty = threadIdx.x >> 4;
  double acc[2][2] = {};
  for (int k0 = 0; k0 < ND; k0 += 32) {
    for (int l = threadIdx.x; l < 1024; l += 256) {
      int r = l >> 5, c = l & 31;
      As[r][c] = FK0x[(size_t)(g0 + r) * ND + k0 + c];
      Bs[r][c] = (double)Gf[(size_t)(h0 + r) * ND + k0 + c];
    }
    __syncthreads();
#pragma unroll
    for (int k = 0; k < 32; k++) {
      double a0v = As[2 * ty][k], a1v = As[2 * ty + 1][k];
      double b0v = Bs[2 * tx][k], b1v = Bs[2 * tx + 1][k];
      acc[0][0] += a0v * b0v; acc[0][1] += a0v * b1v;
      acc[1][0] += a1v * b0v; acc[1][1] += a1v * b1v;
    }
    __syncthreads();
  }
  for (int da = 0; da < 2; da++)
    for (int db = 0; db < 2; db++)
      S[(size_t)(g0 + 2 * ty + da) * MI + h0 + 2 * tx + db] = acc[da][db];
}

__global__ __launch_bounds__(256) void k_tr(const double* __restrict__ src, double* __restrict__ dst,
                                            int R, int Cc) {
  __shared__ double tile[32][33];
  int r0 = blockIdx.y * 32, c0 = blockIdx.x * 32;
  for (int l = threadIdx.x; l < 1024; l += 256) {
    int r = l >> 5, c = l & 31;
    tile[r][c] = src[(size_t)(r0 + r) * Cc + c0 + c];
  }
  __syncthreads();
  for (int l = threadIdx.x; l < 1024; l += 256) {
    int r = l >> 5, c = l & 31;
    dst[(size_t)(c0 + r) * R + r0 + c] = tile[c][r];
  }
}

// ---------------- per-iteration kernels ----------------
__global__ __launch_bounds__(256) void k_A1(const double* __restrict__ Qd, const float* __restrict__ Gf,
                                            const float* __restrict__ Af, const float* __restrict__ GTf,
                                            const float* __restrict__ ATf, const double* __restrict__ qd,
                                            const double* __restrict__ bd, const double* __restrict__ hd,
                                            const double* __restrict__ xv, const double* __restrict__ sv,
                                            const double* __restrict__ zv, const double* __restrict__ yv,
                                            const double* __restrict__ scal,
                                            double* __restrict__ rxv, double* __restrict__ rp,
                                            double* __restrict__ ry, double* __restrict__ uv,
                                            double* __restrict__ dinv) {
  int lane = threadIdx.x & 63;
  if (blockIdx.x < 256) {
    int wid = blockIdx.x * 4 + (int)(threadIdx.x >> 6);
    double acc = 0;
    for (int k = lane; k < ND; k += 64) acc += Qd[(size_t)wid * ND + k] * xv[k];
    for (int k = lane; k < MI; k += 64) acc += (double)GTf[(size_t)wid * MI + k] * zv[k];
    for (int k = lane; k < PE; k += 64) acc += (double)ATf[(size_t)wid * PE + k] * yv[k];
    acc = wred(acc);
    if (lane == 0) rxv[wid] = acc + qd[wid];
  } else {
    int wid = (blockIdx.x - 256) * 4 + (int)(threadIdx.x >> 6);
    if (wid < MI) {
      double acc = 0;
      for (int c = lane; c < ND; c += 64) acc += (double)Gf[(size_t)wid * ND + c] * xv[c];
      acc = wred(acc);
      if (lane == 0) {
        double s0 = sv[wid], z0 = zv[wid];
        double rpv = acc + s0 - hd[wid];
        rp[wid] = rpv;
        double rc0 = s0 * z0 - SIG * scal[0];
        uv[wid] = (-rc0 + z0 * rpv) / s0;
        dinv[wid] = s0 / z0;
      }
    } else {
      int r = wid - MI;
      double acc = 0;
      for (int c = lane; c < ND; c += 64) acc += (double)Af[(size_t)r * ND + c] * xv[c];
      acc = wred(acc);
      if (lane == 0) ry[r] = acc - bd[r];
    }
  }
}

// A2: blocks 0..255 rhs1; 256..319 M=S+diag(dinv); 320..447 g0 -> Mm row NM
__global__ __launch_bounds__(256) void k_A2(const double* __restrict__ rxv, const float* __restrict__ GTf,
                                            const double* __restrict__ uv, const double* __restrict__ dinv,
                                            const double* __restrict__ ry, const double* __restrict__ S,
                                            const double* __restrict__ FK0x, const double* __restrict__ FK0y,
                                            double* __restrict__ rhs1, double* __restrict__ Mm) {
  int t = threadIdx.x, lane = t & 63;
  if (blockIdx.x < 256) {
    int wid = blockIdx.x * 4 + (t >> 6);
    double acc = 0;
    for (int k = lane; k < MI; k += 64) acc += (double)GTf[(size_t)wid * MI + k] * uv[k];
    acc = wred(acc);
    if (lane == 0) rhs1[wid] = -(rxv[wid] + acc);
  } else if (blockIdx.x < 320) {
    int rbase = (blockIdx.x - 256) * 8;
    for (int rr = 0; rr < 8; ++rr) {
      int row = rbase + rr;
      for (int c = t; c < NM; c += 256) {
        double v = S[(size_t)row * MI + c];
        if (row == c) v += dinv[row];
        Mm[(size_t)row * LDM + c] = v;
      }
    }
  } else {
    int j = (blockIdx.x - 320) * 4 + (t >> 6);
    double acc = 0;
    for (int k = lane; k < ND; k += 64) acc += FK0x[(size_t)j * ND + k] * rxv[k];
    for (int m = lane; m < MI; m += 64) acc += S[(size_t)j * MI + m] * uv[m];
    for (int c = lane; c < PE; c += 64) acc += FK0y[(size_t)j * PE + c] * ry[c];
    acc = wred(acc);
    if (lane == 0) Mm[(size_t)NM * LDM + j] = -acc;   // g0 rides as row NM
  }
}

// bwd: strip(kb=7) + full backward solve -> solw   [R8-verified, 768->512]
__global__ __launch_bounds__(256) void k_bwd(const double* __restrict__ Mm, const double* __restrict__ DGC,
                                             double* __restrict__ solw) {
  __shared__ double DT[4096];
  __shared__ double gf[NM];
  __shared__ double acc4[4][64];
  __shared__ double tmp[64];
  int t = threadIdx.x;
  int i = t & 63, p4 = t >> 6;
  for (int l = t; l < NM; l += 256) gf[l] = Mm[(size_t)NM * LDM + l];
  for (int l = t; l < 4096; l += 256) DT[l] = DGC[(size_t)7 * 4096 + l];
  __syncthreads();
  if (t < 64) {
    double s = 0;
#pragma unroll
    for (int k = 0; k < 64; k++) s += gf[448 + k] * DT[k * 64 + t];
    tmp[t] = s;
  }
  __syncthreads();
  if (t < 64) gf[448 + t] = tmp[t];
  __syncthreads();
  for (int kb = 7; kb >= 0; --kb) {
    __syncthreads();
    for (int l = t; l < 4096; l += 256) DT[l] = DGC[(size_t)kb * 4096 + l];
    int tr0 = kb * 64 + 64;
    int R = NM - tr0;
    double s = 0;
    for (int rr = p4; rr < R; rr += 4)
      s += Mm[(size_t)(tr0 + rr) * LDM + kb * 64 + i] * gf[tr0 + rr];
    acc4[p4][i] = s;
    __syncthreads();
    if (t < 64) tmp[t] = gf[kb * 64 + t] - (acc4[0][t] + acc4[1][t] + acc4[2][t] + acc4[3][t]);
    __syncthreads();
    if (t < 64) {
      double v = 0;
#pragma unroll
      for (int l = 0; l < 64; l++) v += DT[t * 64 + l] * tmp[l];
      acc4[0][t] = v;
    }
    __syncthreads();
    if (t < 64) gf[kb * 64 + t] = acc4[0][t];
    __syncthreads();
  }
  for (int l = t; l < NM; l += 256) solw[l] = gf[l];
}

// upd: ds,dz,alpha; s,z update; mu'  (1 block, 512 threads)
__global__ __launch_bounds__(512) void k_upd(const double* __restrict__ solw, const double* __restrict__ rp,
                                             const double* __restrict__ dinv, double* __restrict__ sv,
                                             double* __restrict__ zv, double* __restrict__ scal) {
  __shared__ double red[512];
  __shared__ double dsA[512];
  __shared__ double dzA[512];
  int t = threadIdx.x;
  double mu = scal[0];
  double s0 = sv[t], z0 = zv[t];
  double ds = -rp[t] - dinv[t] * solw[t];   // G dx = dinv .* u
  double rc0 = s0 * z0 - SIG * mu;
  double dz = (-rc0 - z0 * ds) / s0;
  dsA[t] = ds; dzA[t] = dz;
  double rs = (ds < 0.0) ? -s0 / ds : 1.0;
  double rz = (dz < 0.0) ? -z0 / dz : 1.0;
  red[t] = fmin(rs, rz);
  __syncthreads();
  for (int s2 = 256; s2; s2 >>= 1) { if (t < s2) red[t] = fmin(red[t], red[t + s2]); __syncthreads(); }
  double alpha = 0.99 * fmin(1.0, red[0]);
  if (!(alpha == alpha)) alpha = 0.0;
  double us = alpha * dsA[t], uz = alpha * dzA[t];
  if (isfinite(us)) sv[t] += us;
  if (isfinite(uz)) zv[t] += uz;
  __syncthreads();
  red[t] = sv[t] * zv[t];
  __syncthreads();
  for (int s2 = 256; s2; s2 >>= 1) { if (t < s2) red[t] += red[t + s2]; __syncthreads(); }
  if (t == 0) { scal[0] = red[0] / (double)MI; scal[1] = alpha; }
}

// C: dx rows + x update (0..255); dy rows + y update (256..319)
__global__ __launch_bounds__(256) void k_C(const double* __restrict__ XX, const double* __restrict__ XGT,
                                           const double* __restrict__ XY, const double* __restrict__ YXm,
                                           const double* __restrict__ YGT, const double* __restrict__ SAi,
                                           const double* __restrict__ rhs1, const double* __restrict__ solw,
                                           const double* __restrict__ ry, const double* __restrict__ scal,
                                           double* __restrict__ xv, double* __restrict__ yv) {
  int lane = threadIdx.x & 63;
  double al = scal[1];
  if (blockIdx.x < 256) {
    int wid = blockIdx.x * 4 + (int)(threadIdx.x >> 6);
    double acc = 0;
    for (int k = lane; k < ND; k += 64) acc += XX[(size_t)wid * ND + k] * rhs1[k];
    for (int m = lane; m < MI; m += 64) acc -= XGT[(size_t)wid * MI + m] * solw[m];
    for (int c = lane; c < PE; c += 64) acc -= XY[(size_t)wid * PE + c] * ry[c];
    acc = wred(acc);
    if (lane == 0) { double u = al * acc; if (isfinite(u)) xv[wid] += u; }
  } else {
    int r = (blockIdx.x - 256) * 4 + (int)(threadIdx.x >> 6);
    double acc = 0;
    for (int k = lane; k < ND; k += 64) acc += YXm[(size_t)r * ND + k] * rhs1[k];
    for (int m = lane; m < MI; m += 64) acc -= YGT[(size_t)r * MI + m] * solw[m];
    for (int c = lane; c < PE; c += 64) acc += SAi[(size_t)r * PE + c] * ry[c];
    acc = wred(acc);
    if (lane == 0) { double u = al * acc; if (isfinite(u)) yv[r] += u; }
  }
}

__global__ void k_out(const double* __restrict__ xv, float* __restrict__ out) {
  int i = blockIdx.x * blockDim.x + threadIdx.x;
  if (i < ND) out[i] = (float)xv[i];
}

__global__ void k_wsdiag(float mb, float* out) {
  int i = blockIdx.x * 256 + threadIdx.x;
  if (i < ND) out[i] = (i == 0 ? (65536.0f * (1.0f + mb)) : 0.0f);
}

extern "C" void kernel_launch(void* const* d_in, const int* in_sizes, int n_in,
                              void* d_out, int out_size, void* d_ws, size_t ws_size,
                              hipStream_t stream) {
  const float* Lf = (const float*)d_in[0];
  const float* qf = (const float*)d_in[1];
  const float* Gf = (const float*)d_in[2];
  const float* Af = (const float*)d_in[3];
  const float* bf = (const float*)d_in[4];
  const float* x0f = (const float*)d_in[5];
  const float* s0f = (const float*)d_in[6];

  double* w = (double*)d_ws;
  double* Qd  = w; w += (size_t)ND * ND;
  double* XX  = w; w += (size_t)ND * ND;
  double* R1  = w; w += (size_t)ND * ND;          // Qi -> XGT/YXm/YGT
  double* R2  = w; w += (size_t)ND * ND;          // LQ -> Mm(513xLDM)/FK0y/SAi/Smat
  double* XY  = w; w += (size_t)ND * PE;
  double* FK0xReg = w; w += (size_t)MI * ND;      // AQi -> FK0x
  double* SA  = w; w += (size_t)PE * PE;
  double* DGH = w; w += (size_t)16 * 4096;
  double* DGA = w; w += (size_t)4 * 4096;
  double* DGC = w; w += (size_t)8 * 4096;
  double* qd = w; w += ND;  double* bd = w; w += PE;  double* hd = w; w += MI;
  double* xv = w; w += ND;  double* sv = w; w += MI;  double* zv = w; w += MI;  double* yv = w; w += PE;
  double* rxv = w; w += ND; double* rp = w; w += MI;  double* ry = w; w += PE;
  double* uv = w; w += MI;  double* dinv = w; w += MI;
  double* rhs1 = w; w += ND; double* solw = w; w += NM;
  double* scal = w; w += 16;
  float* GTf = (float*)w;
  float* ATf = GTf + (size_t)ND * MI;
  char* wend = (char*)(ATf + (size_t)ND * PE);
  size_t need = (size_t)(wend - (char*)d_ws);
  if (ws_size < need) {
    k_wsdiag<<<4, 256, 0, stream>>>((float)(ws_size >> 20), (float*)d_out);
    return;
  }

  // region aliases
  double* Qi  = R1;
  double* XGT = R1;                                     // 1024x512 (Qi dead)
  double* YXm = R1 + (size_t)ND * MI;                   // 256x1024
  double* YGT = R1 + (size_t)ND * MI + (size_t)PE * ND; // 256x512
  double* LQ  = R2;
  double* Mm  = R2;                                     // 513 x LDM (LQ dead)
  double* FK0y = R2 + (size_t)(NM + 1) * LDM;           // 512x256
  double* SAi  = FK0y + (size_t)MI * PE;                // 256x256
  double* Smat = SAi + (size_t)PE * PE;                 // 512x512
  double* AQi  = FK0xReg;
  double* FK0x = FK0xReg;

  // ---- setup (verified) ----
  k_prep<<<2048, 256, 0, stream>>>(Gf, Af, qf, bf, GTf, ATf, qd, bd, xv, sv, zv, yv, scal);
  k_h<<<128, 256, 0, stream>>>(Gf, x0f, s0f, hd);
  { dim3 g(32, 32); k_qbuild<<<g, 256, 0, stream>>>(Lf, Qd, LQ); }
  for (int kb = 0; kb < 16; kb++) {
    k_chol_diag_inv<<<1, 256, 0, stream>>>(LQ, ND, kb, DGH);
    int nb = 15 - kb;
    if (nb > 0) k_chol_panel<<<nb, 256, 0, stream>>>(LQ, ND, kb, DGH);
    int nt = 2 * nb;
    if (nt > 0) { dim3 gs(nt, nt); k_chol_syrk<<<gs, 256, 0, stream>>>(LQ, ND, kb); }
  }
  for (int kb = 0; kb < 16; kb++)  k_trsmf_g<<<32, 256, 0, stream>>>(LQ, ND, Qi, ND, DGH, kb);
  for (int kb = 15; kb >= 0; kb--) k_trsmb_g<<<32, 256, 0, stream>>>(LQ, ND, Qi, ND, DGH, kb, 16);
  { dim3 g(32, 8);  k_aqi<<<g, 256, 0, stream>>>(Af, Qi, AQi); }
  { dim3 g(8, 8);   k_sa<<<g, 256, 0, stream>>>(AQi, Af, SA); }
  for (int kb = 0; kb < 4; kb++) {
    k_chol_diag_inv<<<1, 256, 0, stream>>>(SA, PE, kb, DGA);
    int nb = 3 - kb;
    if (nb > 0) k_chol_panel<<<nb, 256, 0, stream>>>(SA, PE, kb, DGA);
    int nt = 2 * nb;
    if (nt > 0) { dim3 gs(nt, nt); k_chol_syrk<<<gs, 256, 0, stream>>>(SA, PE, kb); }
  }
  for (int kb = 0; kb < 4; kb++)  k_trsmf_g<<<8, 256, 0, stream>>>(SA, PE, SAi, PE, DGA, kb);
  for (int kb = 3; kb >= 0; kb--) k_trsmb_g<<<8, 256, 0, stream>>>(SA, PE, SAi, PE, DGA, kb, 4);
  { dim3 g(8, 32);  k_xy<<<g, 256, 0, stream>>>(AQi, SAi, XY); }
  { dim3 g(32, 32); k_xx<<<g, 256, 0, stream>>>(Qi, XY, AQi, XX); }
  { dim3 g(32, 16); k_fk0x<<<g, 256, 0, stream>>>(Gf, XX, FK0x); }
  { dim3 g(8, 16);  k_fk0y<<<g, 256, 0, stream>>>(Gf, XY, FK0y); }
  { dim3 g(16, 16); k_smat<<<g, 256, 0, stream>>>(FK0x, Gf, Smat); }
  { dim3 g(32, 16); k_tr<<<g, 256, 0, stream>>>(FK0x, XGT, MI, ND); }
  { dim3 g(8, 32);  k_tr<<<g, 256, 0, stream>>>(XY, YXm, ND, PE); }
  { dim3 g(8, 16);  k_tr<<<g, 256, 0, stream>>>(FK0y, YGT, MI, PE); }

  // ---- iterations: 27 dispatches each ----
  for (int it = 0; it < NITER; ++it) {
    k_A1<<<448, 256, 0, stream>>>(Qd, Gf, Af, GTf, ATf, qd, bd, hd, xv, sv, zv, yv, scal,
                                  rxv, rp, ry, uv, dinv);
    k_A2<<<448, 256, 0, stream>>>(rxv, GTf, uv, dinv, ry, Smat, FK0x, FK0y, rhs1, Mm);
    for (int kb = 0; kb < 8; kb++) {
      k_diag2<<<2, 256, 0, stream>>>(Mm, LDM, kb, DGC);
      int nb = 7 - kb;
      if (nb > 0) {
        k_chol_panel<<<nb, 256, 0, stream>>>(Mm, LDM, kb, DGC);
        dim3 gs(2 * nb, 2 * nb);
        k_chol_syrk<<<gs, 256, 0, stream>>>(Mm, LDM, kb);
      }
    }
    k_bwd<<<1, 256, 0, stream>>>(Mm, DGC, solw);
    k_upd<<<1, 512, 0, stream>>>(solw, rp, dinv, sv, zv, scal);
    k_C<<<320, 256, 0, stream>>>(XX, XGT, XY, YXm, YGT, SAi, rhs1, solw, ry, scal, xv, yv);
  }
  k_out<<<4, 256, 0, stream>>>(xv, (float*)d_out);
}

// Round 11
// 39161.856 us; speedup vs baseline: 3.6049x; 1.1220x over previous
//
#include <hip/hip_runtime.h>
#include <hip/hip_bf16.h>

// IPM QP solver, f64, dispatch-count-optimized (measured ~50us/dispatch).
// Constant precompute (verified): Q, chol(Q) via fused steps, Qi, K0inv blocks
// (XX, XY, SAi), FK0x=G*XX, FK0y=G*XY, S=FK0x*G^T, transposes.
// Per iteration, 12 dispatches:
//  A1: rx, rp(+uv,dinv), ry
//  A2: rhs1, M=S+diag(s/z), g0 -> Mm row 512
//  diag0 + 7 x k_fps (fused panel+syrk+next-diag; panels recomputed on the fly,
//       written to PL; DG(kb+1) produced by the (kb+1,kb+1) block)
//  bwdupd: 8 fwd strips + backward solve + ds/dz/alpha + s,z,mu update
//  C : dx,dy rows (precomputed GEMV) + x,y update
// Output x as f32.

constexpr int ND = 1024;
constexpr int MI = 512;
constexpr int PE = 256;
constexpr int NM = 512;      // per-iter Schur dim
constexpr int LDM = 520;
constexpr double EPSQ = 1e-4;
constexpr double SIG = 0.1;
constexpr int NITER = 25;

__device__ __forceinline__ double wred(double v) {
#pragma unroll
  for (int off = 32; off; off >>= 1) v += __shfl_down(v, off, 64);
  return v;
}

// ---------------- setup ----------------
__global__ void k_prep(const float* __restrict__ Gf, const float* __restrict__ Af,
                       const float* __restrict__ qf, const float* __restrict__ bf,
                       float* __restrict__ GTf, float* __restrict__ ATf,
                       double* __restrict__ qd, double* __restrict__ bd,
                       double* __restrict__ xv, double* __restrict__ sv,
                       double* __restrict__ zv, double* __restrict__ yv,
                       double* __restrict__ scal) {
  if (blockIdx.x == 0 && threadIdx.x == 0) { scal[0] = 1.0; scal[1] = 0.0; }
  for (size_t idx = (size_t)blockIdx.x * blockDim.x + threadIdx.x;
       idx < (size_t)MI * ND; idx += (size_t)gridDim.x * blockDim.x) {
    int k = (int)(idx >> 10), i = (int)(idx & 1023);
    GTf[(size_t)i * MI + k] = Gf[idx];
    if (idx < (size_t)PE * ND) ATf[(size_t)i * PE + k] = Af[idx];
    if (idx < ND) { qd[idx] = (double)qf[idx]; xv[idx] = 0.0; }
    if (idx < MI) { sv[idx] = 1.0; zv[idx] = 1.0; }
    if (idx < PE) { bd[idx] = (double)bf[idx]; yv[idx] = 0.0; }
  }
}

__global__ __launch_bounds__(256) void k_h(const float* __restrict__ Gf,
                                           const float* __restrict__ x0f,
                                           const float* __restrict__ s0f,
                                           double* __restrict__ hd) {
  int wid = blockIdx.x * 4 + (int)(threadIdx.x >> 6), lane = threadIdx.x & 63;
  if (wid >= MI) return;
  double acc = 0;
  for (int c = lane; c < ND; c += 64) acc += (double)Gf[(size_t)wid * ND + c] * (double)x0f[c];
  acc = wred(acc);
  if (lane == 0) hd[wid] = acc + (double)s0f[wid];
}

// Q = tril(L)tril(L)^T + epsI -> Qd and LQ
__global__ __launch_bounds__(256) void k_qbuild(const float* __restrict__ Lf,
                                                double* __restrict__ Qd, double* __restrict__ LQ) {
  __shared__ double As[32][33], Bs[32][33];
  int i0 = blockIdx.y * 32, j0 = blockIdx.x * 32;
  int tx = threadIdx.x & 15, ty = threadIdx.x >> 4;
  double acc[2][2] = {};
  int kmax = (i0 < j0 ? i0 : j0) + 32;
  for (int k0 = 0; k0 < kmax; k0 += 32) {
    for (int l = threadIdx.x; l < 1024; l += 256) {
      int r = l >> 5, c = l & 31;
      As[r][c] = (k0 + c <= i0 + r) ? (double)Lf[(size_t)(i0 + r) * ND + k0 + c] : 0.0;
      Bs[r][c] = (k0 + c <= j0 + r) ? (double)Lf[(size_t)(j0 + r) * ND + k0 + c] : 0.0;
    }
    __syncthreads();
#pragma unroll
    for (int k = 0; k < 32; k++) {
      double a0 = As[2 * ty][k], a1 = As[2 * ty + 1][k];
      double b0 = Bs[2 * tx][k], b1 = Bs[2 * tx + 1][k];
      acc[0][0] += a0 * b0; acc[0][1] += a0 * b1;
      acc[1][0] += a1 * b0; acc[1][1] += a1 * b1;
    }
    __syncthreads();
  }
  for (int da = 0; da < 2; da++)
    for (int db = 0; db < 2; db++) {
      int i = i0 + 2 * ty + da, j = j0 + 2 * tx + db;
      double v = acc[da][db] + (i == j ? EPSQ : 0.0);
      Qd[(size_t)i * ND + j] = v;
      LQ[(size_t)i * ND + j] = v;
    }
}

// diag0: factor A(0,0) 64x64 + write DG[0]  (verified)
__global__ __launch_bounds__(256) void k_chol_diag_inv(double* __restrict__ A, int lda, int kb,
                                                       double* __restrict__ DG) {
  __shared__ double a[64][65];
  __shared__ double invp[2080];
  __shared__ double dfloor;
  int t = threadIdx.x;
  size_t base = (size_t)kb * 64;
  for (int l = t; l < 4096; l += 256) { int r = l >> 6, c = l & 63; a[r][c] = A[(base + r) * lda + base + c]; }
  __syncthreads();
  if (t == 0) {
    double m = 0;
    for (int i = 0; i < 64; i++) m = fmax(m, fabs(a[i][i]));
    dfloor = m * 1e-28 + 1e-280;
  }
  __syncthreads();
  for (int j = 0; j < 64; j++) {
    if (t == 0) a[j][j] = sqrt(fmax(a[j][j], dfloor));
    __syncthreads();
    double piv = a[j][j];
    for (int r = j + 1 + t; r < 64; r += 256) a[r][j] /= piv;
    __syncthreads();
    int w = 63 - j;
    for (int l = t; l < w * w; l += 256) {
      int rr = j + 1 + l / w, cc = j + 1 + l % w;
      if (cc <= rr) a[rr][cc] -= a[rr][j] * a[cc][j];
    }
    __syncthreads();
  }
  for (int l = t; l < 4096; l += 256) { int r = l >> 6, c = l & 63; if (c <= r) A[(base + r) * lda + base + c] = a[r][c]; }
  if (t < 64) {
    int c = t;
    for (int i = c; i < 64; i++) {
      double v = (i == c) ? 1.0 : 0.0;
      for (int k = c; k < i; k++) v -= a[i][k] * invp[k * (k + 1) / 2 + c];
      invp[i * (i + 1) / 2 + c] = v / a[i][i];
    }
  }
  __syncthreads();
  for (int l = t; l < 4096; l += 256) {
    int r = l >> 6, c = l & 63;
    DG[(size_t)kb * 4096 + (size_t)c * 64 + r] = (c <= r) ? invp[r * (r + 1) / 2 + c] : 0.0;
  }
}

// Fused chol step kb: each block (i,j), kb+1<=j<=i<nbk, recomputes panels
// P_i, P_j from A col kb x DG[kb], updates trailing tile A(i,j) -= P_i P_j^T;
// (i,i) writes P_i to PL col kb; block (kb+1,kb+1) factors its tile -> DG[kb+1].
__global__ __launch_bounds__(256) void k_fps(double* __restrict__ A, int lda,
                                             double* __restrict__ PL, int ldp,
                                             double* __restrict__ DG, int kb) {
  extern __shared__ double sh[];
  double* DT = sh;            // 4096
  double* Bs = sh + 4096;     // 4160 (64x65); later invp overlay
  double* Pi = sh + 8256;     // 4160
  double* Pj = sh + 12416;    // 4160; also 'a' for diag factor
  const int t = threadIdx.x;
  int idx = blockIdx.x;
  int bi = (int)((sqrtf(8.0f * (float)idx + 1.0f) - 1.0f) * 0.5f);
  while ((bi + 1) * (bi + 2) / 2 <= idx) ++bi;
  while (bi * (bi + 1) / 2 > idx) --bi;
  int bj = idx - bi * (bi + 1) / 2;
  const int ib = kb + 1 + bi, jb = kb + 1 + bj;
  const int tx = t & 15, ty = t >> 4;

  for (int l = t; l < 4096; l += 256) DT[l] = DG[(size_t)kb * 4096 + l];
  for (int l = t; l < 4096; l += 256) { int r = l >> 6, c = l & 63; Bs[r * 65 + c] = A[(size_t)(ib * 64 + r) * lda + kb * 64 + c]; }
  __syncthreads();
  // Pi = Bs * DT   (P[r][c] = sum_k Bs[r][k]*DT[k*64+c])  == verified panel math
  {
    double acc[4][4] = {};
    for (int k = 0; k < 64; ++k) {
      double b0 = Bs[ty * 65 + k], b1 = Bs[(ty + 16) * 65 + k];
      double b2 = Bs[(ty + 32) * 65 + k], b3 = Bs[(ty + 48) * 65 + k];
      double d0 = DT[k * 64 + tx], d1 = DT[k * 64 + tx + 16];
      double d2 = DT[k * 64 + tx + 32], d3 = DT[k * 64 + tx + 48];
      acc[0][0] += b0 * d0; acc[0][1] += b0 * d1; acc[0][2] += b0 * d2; acc[0][3] += b0 * d3;
      acc[1][0] += b1 * d0; acc[1][1] += b1 * d1; acc[1][2] += b1 * d2; acc[1][3] += b1 * d3;
      acc[2][0] += b2 * d0; acc[2][1] += b2 * d1; acc[2][2] += b2 * d2; acc[2][3] += b2 * d3;
      acc[3][0] += b3 * d0; acc[3][1] += b3 * d1; acc[3][2] += b3 * d2; acc[3][3] += b3 * d3;
    }
    __syncthreads();
    for (int e = 0; e < 4; ++e)
      for (int f = 0; f < 4; ++f) Pi[(ty + 16 * e) * 65 + tx + 16 * f] = acc[e][f];
  }
  __syncthreads();
  if (ib == jb) {
    // write PL col kb
    for (int l = t; l < 4096; l += 256) {
      int r = l >> 6, c = l & 63;
      PL[(size_t)(ib * 64 + r) * ldp + kb * 64 + c] = Pi[r * 65 + c];
    }
    // update tile into 'a' (=Pj buffer): a = A(tile) - Pi Pi^T
    double* a = Pj;
    {
      double acc[4][4] = {};
      for (int k = 0; k < 64; ++k) {
        double p0 = Pi[ty * 65 + k], p1 = Pi[(ty + 16) * 65 + k];
        double p2 = Pi[(ty + 32) * 65 + k], p3 = Pi[(ty + 48) * 65 + k];
        double q0 = Pi[tx * 65 + k], q1 = Pi[(tx + 16) * 65 + k];
        double q2 = Pi[(tx + 32) * 65 + k], q3 = Pi[(tx + 48) * 65 + k];
        acc[0][0] += p0 * q0; acc[0][1] += p0 * q1; acc[0][2] += p0 * q2; acc[0][3] += p0 * q3;
        acc[1][0] += p1 * q0; acc[1][1] += p1 * q1; acc[1][2] += p1 * q2; acc[1][3] += p1 * q3;
        acc[2][0] += p2 * q0; acc[2][1] += p2 * q1; acc[2][2] += p2 * q2; acc[2][3] += p2 * q3;
        acc[3][0] += p3 * q0; acc[3][1] += p3 * q1; acc[3][2] += p3 * q2; acc[3][3] += p3 * q3;
      }
      for (int e = 0; e < 4; ++e)
        for (int f = 0; f < 4; ++f) {
          int r = ty + 16 * e, c = tx + 16 * f;
          a[r * 65 + c] = A[(size_t)(ib * 64 + r) * lda + jb * 64 + c] - acc[e][f];
        }
    }
    __syncthreads();
    if (ib == kb + 1) {
      // factor 'a' -> DG[kb+1]   (verified diag code)
      if (t == 0) {
        double m = 0;
        for (int i = 0; i < 64; i++) m = fmax(m, fabs(a[i * 65 + i]));
        sh[16576] = m * 1e-28 + 1e-280;
      }
      __syncthreads();
      double dfloor = sh[16576];
      for (int j = 0; j < 64; ++j) {
        if (t == 0) a[j * 65 + j] = sqrt(fmax(a[j * 65 + j], dfloor));
        __syncthreads();
        double piv = a[j * 65 + j];
        for (int r = j + 1 + t; r < 64; r += 256) a[r * 65 + j] /= piv;
        __syncthreads();
        int w = 63 - j;
        for (int l = t; l < w * w; l += 256) {
          int rr = j + 1 + l / w, cc = j + 1 + l % w;
          if (cc <= rr) a[rr * 65 + cc] -= a[rr * 65 + j] * a[cc * 65 + j];
        }
        __syncthreads();
      }
      double* invp = Bs;   // Bs dead
      if (t < 64) {
        int c = t;
        for (int i = c; i < 64; ++i) {
          double v = (i == c) ? 1.0 : 0.0;
          for (int k = c; k < i; ++k) v -= a[i * 65 + k] * invp[k * (k + 1) / 2 + c];
          invp[i * (i + 1) / 2 + c] = v / a[i * 65 + i];
        }
      }
      __syncthreads();
      for (int l = t; l < 4096; l += 256) {
        int r = l >> 6, c = l & 63;
        DG[(size_t)(kb + 1) * 4096 + (size_t)c * 64 + r] = (c <= r) ? invp[r * (r + 1) / 2 + c] : 0.0;
      }
    } else {
      // write updated tile back (factored in a later step)
      for (int l = t; l < 4096; l += 256) {
        int r = l >> 6, c = l & 63;
        A[(size_t)(ib * 64 + r) * lda + jb * 64 + c] = a[r * 65 + c];
      }
    }
  } else {
    // load B_j, compute Pj
    for (int l = t; l < 4096; l += 256) { int r = l >> 6, c = l & 63; Bs[r * 65 + c] = A[(size_t)(jb * 64 + r) * lda + kb * 64 + c]; }
    __syncthreads();
    {
      double acc[4][4] = {};
      for (int k = 0; k < 64; ++k) {
        double b0 = Bs[ty * 65 + k], b1 = Bs[(ty + 16) * 65 + k];
        double b2 = Bs[(ty + 32) * 65 + k], b3 = Bs[(ty + 48) * 65 + k];
        double d0 = DT[k * 64 + tx], d1 = DT[k * 64 + tx + 16];
        double d2 = DT[k * 64 + tx + 32], d3 = DT[k * 64 + tx + 48];
        acc[0][0] += b0 * d0; acc[0][1] += b0 * d1; acc[0][2] += b0 * d2; acc[0][3] += b0 * d3;
        acc[1][0] += b1 * d0; acc[1][1] += b1 * d1; acc[1][2] += b1 * d2; acc[1][3] += b1 * d3;
        acc[2][0] += b2 * d0; acc[2][1] += b2 * d1; acc[2][2] += b2 * d2; acc[2][3] += b2 * d3;
        acc[3][0] += b3 * d0; acc[3][1] += b3 * d1; acc[3][2] += b3 * d2; acc[3][3] += b3 * d3;
      }
      __syncthreads();
      for (int e = 0; e < 4; ++e)
        for (int f = 0; f < 4; ++f) Pj[(ty + 16 * e) * 65 + tx + 16 * f] = acc[e][f];
    }
    __syncthreads();
    // A(i,j) -= Pi Pj^T
    double acc[4][4] = {};
    for (int k = 0; k < 64; ++k) {
      double p0 = Pi[ty * 65 + k], p1 = Pi[(ty + 16) * 65 + k];
      double p2 = Pi[(ty + 32) * 65 + k], p3 = Pi[(ty + 48) * 65 + k];
      double q0 = Pj[tx * 65 + k], q1 = Pj[(tx + 16) * 65 + k];
      double q2 = Pj[(tx + 32) * 65 + k], q3 = Pj[(tx + 48) * 65 + k];
      acc[0][0] += p0 * q0; acc[0][1] += p0 * q1; acc[0][2] += p0 * q2; acc[0][3] += p0 * q3;
      acc[1][0] += p1 * q0; acc[1][1] += p1 * q1; acc[1][2] += p1 * q2; acc[1][3] += p1 * q3;
      acc[2][0] += p2 * q0; acc[2][1] += p2 * q1; acc[2][2] += p2 * q2; acc[2][3] += p2 * q3;
      acc[3][0] += p3 * q0; acc[3][1] += p3 * q1; acc[3][2] += p3 * q2; acc[3][3] += p3 * q3;
    }
    for (int e = 0; e < 4; ++e)
      for (int f = 0; f < 4; ++f) {
        int r = ty + 16 * e, c = tx + 16 * f;
        size_t off = (size_t)(ib * 64 + r) * lda + jb * 64 + c;
        A[off] -= acc[e][f];
      }
  }
}

// generic trsm identity-RHS fwd / in-place bwd (verified); L read from PL
__global__ __launch_bounds__(256) void k_trsmf_g(const double* __restrict__ Lm, int lda,
                                                 double* __restrict__ X, int ldx,
                                                 const double* __restrict__ DG, int kb) {
  __shared__ double Lb[64][64];
  __shared__ double Xs[64][33];
  int t = threadIdx.x;
  int c0 = blockIdx.x * 32;
  int lane2 = t & 31, rbase = t >> 5;
  int row0 = kb * 64;
  double acc[8];
#pragma unroll
  for (int e = 0; e < 8; e++) acc[e] = (row0 + rbase + 8 * e == c0 + lane2) ? 1.0 : 0.0;
  for (int jb = 0; jb < kb; jb++) {
    for (int l = t; l < 4096; l += 256) { int r = l >> 6, c = l & 63; Lb[r][c] = Lm[(size_t)(row0 + r) * lda + jb * 64 + c]; }
    for (int l = t; l < 2048; l += 256) { int k = l >> 5, c = l & 31; Xs[k][c] = X[(size_t)(jb * 64 + k) * ldx + c0 + c]; }
    __syncthreads();
#pragma unroll 4
    for (int k = 0; k < 64; k++) {
      double wv = Xs[k][lane2];
#pragma unroll
      for (int e = 0; e < 8; e++) acc[e] -= Lb[rbase + 8 * e][k] * wv;
    }
    __syncthreads();
  }
  __syncthreads();
#pragma unroll
  for (int e = 0; e < 8; e++) Xs[rbase + 8 * e][lane2] = acc[e];
  for (int l = t; l < 4096; l += 256) Lb[l >> 6][l & 63] = DG[(size_t)kb * 4096 + l];
  __syncthreads();
#pragma unroll
  for (int e = 0; e < 8; e++) {
    int i = rbase + 8 * e;
    double s = 0;
#pragma unroll 4
    for (int k = 0; k < 64; k++) s += Lb[k][i] * Xs[k][lane2];
    X[(size_t)(row0 + i) * ldx + c0 + lane2] = s;
  }
}

__global__ __launch_bounds__(256) void k_trsmb_g(const double* __restrict__ Lm, int lda,
                                                 double* __restrict__ X, int ldx,
                                                 const double* __restrict__ DG, int kb, int nkb) {
  __shared__ double Lb[64][64];
  __shared__ double Xs[64][33];
  int t = threadIdx.x;
  int c0 = blockIdx.x * 32;
  int lane2 = t & 31, rbase = t >> 5;
  int row0 = kb * 64;
  double acc[8];
#pragma unroll
  for (int e = 0; e < 8; e++) acc[e] = X[(size_t)(row0 + rbase + 8 * e) * ldx + c0 + lane2];
  for (int jb = kb + 1; jb < nkb; jb++) {
    for (int l = t; l < 4096; l += 256) { int r = l >> 6, c = l & 63; Lb[r][c] = Lm[(size_t)(jb * 64 + r) * lda + kb * 64 + c]; }
    for (int l = t; l < 2048; l += 256) { int k = l >> 5, c = l & 31; Xs[k][c] = X[(size_t)(jb * 64 + k) * ldx + c0 + c]; }
    __syncthreads();
#pragma unroll 4
    for (int k = 0; k < 64; k++) {
      double wv = Xs[k][lane2];
#pragma unroll
      for (int e = 0; e < 8; e++) acc[e] -= Lb[k][rbase + 8 * e] * wv;
    }
    __syncthreads();
  }
  __syncthreads();
#pragma unroll
  for (int e = 0; e < 8; e++) Xs[rbase + 8 * e][lane2] = acc[e];
  for (int l = t; l < 4096; l += 256) Lb[l >> 6][l & 63] = DG[(size_t)kb * 4096 + l];
  __syncthreads();
#pragma unroll
  for (int e = 0; e < 8; e++) {
    int i = rbase + 8 * e;
    double s = 0;
#pragma unroll 4
    for (int k = 0; k < 64; k++) s += Lb[i][k] * Xs[k][lane2];
    X[(size_t)(row0 + i) * ldx + c0 + lane2] = s;
  }
}

// ---------------- setup GEMMs (verified) ----------------
__global__ __launch_bounds__(256) void k_aqi(const float* __restrict__ Af, const double* __restrict__ Qi,
                                             double* __restrict__ AQi) {
  __shared__ double As[32][33], Bs[32][33];
  int i0 = blockIdx.x * 32, a0 = blockIdx.y * 32;
  int tx = threadIdx.x & 15, ty = threadIdx.x >> 4;
  double acc[2][2] = {};
  for (int k0 = 0; k0 < ND; k0 += 32) {
    for (int l = threadIdx.x; l < 1024; l += 256) {
      int r = l >> 5, c = l & 31;
      As[r][c] = (double)Af[(size_t)(a0 + r) * ND + k0 + c];
      Bs[r][c] = Qi[(size_t)(k0 + r) * ND + i0 + c];
    }
    __syncthreads();
#pragma unroll
    for (int k = 0; k < 32; k++) {
      double a0v = As[2 * ty][k], a1v = As[2 * ty + 1][k];
      double b0v = Bs[k][2 * tx], b1v = Bs[k][2 * tx + 1];
      acc[0][0] += a0v * b0v; acc[0][1] += a0v * b1v;
      acc[1][0] += a1v * b0v; acc[1][1] += a1v * b1v;
    }
    __syncthreads();
  }
  for (int da = 0; da < 2; da++)
    for (int db = 0; db < 2; db++)
      AQi[(size_t)(a0 + 2 * ty + da) * ND + i0 + 2 * tx + db] = acc[da][db];
}

__global__ __launch_bounds__(256) void k_sa(const double* __restrict__ AQi, const float* __restrict__ Af,
                                            double* __restrict__ SA) {
  __shared__ double As[32][33], Bs[32][33];
  int a0 = blockIdx.y * 32, b0 = blockIdx.x * 32;
  int tx = threadIdx.x & 15, ty = threadIdx.x >> 4;
  double acc[2][2] = {};
  for (int k0 = 0; k0 < ND; k0 += 32) {
    for (int l = threadIdx.x; l < 1024; l += 256) {
      int r = l >> 5, c = l & 31;
      As[r][c] = AQi[(size_t)(a0 + r) * ND + k0 + c];
      Bs[r][c] = (double)Af[(size_t)(b0 + r) * ND + k0 + c];
    }
    __syncthreads();
#pragma unroll
    for (int k = 0; k < 32; k++) {
      double a0v = As[2 * ty][k], a1v = As[2 * ty + 1][k];
      double b0v = Bs[2 * tx][k], b1v = Bs[2 * tx + 1][k];
      acc[0][0] += a0v * b0v; acc[0][1] += a0v * b1v;
      acc[1][0] += a1v * b0v; acc[1][1] += a1v * b1v;
    }
    __syncthreads();
  }
  for (int da = 0; da < 2; da++)
    for (int db = 0; db < 2; db++)
      SA[(size_t)(a0 + 2 * ty + da) * PE + b0 + 2 * tx + db] = acc[da][db];
}

__global__ __launch_bounds__(256) void k_xy(const double* __restrict__ AQi, const double* __restrict__ SAi,
                                            double* __restrict__ XY) {
  __shared__ double As[32][33], Bs[32][33];
  int b0 = blockIdx.x * 32, i0 = blockIdx.y * 32;
  int tx = threadIdx.x & 15, ty = threadIdx.x >> 4;
  double acc[2][2] = {};
  for (int k0 = 0; k0 < PE; k0 += 32) {
    for (int l = threadIdx.x; l < 1024; l += 256) {
      int r = l >> 5, c = l & 31;
      As[r][c] = AQi[(size_t)(k0 + r) * ND + i0 + c];
      Bs[r][c] = SAi[(size_t)(k0 + r) * PE + b0 + c];
    }
    __syncthreads();
#pragma unroll
    for (int k = 0; k < 32; k++) {
      double a0v = As[k][2 * ty], a1v = As[k][2 * ty + 1];
      double b0v = Bs[k][2 * tx], b1v = Bs[k][2 * tx + 1];
      acc[0][0] += a0v * b0v; acc[0][1] += a0v * b1v;
      acc[1][0] += a1v * b0v; acc[1][1] += a1v * b1v;
    }
    __syncthreads();
  }
  for (int da = 0; da < 2; da++)
    for (int db = 0; db < 2; db++)
      XY[(size_t)(i0 + 2 * ty + da) * PE + b0 + 2 * tx + db] = acc[da][db];
}

__global__ __launch_bounds__(256) void k_xx(const double* __restrict__ Qi, const double* __restrict__ XY,
                                            const double* __restrict__ AQi, double* __restrict__ XX) {
  __shared__ double As[32][33], Bs[32][33];
  int j0 = blockIdx.x * 32, i0 = blockIdx.y * 32;
  int tx = threadIdx.x & 15, ty = threadIdx.x >> 4;
  double acc[2][2] = {};
  for (int k0 = 0; k0 < PE; k0 += 32) {
    for (int l = threadIdx.x; l < 1024; l += 256) {
      int r = l >> 5, c = l & 31;
      As[r][c] = XY[(size_t)(i0 + r) * PE + k0 + c];
      Bs[r][c] = AQi[(size_t)(k0 + r) * ND + j0 + c];
    }
    __syncthreads();
#pragma unroll
    for (int k = 0; k < 32; k++) {
      double a0v = As[2 * ty][k], a1v = As[2 * ty + 1][k];
      double b0v = Bs[k][2 * tx], b1v = Bs[k][2 * tx + 1];
      acc[0][0] += a0v * b0v; acc[0][1] += a0v * b1v;
      acc[1][0] += a1v * b0v; acc[1][1] += a1v * b1v;
    }
    __syncthreads();
  }
  for (int da = 0; da < 2; da++)
    for (int db = 0; db < 2; db++) {
      int i = i0 + 2 * ty + da, j = j0 + 2 * tx + db;
      XX[(size_t)i * ND + j] = Qi[(size_t)i * ND + j] - acc[da][db];
    }
}

__global__ __launch_bounds__(256) void k_fk0x(const float* __restrict__ Gf, const double* __restrict__ XX,
                                              double* __restrict__ FK0x) {
  __shared__ double As[32][33], Bs[32][33];
  int j0 = blockIdx.x * 32, g0 = blockIdx.y * 32;
  int tx = threadIdx.x & 15, ty = threadIdx.x >> 4;
  double acc[2][2] = {};
  for (int k0 = 0; k0 < ND; k0 += 32) {
    for (int l = threadIdx.x; l < 1024; l += 256) {
      int r = l >> 5, c = l & 31;
      As[r][c] = (double)Gf[(size_t)(g0 + r) * ND + k0 + c];
      Bs[r][c] = XX[(size_t)(k0 + r) * ND + j0 + c];
    }
    __syncthreads();
#pragma unroll
    for (int k = 0; k < 32; k++) {
      double a0v = As[2 * ty][k], a1v = As[2 * ty + 1][k];
      double b0v = Bs[k][2 * tx], b1v = Bs[k][2 * tx + 1];
      acc[0][0] += a0v * b0v; acc[0][1] += a0v * b1v;
      acc[1][0] += a1v * b0v; acc[1][1] += a1v * b1v;
    }
    __syncthreads();
  }
  for (int da = 0; da < 2; da++)
    for (int db = 0; db < 2; db++)
      FK0x[(size_t)(g0 + 2 * ty + da) * ND + j0 + 2 * tx + db] = acc[da][db];
}

__global__ __launch_bounds__(256) void k_fk0y(const float* __restrict__ Gf, const double* __restrict__ XY,
                                              double* __restrict__ FK0y) {
  __shared__ double As[32][33], Bs[32][33];
  int b0 = blockIdx.x * 32, g0 = blockIdx.y * 32;
  int tx = threadIdx.x & 15, ty = threadIdx.x >> 4;
  double acc[2][2] = {};
  for (int k0 = 0; k0 < ND; k0 += 32) {
    for (int l = threadIdx.x; l < 1024; l += 256) {
      int r = l >> 5, c = l & 31;
      As[r][c] = (double)Gf[(size_t)(g0 + r) * ND + k0 + c];
      Bs[r][c] = XY[(size_t)(k0 + r) * PE + b0 + c];
    }
    __syncthreads();
#pragma unroll
    for (int k = 0; k < 32; k++) {
      double a0v = As[2 * ty][k], a1v = As[2 * ty + 1][k];
      double b0v = Bs[k][2 * tx], b1v = Bs[k][2 * tx + 1];
      acc[0][0] += a0v * b0v; acc[0][1] += a0v * b1v;
      acc[1][0] += a1v * b0v; acc[1][1] += a1v * b1v;
    }
    __syncthreads();
  }
  for (int da = 0; da < 2; da++)
    for (int db = 0; db < 2; db++)
      FK0y[(size_t)(g0 + 2 * ty + da) * PE + b0 + 2 * tx + db] = acc[da][db];
}

__global__ __launch_bounds__(256) void k_smat(const double* __restrict__ FK0x, const float* __restrict__ Gf,
                                              double* __restrict__ S) {
  __shared__ double As[32][33], Bs[32][33];
  int g0 = blockIdx.y * 32, h0 = blockIdx.x * 32;
  int tx = threadIdx.x & 15, ty = threadIdx.x >> 4;
  double acc[2][2] = {};
  for (int k0 = 0; k0 < ND; k0 += 32) {
    for (int l = threadIdx.x; l < 1024; l += 256) {
      int r = l >> 5, c = l & 31;
      As[r][c] = FK0x[(size_t)(g0 + r) * ND + k0 + c];
      Bs[r][c] = (double)Gf[(size_t)(h0 + r) * ND + k0 + c];
    }
    __syncthreads();
#pragma unroll
    for (int k = 0; k < 32; k++) {
      double a0v = As[2 * ty][k], a1v = As[2 * ty + 1][k];
      double b0v = Bs[2 * tx][k], b1v = Bs[2 * tx + 1][k];
      acc[0][0] += a0v * b0v; acc[0][1] += a0v * b1v;
      acc[1][0] += a1v * b0v; acc[1][1] += a1v * b1v;
    }
    __syncthreads();
  }
  for (int da = 0; da < 2; da++)
    for (int db = 0; db < 2; db++)
      S[(size_t)(g0 + 2 * ty + da) * MI + h0 + 2 * tx + db] = acc[da][db];
}

__global__ __launch_bounds__(256) void k_tr(const double* __restrict__ src, double* __restrict__ dst,
                                            int R, int Cc) {
  __shared__ double tile[32][33];
  int r0 = blockIdx.y * 32, c0 = blockIdx.x * 32;
  for (int l = threadIdx.x; l < 1024; l += 256) {
    int r = l >> 5, c = l & 31;
    tile[r][c] = src[(size_t)(r0 + r) * Cc + c0 + c];
  }
  __syncthreads();
  for (int l = threadIdx.x; l < 1024; l += 256) {
    int r = l >> 5, c = l & 31;
    dst[(size_t)(c0 + r) * R + r0 + c] = tile[c][r];
  }
}

// ---------------- per-iteration kernels ----------------
__global__ __launch_bounds__(256) void k_A1(const double* __restrict__ Qd, const float* __restrict__ Gf,
                                            const float* __restrict__ Af, const float* __restrict__ GTf,
                                            const float* __restrict__ ATf, const double* __restrict__ qd,
                                            const double* __restrict__ bd, const double* __restrict__ hd,
                                            const double* __restrict__ xv, const double* __restrict__ sv,
                                            const double* __restrict__ zv, const double* __restrict__ yv,
                                            const double* __restrict__ scal,
                                            double* __restrict__ rxv, double* __restrict__ rp,
                                            double* __restrict__ ry, double* __restrict__ uv,
                                            double* __restrict__ dinv) {
  int lane = threadIdx.x & 63;
  if (blockIdx.x < 256) {
    int wid = blockIdx.x * 4 + (int)(threadIdx.x >> 6);
    double acc = 0;
    for (int k = lane; k < ND; k += 64) acc += Qd[(size_t)wid * ND + k] * xv[k];
    for (int k = lane; k < MI; k += 64) acc += (double)GTf[(size_t)wid * MI + k] * zv[k];
    for (int k = lane; k < PE; k += 64) acc += (double)ATf[(size_t)wid * PE + k] * yv[k];
    acc = wred(acc);
    if (lane == 0) rxv[wid] = acc + qd[wid];
  } else {
    int wid = (blockIdx.x - 256) * 4 + (int)(threadIdx.x >> 6);
    if (wid < MI) {
      double acc = 0;
      for (int c = lane; c < ND; c += 64) acc += (double)Gf[(size_t)wid * ND + c] * xv[c];
      acc = wred(acc);
      if (lane == 0) {
        double s0 = sv[wid], z0 = zv[wid];
        double rpv = acc + s0 - hd[wid];
        rp[wid] = rpv;
        double rc0 = s0 * z0 - SIG * scal[0];
        uv[wid] = (-rc0 + z0 * rpv) / s0;
        dinv[wid] = s0 / z0;
      }
    } else {
      int r = wid - MI;
      double acc = 0;
      for (int c = lane; c < ND; c += 64) acc += (double)Af[(size_t)r * ND + c] * xv[c];
      acc = wred(acc);
      if (lane == 0) ry[r] = acc - bd[r];
    }
  }
}

// A2: blocks 0..255 rhs1; 256..319 M=S+diag(dinv); 320..447 g0 -> Mm row NM
__global__ __launch_bounds__(256) void k_A2(const double* __restrict__ rxv, const float* __restrict__ GTf,
                                            const double* __restrict__ uv, const double* __restrict__ dinv,
                                            const double* __restrict__ ry, const double* __restrict__ S,
                                            const double* __restrict__ FK0x, const double* __restrict__ FK0y,
                                            double* __restrict__ rhs1, double* __restrict__ Mm) {
  int t = threadIdx.x, lane = t & 63;
  if (blockIdx.x < 256) {
    int wid = blockIdx.x * 4 + (t >> 6);
    double acc = 0;
    for (int k = lane; k < MI; k += 64) acc += (double)GTf[(size_t)wid * MI + k] * uv[k];
    acc = wred(acc);
    if (lane == 0) rhs1[wid] = -(rxv[wid] + acc);
  } else if (blockIdx.x < 320) {
    int rbase = (blockIdx.x - 256) * 8;
    for (int rr = 0; rr < 8; ++rr) {
      int row = rbase + rr;
      for (int c = t; c < NM; c += 256) {
        double v = S[(size_t)row * MI + c];
        if (row == c) v += dinv[row];
        Mm[(size_t)row * LDM + c] = v;
      }
    }
  } else {
    int j = (blockIdx.x - 320) * 4 + (t >> 6);
    double acc = 0;
    for (int k = lane; k < ND; k += 64) acc += FK0x[(size_t)j * ND + k] * rxv[k];
    for (int m = lane; m < MI; m += 64) acc += S[(size_t)j * MI + m] * uv[m];
    for (int c = lane; c < PE; c += 64) acc += FK0y[(size_t)j * PE + c] * ry[c];
    acc = wred(acc);
    if (lane == 0) Mm[(size_t)NM * LDM + j] = -acc;
  }
}

// bwdupd: 8 fwd strips + backward solve (L from PL, inverses from DGC) + upd
__global__ __launch_bounds__(512) void k_bwdupd(const double* __restrict__ Mm, const double* __restrict__ PL,
                                                const double* __restrict__ DGC, const double* __restrict__ rp,
                                                const double* __restrict__ dinv, double* __restrict__ sv,
                                                double* __restrict__ zv, double* __restrict__ scal,
                                                double* __restrict__ solw) {
  __shared__ double DT[4096];
  __shared__ double g[NM];
  __shared__ double pseg[64];
  __shared__ double acc8[8][64];
  __shared__ double tmp[64];
  __shared__ double red[512];
  __shared__ double dsA[512];
  __shared__ double dzA[512];
  int t = threadIdx.x;
  for (int l = t; l < NM; l += 512) g[l] = Mm[(size_t)NM * LDM + l];
  // forward: g <- L^{-1} g
  for (int kbp = 0; kbp < 8; ++kbp) {
    __syncthreads();
    for (int l = t; l < 4096; l += 512) DT[l] = DGC[(size_t)kbp * 4096 + l];
    __syncthreads();
    if (t < 64) {
      double s = 0;
#pragma unroll
      for (int k = 0; k < 64; k++) s += g[kbp * 64 + k] * DT[k * 64 + t];
      pseg[t] = s;
    }
    __syncthreads();
    for (int c = (kbp + 1) * 64 + t; c < NM; c += 512) {
      double s = 0;
#pragma unroll
      for (int k = 0; k < 64; k++) s += pseg[k] * PL[(size_t)c * NM + kbp * 64 + k];
      g[c] -= s;
    }
    if (t < 64) g[kbp * 64 + t] = pseg[t];
  }
  // backward: g <- L^{-T} g
  int i8 = t & 63, p8 = t >> 6;
  for (int kb = 7; kb >= 0; --kb) {
    __syncthreads();
    for (int l = t; l < 4096; l += 512) DT[l] = DGC[(size_t)kb * 4096 + l];
    __syncthreads();
    int tr0 = kb * 64 + 64;
    double s = 0;
    for (int rr = p8; rr < NM - tr0; rr += 8)
      s += PL[(size_t)(tr0 + rr) * NM + kb * 64 + i8] * g[tr0 + rr];
    acc8[p8][i8] = s;
    __syncthreads();
    if (t < 64) {
      double v = g[kb * 64 + t];
#pragma unroll
      for (int p = 0; p < 8; p++) v -= acc8[p][t];
      tmp[t] = v;
    }
    __syncthreads();
    if (t < 64) {
      double v = 0;
#pragma unroll
      for (int l = 0; l < 64; l++) v += DT[t * 64 + l] * tmp[l];
      pseg[t] = v;
    }
    __syncthreads();
    if (t < 64) g[kb * 64 + t] = pseg[t];
  }
  __syncthreads();
  solw[t] = g[t];
  // upd (verified R10 logic)
  double mu = scal[0];
  double s0 = sv[t], z0 = zv[t];
  double ds = -rp[t] - dinv[t] * g[t];
  double rc0 = s0 * z0 - SIG * mu;
  double dz = (-rc0 - z0 * ds) / s0;
  dsA[t] = ds; dzA[t] = dz;
  double rs = (ds < 0.0) ? -s0 / ds : 1.0;
  double rz = (dz < 0.0) ? -z0 / dz : 1.0;
  red[t] = fmin(rs, rz);
  __syncthreads();
  for (int s2 = 256; s2; s2 >>= 1) { if (t < s2) red[t] = fmin(red[t], red[t + s2]); __syncthreads(); }
  double alpha = 0.99 * fmin(1.0, red[0]);
  if (!(alpha == alpha)) alpha = 0.0;
  double us = alpha * dsA[t], uz = alpha * dzA[t];
  if (isfinite(us)) sv[t] += us;
  if (isfinite(uz)) zv[t] += uz;
  __syncthreads();
  red[t] = sv[t] * zv[t];
  __syncthreads();
  for (int s2 = 256; s2; s2 >>= 1) { if (t < s2) red[t] += red[t + s2]; __syncthreads(); }
  if (t == 0) { scal[0] = red[0] / (double)MI; scal[1] = alpha; }
}

// C: dx rows + x update (0..255); dy rows + y update (256..319)
__global__ __launch_bounds__(256) void k_C(const double* __restrict__ XX, const double* __restrict__ XGT,
                                           const double* __restrict__ XY, const double* __restrict__ YXm,
                                           const double* __restrict__ YGT, const double* __restrict__ SAi,
                                           const double* __restrict__ rhs1, const double* __restrict__ solw,
                                           const double* __restrict__ ry, const double* __restrict__ scal,
                                           double* __restrict__ xv, double* __restrict__ yv) {
  int lane = threadIdx.x & 63;
  double al = scal[1];
  if (blockIdx.x < 256) {
    int wid = blockIdx.x * 4 + (int)(threadIdx.x >> 6);
    double acc = 0;
    for (int k = lane; k < ND; k += 64) acc += XX[(size_t)wid * ND + k] * rhs1[k];
    for (int m = lane; m < MI; m += 64) acc -= XGT[(size_t)wid * MI + m] * solw[m];
    for (int c = lane; c < PE; c += 64) acc -= XY[(size_t)wid * PE + c] * ry[c];
    acc = wred(acc);
    if (lane == 0) { double u = al * acc; if (isfinite(u)) xv[wid] += u; }
  } else {
    int r = (blockIdx.x - 256) * 4 + (int)(threadIdx.x >> 6);
    double acc = 0;
    for (int k = lane; k < ND; k += 64) acc += YXm[(size_t)r * ND + k] * rhs1[k];
    for (int m = lane; m < MI; m += 64) acc -= YGT[(size_t)r * MI + m] * solw[m];
    for (int c = lane; c < PE; c += 64) acc += SAi[(size_t)r * PE + c] * ry[c];
    acc = wred(acc);
    if (lane == 0) { double u = al * acc; if (isfinite(u)) yv[r] += u; }
  }
}

__global__ void k_out(const double* __restrict__ xv, float* __restrict__ out) {
  int i = blockIdx.x * blockDim.x + threadIdx.x;
  if (i < ND) out[i] = (float)xv[i];
}

__global__ void k_wsdiag(float mb, float* out) {
  int i = blockIdx.x * 256 + threadIdx.x;
  if (i < ND) out[i] = (i == 0 ? (65536.0f * (1.0f + mb)) : 0.0f);
}

extern "C" void kernel_launch(void* const* d_in, const int* in_sizes, int n_in,
                              void* d_out, int out_size, void* d_ws, size_t ws_size,
                              hipStream_t stream) {
  const float* Lf = (const float*)d_in[0];
  const float* qf = (const float*)d_in[1];
  const float* Gf = (const float*)d_in[2];
  const float* Af = (const float*)d_in[3];
  const float* bf = (const float*)d_in[4];
  const float* x0f = (const float*)d_in[5];
  const float* s0f = (const float*)d_in[6];

  double* w = (double*)d_ws;
  double* Qd  = w; w += (size_t)ND * ND;
  double* XX  = w; w += (size_t)ND * ND;          // also PLQ during setup (dead before k_xx)
  double* R1  = w; w += (size_t)ND * ND;          // Qi -> XGT/YXm/YGT
  double* R2  = w; w += (size_t)ND * ND;          // LQ -> Mm(513xLDM)/FK0y/SAi/Smat
  double* XY  = w; w += (size_t)ND * PE;          // also PLA during setup (dead before k_xy)
  double* FK0xReg = w; w += (size_t)MI * ND;      // AQi -> FK0x
  double* SA  = w; w += (size_t)PE * PE;
  double* PLi = w; w += (size_t)NM * NM;          // iteration chol L panels
  double* DGH = w; w += (size_t)16 * 4096;
  double* DGA = w; w += (size_t)4 * 4096;
  double* DGC = w; w += (size_t)8 * 4096;
  double* qd = w; w += ND;  double* bd = w; w += PE;  double* hd = w; w += MI;
  double* xv = w; w += ND;  double* sv = w; w += MI;  double* zv = w; w += MI;  double* yv = w; w += PE;
  double* rxv = w; w += ND; double* rp = w; w += MI;  double* ry = w; w += PE;
  double* uv = w; w += MI;  double* dinv = w; w += MI;
  double* rhs1 = w; w += ND; double* solw = w; w += NM;
  double* scal = w; w += 16;
  float* GTf = (float*)w;
  float* ATf = GTf + (size_t)ND * MI;
  char* wend = (char*)(ATf + (size_t)ND * PE);
  size_t need = (size_t)(wend - (char*)d_ws);
  if (ws_size < need) {
    k_wsdiag<<<4, 256, 0, stream>>>((float)(ws_size >> 20), (float*)d_out);
    return;
  }

  // region aliases
  double* Qi  = R1;
  double* XGT = R1;                                     // 1024x512 (Qi dead)
  double* YXm = R1 + (size_t)ND * MI;                   // 256x1024
  double* YGT = R1 + (size_t)ND * MI + (size_t)PE * ND; // 256x512
  double* LQ  = R2;
  double* Mm  = R2;                                     // 513 x LDM (LQ dead)
  double* FK0y = R2 + (size_t)(NM + 1) * LDM;           // 512x256
  double* SAi  = FK0y + (size_t)MI * PE;                // 256x256
  double* Smat = SAi + (size_t)PE * PE;                 // 512x512
  double* AQi  = FK0xReg;
  double* FK0x = FK0xReg;
  double* PLQ  = XX;                                    // setup chol(Q) panels
  double* PLA  = XY;                                    // setup chol(SA) panels

  const size_t ldsFPS = (size_t)16640 * sizeof(double);

  // ---- setup ----
  k_prep<<<2048, 256, 0, stream>>>(Gf, Af, qf, bf, GTf, ATf, qd, bd, xv, sv, zv, yv, scal);
  k_h<<<128, 256, 0, stream>>>(Gf, x0f, s0f, hd);
  { dim3 g(32, 32); k_qbuild<<<g, 256, 0, stream>>>(Lf, Qd, LQ); }
  // chol(Q): diag0 + 15 fused steps
  k_chol_diag_inv<<<1, 256, 0, stream>>>(LQ, ND, 0, DGH);
  for (int kb = 0; kb < 15; kb++) {
    int nt = 15 - kb;
    k_fps<<<nt * (nt + 1) / 2, 256, ldsFPS, stream>>>(LQ, ND, PLQ, ND, DGH, kb);
  }
  for (int kb = 0; kb < 16; kb++)  k_trsmf_g<<<32, 256, 0, stream>>>(PLQ, ND, Qi, ND, DGH, kb);
  for (int kb = 15; kb >= 0; kb--) k_trsmb_g<<<32, 256, 0, stream>>>(PLQ, ND, Qi, ND, DGH, kb, 16);
  { dim3 g(32, 8);  k_aqi<<<g, 256, 0, stream>>>(Af, Qi, AQi); }
  { dim3 g(8, 8);   k_sa<<<g, 256, 0, stream>>>(AQi, Af, SA); }
  // chol(SA 256): diag0 + 3 fused steps
  k_chol_diag_inv<<<1, 256, 0, stream>>>(SA, PE, 0, DGA);
  for (int kb = 0; kb < 3; kb++) {
    int nt = 3 - kb;
    k_fps<<<nt * (nt + 1) / 2, 256, ldsFPS, stream>>>(SA, PE, PLA, PE, DGA, kb);
  }
  for (int kb = 0; kb < 4; kb++)  k_trsmf_g<<<8, 256, 0, stream>>>(PLA, PE, SAi, PE, DGA, kb);
  for (int kb = 3; kb >= 0; kb--) k_trsmb_g<<<8, 256, 0, stream>>>(PLA, PE, SAi, PE, DGA, kb, 4);
  { dim3 g(8, 32);  k_xy<<<g, 256, 0, stream>>>(AQi, SAi, XY); }     // overwrites PLA (dead)
  { dim3 g(32, 32); k_xx<<<g, 256, 0, stream>>>(Qi, XY, AQi, XX); }  // overwrites PLQ (dead)
  { dim3 g(32, 16); k_fk0x<<<g, 256, 0, stream>>>(Gf, XX, FK0x); }   // overwrites AQi (dead)
  { dim3 g(8, 16);  k_fk0y<<<g, 256, 0, stream>>>(Gf, XY, FK0y); }
  { dim3 g(16, 16); k_smat<<<g, 256, 0, stream>>>(FK0x, Gf, Smat); }
  { dim3 g(32, 16); k_tr<<<g, 256, 0, stream>>>(FK0x, XGT, MI, ND); } // overwrites Qi (dead)
  { dim3 g(8, 32);  k_tr<<<g, 256, 0, stream>>>(XY, YXm, ND, PE); }
  { dim3 g(8, 16);  k_tr<<<g, 256, 0, stream>>>(FK0y, YGT, MI, PE); }

  // ---- iterations: 12 dispatches each ----
  for (int it = 0; it < NITER; ++it) {
    k_A1<<<448, 256, 0, stream>>>(Qd, Gf, Af, GTf, ATf, qd, bd, hd, xv, sv, zv, yv, scal,
                                  rxv, rp, ry, uv, dinv);
    k_A2<<<448, 256, 0, stream>>>(rxv, GTf, uv, dinv, ry, Smat, FK0x, FK0y, rhs1, Mm);
    k_chol_diag_inv<<<1, 256, 0, stream>>>(Mm, LDM, 0, DGC);
    for (int kb = 0; kb < 7; kb++) {
      int nt = 7 - kb;
      k_fps<<<nt * (nt + 1) / 2, 256, ldsFPS, stream>>>(Mm, LDM, PLi, NM, DGC, kb);
    }
    k_bwdupd<<<1, 512, 0, stream>>>(Mm, PLi, DGC, rp, dinv, sv, zv, scal, solw);
    k_C<<<320, 256, 0, stream>>>(XX, XGT, XY, YXm, YGT, SAi, rhs1, solw, ry, scal, xv, yv);
  }
  k_out<<<4, 256, 0, stream>>>(xv, (float*)d_out);
}